// Round 4
// baseline (2594.493 us; speedup 1.0000x reference)
//
#include <hip/hip_runtime.h>

#define NN 2048
#define NE 32768
#define NG 64
#define DINJ 240
#define DEMB 480
#define DFEAT 512

typedef unsigned short ushort_t;
typedef __attribute__((ext_vector_type(8))) short short8;
typedef __attribute__((ext_vector_type(4))) float floatx4;

__device__ __forceinline__ float b2f(ushort_t u){
  union { unsigned u; float f; } x; x.u = ((unsigned)u) << 16; return x.f;
}
__device__ __forceinline__ ushort_t f2b(float f){
  union { float f; unsigned u; } x; x.f = f;
  unsigned r = x.u + 0x7FFFu + ((x.u >> 16) & 1u);
  return (ushort_t)(r >> 16);
}
__device__ __forceinline__ float wredsum(float v){
  #pragma unroll
  for (int o = 32; o > 0; o >>= 1) v += __shfl_xor(v, o, 64);
  return v;
}
__device__ __forceinline__ float silu_f(float x){ return x / (1.f + __expf(-x)); }

// ---------------- small utility kernels ----------------
__global__ void zero_f32(float* p, int n){
  int i = blockIdx.x*256 + threadIdx.x; if (i < n) p[i] = 0.f;
}

// ---------------- input dtype detection ----------------
// flag=0: float inputs are bf16; flag=1: they are fp32.
__global__ void detect_kernel(const ushort_t* __restrict__ probe, int* flag){
  __shared__ int c;
  if (threadIdx.x == 0) c = 0;
  __syncthreads();
  ushort_t u = probe[2*threadIdx.x];
  int e = (u >> 7) & 0xFF;
  int plausible = (u == 0) || (e >= 100 && e <= 140);
  atomicAdd(&c, plausible);
  __syncthreads();
  if (threadIdx.x == 0) *flag = (c >= 192) ? 0 : 1;
}

// -------- convert small float inputs -> internal FP32 (exact either way) ----
struct CDesc { const void* src; float* dst; int n; };
struct CDescArr { CDesc d[11]; };
__global__ __launch_bounds__(256) void convert_inputs(CDescArr ca, const int* __restrict__ flag){
  CDesc cd = ca.d[blockIdx.y];
  int isf32 = *flag;
  for (int i = blockIdx.x*256 + threadIdx.x; i < cd.n; i += gridDim.x*256){
    cd.dst[i] = isf32 ? ((const float*)cd.src)[i] : b2f(((const ushort_t*)cd.src)[i]);
  }
}

// --- batched weight transpose (K x M -> M x Kpad, split bf16 hi/lo, padded) --
struct TDesc { const void* src; ushort_t* dh; ushort_t* dl; int K; int M; int Kpad; int eoff; };
struct TDescArr { TDesc d[37]; };
__global__ __launch_bounds__(256) void transpose_all(TDescArr ta, const int* __restrict__ flag){
  TDesc td = ta.d[blockIdx.y];
  int isf32 = *flag;
  int total = td.M * td.Kpad;
  for (int i = blockIdx.x*256 + threadIdx.x; i < total; i += gridDim.x*256){
    int n = i / td.Kpad, k = i - n*td.Kpad;
    float x = 0.f;
    if (k < td.K){
      size_t si = (size_t)td.eoff + (size_t)k*td.M + n;
      x = isf32 ? ((const float*)td.src)[si] : b2f(((const ushort_t*)td.src)[si]);
    }
    ushort_t h = f2b(x);
    td.dh[i] = h;
    td.dl[i] = f2b(x - b2f(h));
  }
}

// ---------------- geometry (fp32 pos) ----------------
__global__ void geom_kernel(const float* __restrict__ pos,
                            const int* __restrict__ esrc, const int* __restrict__ edst,
                            float* __restrict__ sh, float* __restrict__ dist){
  int e = blockIdx.x*256 + threadIdx.x; if (e >= NE) return;
  int s = esrc[e], d = edst[e];
  float x = pos[s*3+0] - pos[d*3+0];
  float y = pos[s*3+1] - pos[d*3+1];
  float z = pos[s*3+2] - pos[d*3+2];
  float dd = sqrtf(x*x + y*y + z*z + 1e-12f);
  float ix = x/dd, iy = y/dd, iz = z/dd;
  const float s3 = 1.7320508075688772f, s15 = 3.872983346207417f, s5 = 2.23606797749979f;
  float* o = sh + (size_t)e*9;
  o[0] = 1.f; o[1] = s3*ix; o[2] = s3*iy; o[3] = s3*iz;
  o[4] = s15*ix*iy; o[5] = s15*iy*iz; o[6] = 0.5f*s5*(3.f*iz*iz - 1.f);
  o[7] = s15*ix*iz; o[8] = 0.5f*s15*(ix*ix - iy*iy);
  dist[e] = dd;
}

__global__ void rbf_kernel(const float* __restrict__ dist, float* __restrict__ rbf){
  int idx = blockIdx.x*256 + threadIdx.x; if (idx >= NE*128) return;
  int e = idx >> 7, r = idx & 127;
  float c = (float)r * (5.0f/127.0f);
  float u = (dist[e] - c) * (128.0f/5.0f);
  rbf[idx] = __expf(-0.5f*u*u);
}

__global__ void t9_kernel(const float* __restrict__ rbf, const float* __restrict__ sh,
                          const float* __restrict__ degWr, float* __restrict__ t9){
  int idx = blockIdx.x*256 + threadIdx.x; if (idx >= NE*9) return;
  int e = idx/9, j = idx - e*9;
  float s = 0.f;
  const float* rb = rbf + (size_t)e*128;
  for (int r = 0; r < 128; ++r) s += rb[r]*degWr[r*9+j];
  t9[idx] = sh[idx] * silu_f(s);
}

// ---------------- CSR build ----------------
__global__ void hist_kernel(const int* __restrict__ edst, int* counts){
  int e = blockIdx.x*256 + threadIdx.x; if (e < NE) atomicAdd(&counts[edst[e]], 1);
}
__global__ __launch_bounds__(1024) void scan_kernel(const int* __restrict__ counts,
                                                    int* rowptr, int* cursor){
  __shared__ int s[1024];
  int t = threadIdx.x;
  int c0 = counts[2*t], c1 = counts[2*t+1];
  s[t] = c0 + c1;
  __syncthreads();
  for (int off = 1; off < 1024; off <<= 1){
    int v = (t >= off) ? s[t-off] : 0;
    __syncthreads();
    s[t] += v;
    __syncthreads();
  }
  int excl = s[t] - (c0 + c1);
  rowptr[2*t]   = excl;       cursor[2*t]   = excl;
  rowptr[2*t+1] = excl + c0;  cursor[2*t+1] = excl + c0;
  if (t == 1023) rowptr[2048] = s[1023];
}
__global__ void scatter_kernel(const int* __restrict__ edst, int* cursor, int* perm){
  int e = blockIdx.x*256 + threadIdx.x; if (e >= NE) return;
  int p = atomicAdd(&cursor[edst[e]], 1);
  perm[p] = e;
}

// ---------------- inj = atom_table[node_atom] + (sum_e t9) @ degWsh / 16 -----
__global__ __launch_bounds__(64) void inj_kernel(const float* __restrict__ t9,
    const int* __restrict__ rowptr, const int* __restrict__ perm,
    const int* __restrict__ node_atom, const float* __restrict__ atom_table,
    const float* __restrict__ degWsh, float* __restrict__ inj){
  int i = blockIdx.x; int lane = threadIdx.x;
  int b = rowptr[i], e = rowptr[i+1];
  float T[9];
  #pragma unroll
  for (int j = 0; j < 9; ++j) T[j] = 0.f;
  for (int idx = b; idx < e; ++idx){
    int ed = perm[idx];
    #pragma unroll
    for (int j = 0; j < 9; ++j) T[j] += t9[(size_t)ed*9+j];
  }
  int a = node_atom[i];
  for (int c = lane; c < DINJ; c += 64){
    float s = 0.f;
    #pragma unroll
    for (int j = 0; j < 9; ++j) s += T[j]*degWsh[j*DINJ+c];
    inj[(size_t)i*DINJ+c] = atom_table[(size_t)a*DINJ+c] + s*(1.0f/16.0f);
  }
}

// ---------------- zcat = [z | inj] ----------------
__global__ void zcat_kernel(const float* __restrict__ z, const float* __restrict__ inj,
                            float* __restrict__ zc){
  int i = blockIdx.x*256 + threadIdx.x; if (i >= NN*720) return;
  int n = i / 720, d = i - n*720;
  zc[i] = (d < DEMB) ? z[(size_t)n*DEMB + d] : inj[(size_t)n*DINJ + (d - DEMB)];
}

// ------- LayerNorm (fp32 in -> split bf16 hi/lo out, zero-padded to Kpad) ----
__global__ __launch_bounds__(256) void ln_kernel(const float* __restrict__ in, int D,
                                                 int Kpad, ushort_t* __restrict__ oh,
                                                 ushort_t* __restrict__ ol){
  int i = blockIdx.x; int t = threadIdx.x;
  const float* row = in + (size_t)i*D;
  float s = 0.f, sq = 0.f;
  for (int d = t; d < D; d += 256){ float x = row[d]; s += x; sq += x*x; }
  __shared__ float ls[4], lq[4];
  s = wredsum(s); sq = wredsum(sq);
  int lane = t & 63, w = t >> 6;
  if (lane == 0){ ls[w] = s; lq[w] = sq; }
  __syncthreads();
  s  = ls[0]+ls[1]+ls[2]+ls[3];
  sq = lq[0]+lq[1]+lq[2]+lq[3];
  float mu = s / (float)D;
  float var = fmaxf(sq / (float)D - mu*mu, 0.f);
  float rs = rsqrtf(var + 1e-6f);
  ushort_t* ohrow = oh + (size_t)i*Kpad;
  ushort_t* olrow = ol + (size_t)i*Kpad;
  for (int d = t; d < D; d += 256){
    float x = (row[d]-mu)*rs;
    ushort_t h = f2b(x);
    ohrow[d] = h;
    olrow[d] = f2b(x - b2f(h));
  }
  for (int d = D + t; d < Kpad; d += 256){ ohrow[d] = 0; olrow[d] = 0; }
}

// -- MFMA GEMM: C = (Ah+Al) * (Bh+Bl)^T, both operands split bf16 (~fp32) -----
// flags: 1 = silu, 2 = add residual R, 4 = write split bf16 (Cbh/Cbl) else fp32
__global__ __launch_bounds__(256) void gemm_bt(const ushort_t* __restrict__ Ah,
    const ushort_t* __restrict__ Al,
    const ushort_t* __restrict__ BTh, const ushort_t* __restrict__ BTl,
    int N, int Kpad,
    float* __restrict__ Cf, ushort_t* __restrict__ Cbh, ushort_t* __restrict__ Cbl,
    const float* __restrict__ R, int flags){
  int lane = threadIdx.x & 63, wave = threadIdx.x >> 6;
  int ntile = blockIdx.x*4 + wave;
  if (ntile*16 >= N) return;
  int row0 = blockIdx.y*16, col0 = ntile*16;
  int m = lane & 15, q4 = lane >> 4;
  const short8* aph = (const short8*)(Ah  + (size_t)(row0+m)*Kpad + q4*8);
  const short8* apl = (const short8*)(Al  + (size_t)(row0+m)*Kpad + q4*8);
  const short8* bph = (const short8*)(BTh + (size_t)(col0+m)*Kpad + q4*8);
  const short8* bpl = (const short8*)(BTl + (size_t)(col0+m)*Kpad + q4*8);
  floatx4 acc = {0.f, 0.f, 0.f, 0.f};
  int steps = Kpad >> 5;
  for (int s = 0; s < steps; ++s){
    short8 ah = aph[s*4];
    short8 al = apl[s*4];
    short8 bh = bph[s*4];
    short8 bl = bpl[s*4];
    acc = __builtin_amdgcn_mfma_f32_16x16x32_bf16(ah, bh, acc, 0, 0, 0);
    acc = __builtin_amdgcn_mfma_f32_16x16x32_bf16(al, bh, acc, 0, 0, 0);
    acc = __builtin_amdgcn_mfma_f32_16x16x32_bf16(ah, bl, acc, 0, 0, 0);
  }
  int col = col0 + m;
  int rowb = row0 + q4*4;
  #pragma unroll
  for (int r = 0; r < 4; ++r){
    size_t idx = (size_t)(rowb + r)*N + col;
    float v = acc[r];
    if (flags & 2) v += R[idx];
    if (flags & 1) v = silu_f(v);
    if (flags & 4){
      ushort_t h = f2b(v);
      Cbh[idx] = h;
      Cbl[idx] = f2b(v - b2f(h));
    } else {
      Cf[idx] = v;
    }
  }
}

// ---------------- per-edge gate r[e][h] and logit[e][h] ----------------
__global__ __launch_bounds__(256) void edge_logit_kernel(
    const float* __restrict__ q, const float* __restrict__ k,
    const float* __restrict__ sh, const float* __restrict__ rbf,
    const float* __restrict__ Wsh, const float* __restrict__ Wr,
    const int* __restrict__ esrc, const int* __restrict__ edst,
    float* __restrict__ r_out, float* __restrict__ logit){
  int e = blockIdx.x*4 + (threadIdx.x >> 6);
  int lane = threadIdx.x & 63;
  int s = esrc[e], dd = edst[e];
  float rb1 = rbf[(size_t)e*128 + lane], rb2 = rbf[(size_t)e*128 + 64 + lane];
  float shj[9];
  #pragma unroll
  for (int j = 0; j < 9; ++j) shj[j] = sh[(size_t)e*9 + j];
  float rh[4];
  #pragma unroll
  for (int h = 0; h < 4; ++h){
    float p = rb1*Wr[lane*4+h] + rb2*Wr[(lane+64)*4+h];
    p = wredsum(p);
    rh[h] = silu_f(p);
  }
  if (lane == 0){
    r_out[e*4+0] = rh[0]; r_out[e*4+1] = rh[1];
    r_out[e*4+2] = rh[2]; r_out[e*4+3] = rh[3];
  }
  const float inv = 0.091287092917527686f; // 1/sqrt(120)
  #pragma unroll
  for (int h = 0; h < 4; ++h){
    float partial = 0.f;
    for (int d0 = lane; d0 < 120; d0 += 64){
      int d = h*120 + d0;
      float mm = 0.f;
      #pragma unroll
      for (int j = 0; j < 9; ++j) mm += shj[j]*Wsh[j*DEMB + d];
      partial += q[(size_t)dd*DEMB + d] * (k[(size_t)s*DEMB + d] + mm);
    }
    partial = wredsum(partial);
    if (lane == 0) logit[e*4+h] = rh[h]*partial*inv;
  }
}

// ------- per-node softmax + aggregation -> agg (split bf16 hi/lo) ------------
#define CHUNK 128
__global__ __launch_bounds__(128) void node_attn_kernel(
    const float* __restrict__ logit, const float* __restrict__ r_e,
    const float* __restrict__ v, const float* __restrict__ sh,
    const float* __restrict__ Wsh,
    const int* __restrict__ rowptr, const int* __restrict__ perm,
    const int* __restrict__ esrc, ushort_t* __restrict__ aggh,
    ushort_t* __restrict__ aggl){
  int i = blockIdx.x; int t = threadIdx.x;
  int b = rowptr[i], en = rowptr[i+1]; int deg = en - b;
  __shared__ float mxs[4], dens[4], S[4][9];
  __shared__ float wbuf[CHUNK][4];
  __shared__ int srcbuf[CHUNK];
  if (t < 4){
    float mx = -1e30f;
    for (int idx = 0; idx < deg; ++idx){
      int e = perm[b+idx]; mx = fmaxf(mx, logit[e*4+t]);
    }
    if (deg == 0) mx = 0.f;
    float den = 0.f;
    for (int idx = 0; idx < deg; ++idx){
      int e = perm[b+idx]; den += __expf(logit[e*4+t]-mx);
    }
    mxs[t] = mx; dens[t] = den + 1e-9f;
  }
  __syncthreads();
  if (t < 36){
    int h = t/9, j = t - h*9;
    float a = 0.f;
    for (int idx = 0; idx < deg; ++idx){
      int e = perm[b+idx];
      float w = __expf(logit[e*4+h]-mxs[h]) / dens[h] * r_e[e*4+h];
      a += w * sh[(size_t)e*9+j];
    }
    S[h][j] = a;
  }
  __syncthreads();
  float acc[4] = {0.f, 0.f, 0.f, 0.f};
  for (int c0 = 0; c0 < deg; c0 += CHUNK){
    int cn = min(CHUNK, deg - c0);
    if (t < cn){
      int e = perm[b + c0 + t];
      #pragma unroll
      for (int h = 0; h < 4; ++h)
        wbuf[t][h] = __expf(logit[e*4+h]-mxs[h]) / dens[h] * r_e[e*4+h];
      srcbuf[t] = esrc[e];
    }
    __syncthreads();
    #pragma unroll
    for (int rseg = 0; rseg < 4; ++rseg){
      int d = t + rseg*128;
      if (d < DEMB){
        int h = d/120;
        float a = acc[rseg];
        for (int le = 0; le < cn; ++le)
          a += wbuf[le][h] * v[(size_t)srcbuf[le]*DEMB + d];
        acc[rseg] = a;
      }
    }
    __syncthreads();
  }
  #pragma unroll
  for (int rseg = 0; rseg < 4; ++rseg){
    int d = t + rseg*128;
    if (d < DEMB){
      int h = d/120;
      float mm = 0.f;
      #pragma unroll
      for (int j = 0; j < 9; ++j) mm += S[h][j]*Wsh[j*DEMB + d];
      float x = acc[rseg] + mm;
      ushort_t hh = f2b(x);
      aggh[(size_t)i*DEMB + d] = hh;
      aggl[(size_t)i*DEMB + d] = f2b(x - b2f(hh));
    }
  }
}

// ---------------- head ----------------
__global__ __launch_bounds__(256) void head_dot_kernel(const ushort_t* __restrict__ g1h,
    const ushort_t* __restrict__ g1l,
    const float* __restrict__ hW2, const int* __restrict__ batch, float* gsum){
  int i = blockIdx.x*4 + (threadIdx.x >> 6);
  int lane = threadIdx.x & 63;
  float s = 0.f;
  for (int d = lane; d < DFEAT; d += 64)
    s += (b2f(g1h[(size_t)i*DFEAT + d]) + b2f(g1l[(size_t)i*DFEAT + d])) * hW2[d];
  s = wredsum(s);
  if (lane == 0) atomicAdd(&gsum[batch[i]], s);
}
__global__ void finalize_kernel(const float* __restrict__ gsum,
                                const int* __restrict__ flag, void* out){
  int g = threadIdx.x;
  if (g < NG){
    float v = gsum[g] * 0.17677669529663687f; // 1/sqrt(32)
    if (*flag) ((float*)out)[g] = v;
    else       ((ushort_t*)out)[g] = f2b(v);
  }
}

// =====================================================================
extern "C" void kernel_launch(void* const* d_in, const int* in_sizes, int n_in,
                              void* d_out, int out_size, void* d_ws, size_t ws_size,
                              hipStream_t stream) {
  (void)in_sizes; (void)n_in; (void)out_size; (void)ws_size;
  const void* pos        = d_in[0];
  const int*  node_atom  = (const int*)d_in[1];
  const int*  esrc       = (const int*)d_in[2];
  const int*  edst       = (const int*)d_in[3];
  const int*  batch      = (const int*)d_in[4];
  const void* atom_table = d_in[5];
  const void* degWr      = d_in[6];
  const void* degWsh     = d_in[7];
  const void* b0_Wq  = d_in[8];
  const void* b0_Wk  = d_in[9];
  const void* b0_Wv  = d_in[10];
  const void* b0_Wsh = d_in[11];
  const void* b0_Wr  = d_in[12];
  const void* b0_Wo  = d_in[13];
  const void* b0_F1  = d_in[14];
  const void* b0_F2  = d_in[15];
  const void* bm_Wq  = d_in[16];
  const void* bm_Wk  = d_in[17];
  const void* bm_Wv  = d_in[18];
  const void* bm_Wsh = d_in[19];
  const void* bm_Wr  = d_in[20];
  const void* bm_Wo  = d_in[21];
  const void* bm_F1  = d_in[22];
  const void* bm_F2  = d_in[23];
  const void* bf_Wq  = d_in[24];
  const void* bf_Wk  = d_in[25];
  const void* bf_Wv  = d_in[26];
  const void* bf_Wsh = d_in[27];
  const void* bf_Wr  = d_in[28];
  const void* bf_Wo  = d_in[29];
  const void* bf_F1  = d_in[30];
  const void* bf_F2  = d_in[31];
  const void* hW1    = d_in[32];
  const void* hW2    = d_in[33];

  char* bws = (char*)d_ws;
  size_t off = 0;
  auto alloc = [&](size_t bytes) -> void* {
    void* p = bws + off;
    off += (bytes + 255) & ~(size_t)255;
    return p;
  };
  int* dflag   = (int*)alloc(256);
  float* sh_f  = (float*)alloc((size_t)NE*9*4);
  float* dist  = (float*)alloc((size_t)NE*4);
  float* rbf_f = (float*)alloc((size_t)NE*128*4);
  float* t9    = (float*)alloc((size_t)NE*9*4);
  int* counts  = (int*)alloc(2048*4);
  int* rowptr  = (int*)alloc(2049*4);
  int* cursor  = (int*)alloc(2048*4);
  int* perm    = (int*)alloc((size_t)NE*4);
  float* injb  = (float*)alloc((size_t)NN*DINJ*4);
  float* zA    = (float*)alloc((size_t)NN*512*4);
  float* zB    = (float*)alloc((size_t)NN*512*4);
  float* zcat  = (float*)alloc((size_t)NN*720*4);
  ushort_t* xlnh = (ushort_t*)alloc((size_t)NN*736*2);
  ushort_t* xlnl = (ushort_t*)alloc((size_t)NN*736*2);
  float* qb    = (float*)alloc((size_t)NN*DEMB*4);
  float* kb    = (float*)alloc((size_t)NN*DEMB*4);
  float* vb    = (float*)alloc((size_t)NN*DEMB*4);
  float* r_e   = (float*)alloc((size_t)NE*4*4);
  float* logit = (float*)alloc((size_t)NE*4*4);
  ushort_t* aggh = (ushort_t*)alloc((size_t)NN*DEMB*2);
  ushort_t* aggl = (ushort_t*)alloc((size_t)NN*DEMB*2);
  float* ybuf  = (float*)alloc((size_t)NN*720*4);
  ushort_t* h1h = (ushort_t*)alloc((size_t)NN*DEMB*2);
  ushort_t* h1l = (ushort_t*)alloc((size_t)NN*DEMB*2);
  ushort_t* g1h = (ushort_t*)alloc((size_t)NN*DFEAT*2);
  ushort_t* g1l = (ushort_t*)alloc((size_t)NN*DFEAT*2);
  float* gsum  = (float*)alloc(64*4);

  // fp32 internal copies of small tensors (exact for either input dtype)
  float* pos_c    = (float*)alloc((size_t)NN*3*4);
  float* atom_c   = (float*)alloc((size_t)64*DINJ*4);
  float* degWr_c  = (float*)alloc((size_t)128*9*4);
  float* degWsh_c = (float*)alloc((size_t)9*DINJ*4);
  float* b0_Wsh_c = (float*)alloc((size_t)9*480*4);
  float* b0_Wr_c  = (float*)alloc((size_t)128*4*4);
  float* bm_Wsh_c = (float*)alloc((size_t)4*9*480*4);
  float* bm_Wr_c  = (float*)alloc((size_t)4*128*4*4);
  float* bf_Wsh_c = (float*)alloc((size_t)9*480*4);
  float* bf_Wr_c  = (float*)alloc((size_t)128*4*4);
  float* hW2_c    = (float*)alloc((size_t)512*4);

  // transposed weights (split bf16 hi/lo, M x Kpad)
  auto allocW = [&](size_t elems, ushort_t*& h, ushort_t*& l){
    h = (ushort_t*)alloc(elems*2); l = (ushort_t*)alloc(elems*2);
  };
  ushort_t *b0_WqTh,*b0_WqTl,*b0_WkTh,*b0_WkTl,*b0_WvTh,*b0_WvTl;
  ushort_t *b0_WoTh,*b0_WoTl,*b0_F1Th,*b0_F1Tl,*b0_F2Th,*b0_F2Tl;
  allocW((size_t)480*736, b0_WqTh, b0_WqTl);
  allocW((size_t)480*736, b0_WkTh, b0_WkTl);
  allocW((size_t)480*736, b0_WvTh, b0_WvTl);
  allocW((size_t)720*480, b0_WoTh, b0_WoTl);
  allocW((size_t)480*736, b0_F1Th, b0_F1Tl);
  allocW((size_t)480*480, b0_F2Th, b0_F2Tl);
  ushort_t* bmTh[4][6]; ushort_t* bmTl[4][6];
  for (int i = 0; i < 4; ++i)
    for (int j = 0; j < 6; ++j)
      allocW((size_t)480*480, bmTh[i][j], bmTl[i][j]);
  ushort_t *bf_WqTh,*bf_WqTl,*bf_WkTh,*bf_WkTl,*bf_WvTh,*bf_WvTl;
  ushort_t *bf_WoTh,*bf_WoTl,*bf_F1Th,*bf_F1Tl,*bf_F2Th,*bf_F2Tl,*hW1Th,*hW1Tl;
  allocW((size_t)480*480, bf_WqTh, bf_WqTl);
  allocW((size_t)480*480, bf_WkTh, bf_WkTl);
  allocW((size_t)480*480, bf_WvTh, bf_WvTl);
  allocW((size_t)480*480, bf_WoTh, bf_WoTl);
  allocW((size_t)480*480, bf_F1Th, bf_F1Tl);
  allocW((size_t)512*480, bf_F2Th, bf_F2Tl);
  allocW((size_t)512*512, hW1Th, hW1Tl);

  detect_kernel<<<1, 256, 0, stream>>>((const ushort_t*)atom_table, dflag);

  CDescArr ca;
  int ci = 0;
  auto addC = [&](const void* s, float* d, int n){
    ca.d[ci].src = s; ca.d[ci].dst = d; ca.d[ci].n = n; ++ci;
  };
  addC(pos, pos_c, NN*3);
  addC(atom_table, atom_c, 64*DINJ);
  addC(degWr, degWr_c, 128*9);
  addC(degWsh, degWsh_c, 9*DINJ);
  addC(b0_Wsh, b0_Wsh_c, 9*480);
  addC(b0_Wr, b0_Wr_c, 128*4);
  addC(bm_Wsh, bm_Wsh_c, 4*9*480);
  addC(bm_Wr, bm_Wr_c, 4*128*4);
  addC(bf_Wsh, bf_Wsh_c, 9*480);
  addC(bf_Wr, bf_Wr_c, 128*4);
  addC(hW2, hW2_c, 512);
  convert_inputs<<<dim3(8, 11), 256, 0, stream>>>(ca, dflag);

  TDescArr ta;
  int ti = 0;
  auto addT = [&](const void* s, ushort_t* dh, ushort_t* dl, int K, int M, int Kp, int eo){
    ta.d[ti].src = s; ta.d[ti].dh = dh; ta.d[ti].dl = dl; ta.d[ti].K = K; ta.d[ti].M = M;
    ta.d[ti].Kpad = Kp; ta.d[ti].eoff = eo; ++ti;
  };
  addT(b0_Wq, b0_WqTh, b0_WqTl, 720, 480, 736, 0);
  addT(b0_Wk, b0_WkTh, b0_WkTl, 720, 480, 736, 0);
  addT(b0_Wv, b0_WvTh, b0_WvTl, 720, 480, 736, 0);
  addT(b0_Wo, b0_WoTh, b0_WoTl, 480, 720, 480, 0);
  addT(b0_F1, b0_F1Th, b0_F1Tl, 720, 480, 736, 0);
  addT(b0_F2, b0_F2Th, b0_F2Tl, 480, 480, 480, 0);
  for (int i = 0; i < 4; ++i){
    int eo = i*480*480;
    addT(bm_Wq, bmTh[i][0], bmTl[i][0], 480, 480, 480, eo);
    addT(bm_Wk, bmTh[i][1], bmTl[i][1], 480, 480, 480, eo);
    addT(bm_Wv, bmTh[i][2], bmTl[i][2], 480, 480, 480, eo);
    addT(bm_Wo, bmTh[i][3], bmTl[i][3], 480, 480, 480, eo);
    addT(bm_F1, bmTh[i][4], bmTl[i][4], 480, 480, 480, eo);
    addT(bm_F2, bmTh[i][5], bmTl[i][5], 480, 480, 480, eo);
  }
  addT(bf_Wq, bf_WqTh, bf_WqTl, 480, 480, 480, 0);
  addT(bf_Wk, bf_WkTh, bf_WkTl, 480, 480, 480, 0);
  addT(bf_Wv, bf_WvTh, bf_WvTl, 480, 480, 480, 0);
  addT(bf_Wo, bf_WoTh, bf_WoTl, 480, 480, 480, 0);
  addT(bf_F1, bf_F1Th, bf_F1Tl, 480, 480, 480, 0);
  addT(bf_F2, bf_F2Th, bf_F2Tl, 480, 512, 480, 0);
  addT(hW1,   hW1Th,   hW1Tl,   512, 512, 512, 0);
  transpose_all<<<dim3(64, 37), 256, 0, stream>>>(ta, dflag);

  geom_kernel<<<NE/256, 256, 0, stream>>>(pos_c, esrc, edst, sh_f, dist);
  rbf_kernel<<<(NE*128)/256, 256, 0, stream>>>(dist, rbf_f);
  t9_kernel<<<(NE*9 + 255)/256, 256, 0, stream>>>(rbf_f, sh_f, degWr_c, t9);

  zero_f32<<<(2048 + 255)/256, 256, 0, stream>>>((float*)counts, 2048);
  hist_kernel<<<NE/256, 256, 0, stream>>>(edst, counts);
  scan_kernel<<<1, 1024, 0, stream>>>(counts, rowptr, cursor);
  scatter_kernel<<<NE/256, 256, 0, stream>>>(edst, cursor, perm);

  inj_kernel<<<NN, 64, 0, stream>>>(t9, rowptr, perm, node_atom, atom_c, degWsh_c, injb);
  zero_f32<<<(NN*DEMB)/256, 256, 0, stream>>>(zA, NN*DEMB);

  auto gemm = [&](const ushort_t* Ah, const ushort_t* Al,
                  const ushort_t* BTh, const ushort_t* BTl,
                  int N, int Kp, float* Cf, ushort_t* Cbh, ushort_t* Cbl,
                  const float* R, int flags){
    int nt = (N/16 + 3)/4;
    gemm_bt<<<dim3(nt, 128), 256, 0, stream>>>(Ah, Al, BTh, BTl, N, Kp, Cf, Cbh, Cbl, R, flags);
  };

  struct BW {
    const float *Wsh, *Wr;
    const ushort_t *WqTh,*WqTl,*WkTh,*WkTl,*WvTh,*WvTl,*WoTh,*WoTl,*F1Th,*F1Tl,*F2Th,*F2Tl;
    int Din, Kpad, Dout; bool res;
  };
  auto run_block = [&](const BW& bw, const float* zin, float* zout){
    ln_kernel<<<NN, 256, 0, stream>>>(zin, bw.Din, bw.Kpad, xlnh, xlnl);
    gemm(xlnh, xlnl, bw.WqTh, bw.WqTl, DEMB, bw.Kpad, qb, nullptr, nullptr, nullptr, 0);
    gemm(xlnh, xlnl, bw.WkTh, bw.WkTl, DEMB, bw.Kpad, kb, nullptr, nullptr, nullptr, 0);
    gemm(xlnh, xlnl, bw.WvTh, bw.WvTl, DEMB, bw.Kpad, vb, nullptr, nullptr, nullptr, 0);
    edge_logit_kernel<<<NE/4, 256, 0, stream>>>(qb, kb, sh_f, rbf_f, bw.Wsh, bw.Wr,
                                                esrc, edst, r_e, logit);
    node_attn_kernel<<<NN, 128, 0, stream>>>(logit, r_e, vb, sh_f, bw.Wsh,
                                             rowptr, perm, esrc, aggh, aggl);
    gemm(aggh, aggl, bw.WoTh, bw.WoTl, bw.Din, 480, ybuf, nullptr, nullptr, zin, 2);
    ln_kernel<<<NN, 256, 0, stream>>>(ybuf, bw.Din, bw.Kpad, xlnh, xlnl);
    gemm(xlnh, xlnl, bw.F1Th, bw.F1Tl, DEMB, bw.Kpad, nullptr, h1h, h1l, nullptr, 1|4);
    gemm(h1h, h1l, bw.F2Th, bw.F2Tl, bw.Dout, 480, zout, nullptr, nullptr,
         bw.res ? ybuf : nullptr, bw.res ? 2 : 0);
  };

  BW b0 = { b0_Wsh_c, b0_Wr_c,
            b0_WqTh,b0_WqTl,b0_WkTh,b0_WkTl,b0_WvTh,b0_WvTl,
            b0_WoTh,b0_WoTl,b0_F1Th,b0_F1Tl,b0_F2Th,b0_F2Tl,
            720, 736, 480, false };
  BW bm[4];
  for (int i = 0; i < 4; ++i){
    bm[i] = { bm_Wsh_c + (size_t)i*9*480, bm_Wr_c + (size_t)i*128*4,
              bmTh[i][0],bmTl[i][0],bmTh[i][1],bmTl[i][1],bmTh[i][2],bmTl[i][2],
              bmTh[i][3],bmTl[i][3],bmTh[i][4],bmTl[i][4],bmTh[i][5],bmTl[i][5],
              480, 480, 480, true };
  }
  BW bf = { bf_Wsh_c, bf_Wr_c,
            bf_WqTh,bf_WqTl,bf_WkTh,bf_WkTl,bf_WvTh,bf_WvTl,
            bf_WoTh,bf_WoTl,bf_F1Th,bf_F1Tl,bf_F2Th,bf_F2Tl,
            480, 480, 512, false };

  float* z  = zA;
  float* z2 = zB;
  for (int iter = 0; iter < 2; ++iter){
    zcat_kernel<<<(NN*720)/256, 256, 0, stream>>>(z, injb, zcat);
    run_block(b0, zcat, z2);
    { float* tmp = z; z = z2; z2 = tmp; }
    for (int i = 0; i < 4; ++i){
      run_block(bm[i], z, z2);
      { float* tmp = z; z = z2; z2 = tmp; }
    }
  }
  run_block(bf, z, z2);
  ln_kernel<<<NN, 256, 0, stream>>>(z2, DFEAT, DFEAT, xlnh, xlnl);
  gemm(xlnh, xlnl, hW1Th, hW1Tl, DFEAT, DFEAT, nullptr, g1h, g1l, nullptr, 1|4);
  zero_f32<<<1, 64, 0, stream>>>(gsum, 64);
  head_dot_kernel<<<NN/4, 256, 0, stream>>>(g1h, g1l, hW2_c, batch, gsum);
  finalize_kernel<<<1, 64, 0, stream>>>(gsum, dflag, d_out);
}

// Round 5
// 2279.375 us; speedup vs baseline: 1.1382x; 1.1382x over previous
//
#include <hip/hip_runtime.h>

#define NN 2048
#define NE 32768
#define NG 64
#define DINJ 240
#define DEMB 480
#define DFEAT 512

typedef unsigned short ushort_t;
typedef __attribute__((ext_vector_type(8))) short short8;
typedef __attribute__((ext_vector_type(4))) float floatx4;

__device__ __forceinline__ float b2f(ushort_t u){
  union { unsigned u; float f; } x; x.u = ((unsigned)u) << 16; return x.f;
}
__device__ __forceinline__ ushort_t f2b(float f){
  union { float f; unsigned u; } x; x.f = f;
  unsigned r = x.u + 0x7FFFu + ((x.u >> 16) & 1u);
  return (ushort_t)(r >> 16);
}
__device__ __forceinline__ float wredsum(float v){
  #pragma unroll
  for (int o = 32; o > 0; o >>= 1) v += __shfl_xor(v, o, 64);
  return v;
}
__device__ __forceinline__ float silu_f(float x){ return x / (1.f + __expf(-x)); }

// ---------------- small utility kernels ----------------
__global__ void zero_f32(float* p, int n){
  int i = blockIdx.x*256 + threadIdx.x; if (i < n) p[i] = 0.f;
}

// ---------------- input dtype detection ----------------
// flag=0: float inputs are bf16; flag=1: they are fp32.
__global__ void detect_kernel(const ushort_t* __restrict__ probe, int* flag){
  __shared__ int c;
  if (threadIdx.x == 0) c = 0;
  __syncthreads();
  ushort_t u = probe[2*threadIdx.x];
  int e = (u >> 7) & 0xFF;
  int plausible = (u == 0) || (e >= 100 && e <= 140);
  atomicAdd(&c, plausible);
  __syncthreads();
  if (threadIdx.x == 0) *flag = (c >= 192) ? 0 : 1;
}

// -------- convert small float inputs -> internal FP32 (exact either way) ----
struct CDesc { const void* src; float* dst; int n; };
struct CDescArr { CDesc d[11]; };
__global__ __launch_bounds__(256) void convert_inputs(CDescArr ca, const int* __restrict__ flag){
  CDesc cd = ca.d[blockIdx.y];
  int isf32 = *flag;
  for (int i = blockIdx.x*256 + threadIdx.x; i < cd.n; i += gridDim.x*256){
    cd.dst[i] = isf32 ? ((const float*)cd.src)[i] : b2f(((const ushort_t*)cd.src)[i]);
  }
}

// --- LDS-tiled weight transpose: src (K x M row-major) -> dst (Mpad x Kpad) --
// split bf16 hi/lo, zero-padded rows [M,Mpad) and cols [K,Kpad).
struct TDesc { const void* src; ushort_t* dh; ushort_t* dl; int K; int M; int Kpad; int Mpad; int eoff; };
struct TDescArr { TDesc d[37]; };
__global__ __launch_bounds__(256) void transpose_all(TDescArr ta, const int* __restrict__ flag){
  TDesc td = ta.d[blockIdx.z];
  int k0 = blockIdx.x*32, m0 = blockIdx.y*32;
  if (k0 >= td.Kpad || m0 >= td.Mpad) return;
  int isf32 = *flag;
  __shared__ float lds[32*33];
  int tx = threadIdx.x & 31, ty = threadIdx.x >> 5;
  // read phase: coalesced over m (tx)
  #pragma unroll
  for (int r = 0; r < 4; ++r){
    int kl = ty + r*8;
    int k = k0 + kl, mm = m0 + tx;
    float x = 0.f;
    if (k < td.K && mm < td.M){
      size_t si = (size_t)td.eoff + (size_t)k*td.M + mm;
      x = isf32 ? ((const float*)td.src)[si] : b2f(((const ushort_t*)td.src)[si]);
    }
    lds[kl*33 + tx] = x;
  }
  __syncthreads();
  // write phase: coalesced over k (tx)
  #pragma unroll
  for (int r = 0; r < 4; ++r){
    int nl = ty + r*8;
    int n = m0 + nl, k = k0 + tx;
    if (n < td.Mpad && k < td.Kpad){
      float x = lds[tx*33 + nl];
      ushort_t h = f2b(x);
      size_t di = (size_t)n*td.Kpad + k;
      td.dh[di] = h;
      td.dl[di] = f2b(x - b2f(h));
    }
  }
}

// ---------------- geometry (fp32 pos) ----------------
__global__ void geom_kernel(const float* __restrict__ pos,
                            const int* __restrict__ esrc, const int* __restrict__ edst,
                            float* __restrict__ sh, float* __restrict__ dist){
  int e = blockIdx.x*256 + threadIdx.x; if (e >= NE) return;
  int s = esrc[e], d = edst[e];
  float x = pos[s*3+0] - pos[d*3+0];
  float y = pos[s*3+1] - pos[d*3+1];
  float z = pos[s*3+2] - pos[d*3+2];
  float dd = sqrtf(x*x + y*y + z*z + 1e-12f);
  float ix = x/dd, iy = y/dd, iz = z/dd;
  const float s3 = 1.7320508075688772f, s15 = 3.872983346207417f, s5 = 2.23606797749979f;
  float* o = sh + (size_t)e*9;
  o[0] = 1.f; o[1] = s3*ix; o[2] = s3*iy; o[3] = s3*iz;
  o[4] = s15*ix*iy; o[5] = s15*iy*iz; o[6] = 0.5f*s5*(3.f*iz*iz - 1.f);
  o[7] = s15*ix*iz; o[8] = 0.5f*s15*(ix*ix - iy*iy);
  dist[e] = dd;
}

__global__ void rbf_kernel(const float* __restrict__ dist, float* __restrict__ rbf){
  int idx = blockIdx.x*256 + threadIdx.x; if (idx >= NE*128) return;
  int e = idx >> 7, r = idx & 127;
  float c = (float)r * (5.0f/127.0f);
  float u = (dist[e] - c) * (128.0f/5.0f);
  rbf[idx] = __expf(-0.5f*u*u);
}

__global__ void t9_kernel(const float* __restrict__ rbf, const float* __restrict__ sh,
                          const float* __restrict__ degWr, float* __restrict__ t9){
  int idx = blockIdx.x*256 + threadIdx.x; if (idx >= NE*9) return;
  int e = idx/9, j = idx - e*9;
  float s = 0.f;
  const float* rb = rbf + (size_t)e*128;
  for (int r = 0; r < 128; ++r) s += rb[r]*degWr[r*9+j];
  t9[idx] = sh[idx] * silu_f(s);
}

// ---------------- CSR build ----------------
__global__ void hist_kernel(const int* __restrict__ edst, int* counts){
  int e = blockIdx.x*256 + threadIdx.x; if (e < NE) atomicAdd(&counts[edst[e]], 1);
}
__global__ __launch_bounds__(1024) void scan_kernel(const int* __restrict__ counts,
                                                    int* rowptr, int* cursor){
  __shared__ int s[1024];
  int t = threadIdx.x;
  int c0 = counts[2*t], c1 = counts[2*t+1];
  s[t] = c0 + c1;
  __syncthreads();
  for (int off = 1; off < 1024; off <<= 1){
    int v = (t >= off) ? s[t-off] : 0;
    __syncthreads();
    s[t] += v;
    __syncthreads();
  }
  int excl = s[t] - (c0 + c1);
  rowptr[2*t]   = excl;       cursor[2*t]   = excl;
  rowptr[2*t+1] = excl + c0;  cursor[2*t+1] = excl + c0;
  if (t == 1023) rowptr[2048] = s[1023];
}
__global__ void scatter_kernel(const int* __restrict__ edst, int* cursor, int* perm){
  int e = blockIdx.x*256 + threadIdx.x; if (e >= NE) return;
  int p = atomicAdd(&cursor[edst[e]], 1);
  perm[p] = e;
}

// ---------------- inj = atom_table[node_atom] + (sum_e t9) @ degWsh / 16 -----
__global__ __launch_bounds__(64) void inj_kernel(const float* __restrict__ t9,
    const int* __restrict__ rowptr, const int* __restrict__ perm,
    const int* __restrict__ node_atom, const float* __restrict__ atom_table,
    const float* __restrict__ degWsh, float* __restrict__ inj){
  int i = blockIdx.x; int lane = threadIdx.x;
  int b = rowptr[i], e = rowptr[i+1];
  float T[9];
  #pragma unroll
  for (int j = 0; j < 9; ++j) T[j] = 0.f;
  for (int idx = b; idx < e; ++idx){
    int ed = perm[idx];
    #pragma unroll
    for (int j = 0; j < 9; ++j) T[j] += t9[(size_t)ed*9+j];
  }
  int a = node_atom[i];
  for (int c = lane; c < DINJ; c += 64){
    float s = 0.f;
    #pragma unroll
    for (int j = 0; j < 9; ++j) s += T[j]*degWsh[j*DINJ+c];
    inj[(size_t)i*DINJ+c] = atom_table[(size_t)a*DINJ+c] + s*(1.0f/16.0f);
  }
}

// ---------------- zcat = [z | inj] ----------------
__global__ void zcat_kernel(const float* __restrict__ z, const float* __restrict__ inj,
                            float* __restrict__ zc){
  int i = blockIdx.x*256 + threadIdx.x; if (i >= NN*720) return;
  int n = i / 720, d = i - n*720;
  zc[i] = (d < DEMB) ? z[(size_t)n*DEMB + d] : inj[(size_t)n*DINJ + (d - DEMB)];
}

// ------- LayerNorm (fp32 in -> split bf16 hi/lo out, zero-padded to Kpad) ----
__global__ __launch_bounds__(256) void ln_kernel(const float* __restrict__ in, int D,
                                                 int Kpad, ushort_t* __restrict__ oh,
                                                 ushort_t* __restrict__ ol){
  int i = blockIdx.x; int t = threadIdx.x;
  const float* row = in + (size_t)i*D;
  float s = 0.f, sq = 0.f;
  for (int d = t; d < D; d += 256){ float x = row[d]; s += x; sq += x*x; }
  __shared__ float ls[4], lq[4];
  s = wredsum(s); sq = wredsum(sq);
  int lane = t & 63, w = t >> 6;
  if (lane == 0){ ls[w] = s; lq[w] = sq; }
  __syncthreads();
  s  = ls[0]+ls[1]+ls[2]+ls[3];
  sq = lq[0]+lq[1]+lq[2]+lq[3];
  float mu = s / (float)D;
  float var = fmaxf(sq / (float)D - mu*mu, 0.f);
  float rs = rsqrtf(var + 1e-6f);
  ushort_t* ohrow = oh + (size_t)i*Kpad;
  ushort_t* olrow = ol + (size_t)i*Kpad;
  for (int d = t; d < D; d += 256){
    float x = (row[d]-mu)*rs;
    ushort_t h = f2b(x);
    ohrow[d] = h;
    olrow[d] = f2b(x - b2f(h));
  }
  for (int d = D + t; d < Kpad; d += 256){ ohrow[d] = 0; olrow[d] = 0; }
}

// -- MFMA GEMM: C = (Ah+Al)*(Bh+Bl)^T. 64x64 block tile, 32x32 per wave as
//    2x2 of verified 16x16x32 fragments. BT is Npad x Kpad (zero-padded).
// flags: 1 = silu, 2 = add residual R (ldc-strided), 4 = split bf16 out
__global__ __launch_bounds__(256) void gemm_bt(
    const ushort_t* __restrict__ Ah, const ushort_t* __restrict__ Al,
    const ushort_t* __restrict__ BTh, const ushort_t* __restrict__ BTl,
    int N, int Kpad, int ldc,
    float* __restrict__ Cf, ushort_t* __restrict__ Cbh, ushort_t* __restrict__ Cbl,
    const float* __restrict__ R, int flags){
  int lane = threadIdx.x & 63, wave = threadIdx.x >> 6;
  int row0 = blockIdx.y*64 + (wave>>1)*32;
  int col0 = blockIdx.x*64 + (wave&1)*32;
  int m = lane & 15, q4 = lane >> 4;
  size_t a0 = (size_t)(row0+m)*Kpad + q4*8;
  size_t a1 = a0 + (size_t)16*Kpad;
  size_t b0 = (size_t)(col0+m)*Kpad + q4*8;
  size_t b1 = b0 + (size_t)16*Kpad;
  floatx4 acc00 = {0,0,0,0}, acc01 = {0,0,0,0}, acc10 = {0,0,0,0}, acc11 = {0,0,0,0};
  int steps = Kpad >> 5;
  for (int s = 0; s < steps; ++s){
    size_t o = (size_t)s*32;
    short8 A0h = *(const short8*)(Ah + a0 + o);
    short8 A0l = *(const short8*)(Al + a0 + o);
    short8 A1h = *(const short8*)(Ah + a1 + o);
    short8 A1l = *(const short8*)(Al + a1 + o);
    short8 B0h = *(const short8*)(BTh + b0 + o);
    short8 B0l = *(const short8*)(BTl + b0 + o);
    short8 B1h = *(const short8*)(BTh + b1 + o);
    short8 B1l = *(const short8*)(BTl + b1 + o);
    acc00 = __builtin_amdgcn_mfma_f32_16x16x32_bf16(A0h, B0h, acc00, 0, 0, 0);
    acc00 = __builtin_amdgcn_mfma_f32_16x16x32_bf16(A0l, B0h, acc00, 0, 0, 0);
    acc00 = __builtin_amdgcn_mfma_f32_16x16x32_bf16(A0h, B0l, acc00, 0, 0, 0);
    acc01 = __builtin_amdgcn_mfma_f32_16x16x32_bf16(A0h, B1h, acc01, 0, 0, 0);
    acc01 = __builtin_amdgcn_mfma_f32_16x16x32_bf16(A0l, B1h, acc01, 0, 0, 0);
    acc01 = __builtin_amdgcn_mfma_f32_16x16x32_bf16(A0h, B1l, acc01, 0, 0, 0);
    acc10 = __builtin_amdgcn_mfma_f32_16x16x32_bf16(A1h, B0h, acc10, 0, 0, 0);
    acc10 = __builtin_amdgcn_mfma_f32_16x16x32_bf16(A1l, B0h, acc10, 0, 0, 0);
    acc10 = __builtin_amdgcn_mfma_f32_16x16x32_bf16(A1h, B0l, acc10, 0, 0, 0);
    acc11 = __builtin_amdgcn_mfma_f32_16x16x32_bf16(A1h, B1h, acc11, 0, 0, 0);
    acc11 = __builtin_amdgcn_mfma_f32_16x16x32_bf16(A1l, B1h, acc11, 0, 0, 0);
    acc11 = __builtin_amdgcn_mfma_f32_16x16x32_bf16(A1h, B1l, acc11, 0, 0, 0);
  }
  #pragma unroll
  for (int rr = 0; rr < 2; ++rr){
    #pragma unroll
    for (int cc = 0; cc < 2; ++cc){
      int col = col0 + cc*16 + m;
      if (col >= N) continue;
      floatx4 acc = rr ? (cc ? acc11 : acc10) : (cc ? acc01 : acc00);
      int rowb = row0 + rr*16 + q4*4;
      #pragma unroll
      for (int r = 0; r < 4; ++r){
        size_t idx = (size_t)(rowb + r)*ldc + col;
        float v = acc[r];
        if (flags & 2) v += R[idx];
        if (flags & 1) v = silu_f(v);
        if (flags & 4){
          ushort_t h = f2b(v);
          Cbh[idx] = h;
          Cbl[idx] = f2b(v - b2f(h));
        } else {
          Cf[idx] = v;
        }
      }
    }
  }
}

// ---------------- per-edge gate r[e][h] and logit[e][h] ----------------
// qkv layout: per node 1440 floats = [q(480) | k(480) | v(480)]
__global__ __launch_bounds__(256) void edge_logit_kernel(
    const float* __restrict__ qkv,
    const float* __restrict__ sh, const float* __restrict__ rbf,
    const float* __restrict__ Wsh, const float* __restrict__ Wr,
    const int* __restrict__ esrc, const int* __restrict__ edst,
    float* __restrict__ r_out, float* __restrict__ logit){
  int e = blockIdx.x*4 + (threadIdx.x >> 6);
  int lane = threadIdx.x & 63;
  int s = esrc[e], dd = edst[e];
  float rb1 = rbf[(size_t)e*128 + lane], rb2 = rbf[(size_t)e*128 + 64 + lane];
  float shj[9];
  #pragma unroll
  for (int j = 0; j < 9; ++j) shj[j] = sh[(size_t)e*9 + j];
  float rh[4];
  #pragma unroll
  for (int h = 0; h < 4; ++h){
    float p = rb1*Wr[lane*4+h] + rb2*Wr[(lane+64)*4+h];
    p = wredsum(p);
    rh[h] = silu_f(p);
  }
  if (lane == 0){
    r_out[e*4+0] = rh[0]; r_out[e*4+1] = rh[1];
    r_out[e*4+2] = rh[2]; r_out[e*4+3] = rh[3];
  }
  const float* qrow = qkv + (size_t)dd*1440;
  const float* krow = qkv + (size_t)s*1440 + 480;
  const float inv = 0.091287092917527686f; // 1/sqrt(120)
  #pragma unroll
  for (int h = 0; h < 4; ++h){
    float partial = 0.f;
    for (int d0 = lane; d0 < 120; d0 += 64){
      int d = h*120 + d0;
      float mm = 0.f;
      #pragma unroll
      for (int j = 0; j < 9; ++j) mm += shj[j]*Wsh[j*DEMB + d];
      partial += qrow[d] * (krow[d] + mm);
    }
    partial = wredsum(partial);
    if (lane == 0) logit[e*4+h] = rh[h]*partial*inv;
  }
}

// ------- per-node softmax + aggregation -> agg (split bf16 hi/lo) ------------
#define CHUNK 128
__global__ __launch_bounds__(128) void node_attn_kernel(
    const float* __restrict__ logit, const float* __restrict__ r_e,
    const float* __restrict__ qkv, const float* __restrict__ sh,
    const float* __restrict__ Wsh,
    const int* __restrict__ rowptr, const int* __restrict__ perm,
    const int* __restrict__ esrc, ushort_t* __restrict__ aggh,
    ushort_t* __restrict__ aggl){
  int i = blockIdx.x; int t = threadIdx.x;
  int b = rowptr[i], en = rowptr[i+1]; int deg = en - b;
  __shared__ float mxs[4], dens[4], S[4][9];
  __shared__ float wbuf[CHUNK][4];
  __shared__ int srcbuf[CHUNK];
  if (t < 4){
    float mx = -1e30f;
    for (int idx = 0; idx < deg; ++idx){
      int e = perm[b+idx]; mx = fmaxf(mx, logit[e*4+t]);
    }
    if (deg == 0) mx = 0.f;
    float den = 0.f;
    for (int idx = 0; idx < deg; ++idx){
      int e = perm[b+idx]; den += __expf(logit[e*4+t]-mx);
    }
    mxs[t] = mx; dens[t] = den + 1e-9f;
  }
  __syncthreads();
  if (t < 36){
    int h = t/9, j = t - h*9;
    float a = 0.f;
    for (int idx = 0; idx < deg; ++idx){
      int e = perm[b+idx];
      float w = __expf(logit[e*4+h]-mxs[h]) / dens[h] * r_e[e*4+h];
      a += w * sh[(size_t)e*9+j];
    }
    S[h][j] = a;
  }
  __syncthreads();
  float acc[4] = {0.f, 0.f, 0.f, 0.f};
  for (int c0 = 0; c0 < deg; c0 += CHUNK){
    int cn = min(CHUNK, deg - c0);
    if (t < cn){
      int e = perm[b + c0 + t];
      #pragma unroll
      for (int h = 0; h < 4; ++h)
        wbuf[t][h] = __expf(logit[e*4+h]-mxs[h]) / dens[h] * r_e[e*4+h];
      srcbuf[t] = esrc[e];
    }
    __syncthreads();
    #pragma unroll
    for (int rseg = 0; rseg < 4; ++rseg){
      int d = t + rseg*128;
      if (d < DEMB){
        int h = d/120;
        float a = acc[rseg];
        for (int le = 0; le < cn; ++le)
          a += wbuf[le][h] * qkv[(size_t)srcbuf[le]*1440 + 960 + d];
        acc[rseg] = a;
      }
    }
    __syncthreads();
  }
  #pragma unroll
  for (int rseg = 0; rseg < 4; ++rseg){
    int d = t + rseg*128;
    if (d < DEMB){
      int h = d/120;
      float mm = 0.f;
      #pragma unroll
      for (int j = 0; j < 9; ++j) mm += S[h][j]*Wsh[j*DEMB + d];
      float x = acc[rseg] + mm;
      ushort_t hh = f2b(x);
      aggh[(size_t)i*DEMB + d] = hh;
      aggl[(size_t)i*DEMB + d] = f2b(x - b2f(hh));
    }
  }
}

// ---------------- head ----------------
__global__ __launch_bounds__(256) void head_dot_kernel(const ushort_t* __restrict__ g1h,
    const ushort_t* __restrict__ g1l,
    const float* __restrict__ hW2, const int* __restrict__ batch, float* gsum){
  int i = blockIdx.x*4 + (threadIdx.x >> 6);
  int lane = threadIdx.x & 63;
  float s = 0.f;
  for (int d = lane; d < DFEAT; d += 64)
    s += (b2f(g1h[(size_t)i*DFEAT + d]) + b2f(g1l[(size_t)i*DFEAT + d])) * hW2[d];
  s = wredsum(s);
  if (lane == 0) atomicAdd(&gsum[batch[i]], s);
}
__global__ void finalize_kernel(const float* __restrict__ gsum,
                                const int* __restrict__ flag, void* out){
  int g = threadIdx.x;
  if (g < NG){
    float v = gsum[g] * 0.17677669529663687f; // 1/sqrt(32)
    if (*flag) ((float*)out)[g] = v;
    else       ((ushort_t*)out)[g] = f2b(v);
  }
}

// =====================================================================
extern "C" void kernel_launch(void* const* d_in, const int* in_sizes, int n_in,
                              void* d_out, int out_size, void* d_ws, size_t ws_size,
                              hipStream_t stream) {
  (void)in_sizes; (void)n_in; (void)out_size; (void)ws_size;
  const void* pos        = d_in[0];
  const int*  node_atom  = (const int*)d_in[1];
  const int*  esrc       = (const int*)d_in[2];
  const int*  edst       = (const int*)d_in[3];
  const int*  batch      = (const int*)d_in[4];
  const void* atom_table = d_in[5];
  const void* degWr      = d_in[6];
  const void* degWsh     = d_in[7];
  const void* b0_Wq  = d_in[8];
  const void* b0_Wk  = d_in[9];
  const void* b0_Wv  = d_in[10];
  const void* b0_Wsh = d_in[11];
  const void* b0_Wr  = d_in[12];
  const void* b0_Wo  = d_in[13];
  const void* b0_F1  = d_in[14];
  const void* b0_F2  = d_in[15];
  const void* bm_Wq  = d_in[16];
  const void* bm_Wk  = d_in[17];
  const void* bm_Wv  = d_in[18];
  const void* bm_Wsh = d_in[19];
  const void* bm_Wr  = d_in[20];
  const void* bm_Wo  = d_in[21];
  const void* bm_F1  = d_in[22];
  const void* bm_F2  = d_in[23];
  const void* bf_Wq  = d_in[24];
  const void* bf_Wk  = d_in[25];
  const void* bf_Wv  = d_in[26];
  const void* bf_Wsh = d_in[27];
  const void* bf_Wr  = d_in[28];
  const void* bf_Wo  = d_in[29];
  const void* bf_F1  = d_in[30];
  const void* bf_F2  = d_in[31];
  const void* hW1    = d_in[32];
  const void* hW2    = d_in[33];

  char* bws = (char*)d_ws;
  size_t off = 0;
  auto alloc = [&](size_t bytes) -> void* {
    void* p = bws + off;
    off += (bytes + 255) & ~(size_t)255;
    return p;
  };
  int* dflag   = (int*)alloc(256);
  float* sh_f  = (float*)alloc((size_t)NE*9*4);
  float* dist  = (float*)alloc((size_t)NE*4);
  float* rbf_f = (float*)alloc((size_t)NE*128*4);
  float* t9    = (float*)alloc((size_t)NE*9*4);
  int* counts  = (int*)alloc(2048*4);
  int* rowptr  = (int*)alloc(2049*4);
  int* cursor  = (int*)alloc(2048*4);
  int* perm    = (int*)alloc((size_t)NE*4);
  float* injb  = (float*)alloc((size_t)NN*DINJ*4);
  float* zA    = (float*)alloc((size_t)NN*512*4);
  float* zB    = (float*)alloc((size_t)NN*512*4);
  float* zcat  = (float*)alloc((size_t)NN*720*4);
  ushort_t* xlnh = (ushort_t*)alloc((size_t)NN*736*2);
  ushort_t* xlnl = (ushort_t*)alloc((size_t)NN*736*2);
  float* qkvb  = (float*)alloc((size_t)NN*1440*4);
  float* r_e   = (float*)alloc((size_t)NE*4*4);
  float* logit = (float*)alloc((size_t)NE*4*4);
  ushort_t* aggh = (ushort_t*)alloc((size_t)NN*DEMB*2);
  ushort_t* aggl = (ushort_t*)alloc((size_t)NN*DEMB*2);
  float* ybuf  = (float*)alloc((size_t)NN*720*4);
  ushort_t* h1h = (ushort_t*)alloc((size_t)NN*DEMB*2);
  ushort_t* h1l = (ushort_t*)alloc((size_t)NN*DEMB*2);
  ushort_t* g1h = (ushort_t*)alloc((size_t)NN*DFEAT*2);
  ushort_t* g1l = (ushort_t*)alloc((size_t)NN*DFEAT*2);
  float* gsum  = (float*)alloc(64*4);

  // fp32 internal copies of small tensors
  float* pos_c    = (float*)alloc((size_t)NN*3*4);
  float* atom_c   = (float*)alloc((size_t)64*DINJ*4);
  float* degWr_c  = (float*)alloc((size_t)128*9*4);
  float* degWsh_c = (float*)alloc((size_t)9*DINJ*4);
  float* b0_Wsh_c = (float*)alloc((size_t)9*480*4);
  float* b0_Wr_c  = (float*)alloc((size_t)128*4*4);
  float* bm_Wsh_c = (float*)alloc((size_t)4*9*480*4);
  float* bm_Wr_c  = (float*)alloc((size_t)4*128*4*4);
  float* bf_Wsh_c = (float*)alloc((size_t)9*480*4);
  float* bf_Wr_c  = (float*)alloc((size_t)128*4*4);
  float* hW2_c    = (float*)alloc((size_t)512*4);

  // transposed weights (split bf16 hi/lo, Npad x Kpad)
  auto allocW = [&](size_t elems, ushort_t*& h, ushort_t*& l){
    h = (ushort_t*)alloc(elems*2); l = (ushort_t*)alloc(elems*2);
  };
  ushort_t *b0_qkvTh,*b0_qkvTl,*b0_WoTh,*b0_WoTl,*b0_F1Th,*b0_F1Tl,*b0_F2Th,*b0_F2Tl;
  allocW((size_t)1472*736, b0_qkvTh, b0_qkvTl);
  allocW((size_t)768*480,  b0_WoTh,  b0_WoTl);
  allocW((size_t)512*736,  b0_F1Th,  b0_F1Tl);
  allocW((size_t)512*480,  b0_F2Th,  b0_F2Tl);
  ushort_t *bm_qkvTh[4],*bm_qkvTl[4],*bm_WoTh[4],*bm_WoTl[4],*bm_F1Th[4],*bm_F1Tl[4],*bm_F2Th[4],*bm_F2Tl[4];
  for (int i = 0; i < 4; ++i){
    allocW((size_t)1472*480, bm_qkvTh[i], bm_qkvTl[i]);
    allocW((size_t)512*480,  bm_WoTh[i],  bm_WoTl[i]);
    allocW((size_t)512*480,  bm_F1Th[i],  bm_F1Tl[i]);
    allocW((size_t)512*480,  bm_F2Th[i],  bm_F2Tl[i]);
  }
  ushort_t *bf_qkvTh,*bf_qkvTl,*bf_WoTh,*bf_WoTl,*bf_F1Th,*bf_F1Tl,*bf_F2Th,*bf_F2Tl,*hW1Th,*hW1Tl;
  allocW((size_t)1472*480, bf_qkvTh, bf_qkvTl);
  allocW((size_t)512*480,  bf_WoTh,  bf_WoTl);
  allocW((size_t)512*480,  bf_F1Th,  bf_F1Tl);
  allocW((size_t)512*480,  bf_F2Th,  bf_F2Tl);
  allocW((size_t)512*512,  hW1Th,    hW1Tl);

  detect_kernel<<<1, 256, 0, stream>>>((const ushort_t*)atom_table, dflag);

  CDescArr ca;
  int ci = 0;
  auto addC = [&](const void* s, float* d, int n){
    ca.d[ci].src = s; ca.d[ci].dst = d; ca.d[ci].n = n; ++ci;
  };
  addC(pos, pos_c, NN*3);
  addC(atom_table, atom_c, 64*DINJ);
  addC(degWr, degWr_c, 128*9);
  addC(degWsh, degWsh_c, 9*DINJ);
  addC(b0_Wsh, b0_Wsh_c, 9*480);
  addC(b0_Wr, b0_Wr_c, 128*4);
  addC(bm_Wsh, bm_Wsh_c, 4*9*480);
  addC(bm_Wr, bm_Wr_c, 4*128*4);
  addC(bf_Wsh, bf_Wsh_c, 9*480);
  addC(bf_Wr, bf_Wr_c, 128*4);
  addC(hW2, hW2_c, 512);
  convert_inputs<<<dim3(8, 11), 256, 0, stream>>>(ca, dflag);

  TDescArr ta;
  int ti = 0;
  // src KxM -> dst (Mpad x Kpad) at dh/dl (+row offset into fused buffers)
  auto addT = [&](const void* s, ushort_t* dh, ushort_t* dl, int K, int M,
                  int Kp, int Mp, int rowoff, int eo){
    ta.d[ti].src = s;
    ta.d[ti].dh = dh + (size_t)rowoff*Kp;
    ta.d[ti].dl = dl + (size_t)rowoff*Kp;
    ta.d[ti].K = K; ta.d[ti].M = M; ta.d[ti].Kpad = Kp; ta.d[ti].Mpad = Mp;
    ta.d[ti].eoff = eo; ++ti;
  };
  // b0 (K=720 -> Kpad 736)
  addT(b0_Wq, b0_qkvTh, b0_qkvTl, 720, 480, 736, 480, 0,   0);
  addT(b0_Wk, b0_qkvTh, b0_qkvTl, 720, 480, 736, 480, 480, 0);
  addT(b0_Wv, b0_qkvTh, b0_qkvTl, 720, 480, 736, 512, 960, 0);
  addT(b0_Wo, b0_WoTh,  b0_WoTl,  480, 720, 480, 768, 0,   0);
  addT(b0_F1, b0_F1Th,  b0_F1Tl,  720, 480, 736, 512, 0,   0);
  addT(b0_F2, b0_F2Th,  b0_F2Tl,  480, 480, 480, 512, 0,   0);
  for (int i = 0; i < 4; ++i){
    int eo = i*480*480;
    addT(bm_Wq, bm_qkvTh[i], bm_qkvTl[i], 480, 480, 480, 480, 0,   eo);
    addT(bm_Wk, bm_qkvTh[i], bm_qkvTl[i], 480, 480, 480, 480, 480, eo);
    addT(bm_Wv, bm_qkvTh[i], bm_qkvTl[i], 480, 480, 480, 512, 960, eo);
    addT(bm_Wo, bm_WoTh[i],  bm_WoTl[i],  480, 480, 480, 512, 0,   eo);
    addT(bm_F1, bm_F1Th[i],  bm_F1Tl[i],  480, 480, 480, 512, 0,   eo);
    addT(bm_F2, bm_F2Th[i],  bm_F2Tl[i],  480, 480, 480, 512, 0,   eo);
  }
  addT(bf_Wq, bf_qkvTh, bf_qkvTl, 480, 480, 480, 480, 0,   0);
  addT(bf_Wk, bf_qkvTh, bf_qkvTl, 480, 480, 480, 480, 480, 0);
  addT(bf_Wv, bf_qkvTh, bf_qkvTl, 480, 480, 480, 512, 960, 0);
  addT(bf_Wo, bf_WoTh,  bf_WoTl,  480, 480, 480, 512, 0,   0);
  addT(bf_F1, bf_F1Th,  bf_F1Tl,  480, 480, 480, 512, 0,   0);
  addT(bf_F2, bf_F2Th,  bf_F2Tl,  480, 512, 480, 512, 0,   0);
  addT(hW1,   hW1Th,    hW1Tl,    512, 512, 512, 512, 0,   0);
  transpose_all<<<dim3(23, 24, 37), 256, 0, stream>>>(ta, dflag);

  geom_kernel<<<NE/256, 256, 0, stream>>>(pos_c, esrc, edst, sh_f, dist);
  rbf_kernel<<<(NE*128)/256, 256, 0, stream>>>(dist, rbf_f);
  t9_kernel<<<(NE*9 + 255)/256, 256, 0, stream>>>(rbf_f, sh_f, degWr_c, t9);

  zero_f32<<<(2048 + 255)/256, 256, 0, stream>>>((float*)counts, 2048);
  hist_kernel<<<NE/256, 256, 0, stream>>>(edst, counts);
  scan_kernel<<<1, 1024, 0, stream>>>(counts, rowptr, cursor);
  scatter_kernel<<<NE/256, 256, 0, stream>>>(edst, cursor, perm);

  inj_kernel<<<NN, 64, 0, stream>>>(t9, rowptr, perm, node_atom, atom_c, degWsh_c, injb);
  zero_f32<<<(NN*DEMB)/256, 256, 0, stream>>>(zA, NN*DEMB);

  auto gemm = [&](const ushort_t* Ah, const ushort_t* Al,
                  const ushort_t* BTh, const ushort_t* BTl,
                  int N, int Npad, int Kp, int ldc,
                  float* Cf, ushort_t* Cbh, ushort_t* Cbl,
                  const float* R, int flags){
    gemm_bt<<<dim3(Npad/64, 32), 256, 0, stream>>>(Ah, Al, BTh, BTl, N, Kp, ldc,
                                                   Cf, Cbh, Cbl, R, flags);
  };

  struct BW {
    const float *Wsh, *Wr;
    const ushort_t *qkvTh,*qkvTl,*WoTh,*WoTl,*F1Th,*F1Tl,*F2Th,*F2Tl;
    int Din, Kpad, Dout; bool res;
  };
  auto run_block = [&](const BW& bw, const float* zin, float* zout){
    ln_kernel<<<NN, 256, 0, stream>>>(zin, bw.Din, bw.Kpad, xlnh, xlnl);
    gemm(xlnh, xlnl, bw.qkvTh, bw.qkvTl, 1440, 1472, bw.Kpad, 1440,
         qkvb, nullptr, nullptr, nullptr, 0);
    edge_logit_kernel<<<NE/4, 256, 0, stream>>>(qkvb, sh_f, rbf_f, bw.Wsh, bw.Wr,
                                                esrc, edst, r_e, logit);
    node_attn_kernel<<<NN, 128, 0, stream>>>(logit, r_e, qkvb, sh_f, bw.Wsh,
                                             rowptr, perm, esrc, aggh, aggl);
    int WoNpad = (bw.Din == 720) ? 768 : 512;
    gemm(aggh, aggl, bw.WoTh, bw.WoTl, bw.Din, WoNpad, 480, bw.Din,
         ybuf, nullptr, nullptr, zin, 2);
    ln_kernel<<<NN, 256, 0, stream>>>(ybuf, bw.Din, bw.Kpad, xlnh, xlnl);
    gemm(xlnh, xlnl, bw.F1Th, bw.F1Tl, DEMB, 512, bw.Kpad, DEMB,
         nullptr, h1h, h1l, nullptr, 1|4);
    gemm(h1h, h1l, bw.F2Th, bw.F2Tl, bw.Dout, 512, 480, bw.Dout,
         zout, nullptr, nullptr, bw.res ? ybuf : nullptr, bw.res ? 2 : 0);
  };

  BW b0 = { b0_Wsh_c, b0_Wr_c,
            b0_qkvTh,b0_qkvTl,b0_WoTh,b0_WoTl,b0_F1Th,b0_F1Tl,b0_F2Th,b0_F2Tl,
            720, 736, 480, false };
  BW bm[4];
  for (int i = 0; i < 4; ++i){
    bm[i] = { bm_Wsh_c + (size_t)i*9*480, bm_Wr_c + (size_t)i*128*4,
              bm_qkvTh[i],bm_qkvTl[i],bm_WoTh[i],bm_WoTl[i],
              bm_F1Th[i],bm_F1Tl[i],bm_F2Th[i],bm_F2Tl[i],
              480, 480, 480, true };
  }
  BW bf = { bf_Wsh_c, bf_Wr_c,
            bf_qkvTh,bf_qkvTl,bf_WoTh,bf_WoTl,bf_F1Th,bf_F1Tl,bf_F2Th,bf_F2Tl,
            480, 480, 512, false };

  float* z  = zA;
  float* z2 = zB;
  for (int iter = 0; iter < 2; ++iter){
    zcat_kernel<<<(NN*720)/256, 256, 0, stream>>>(z, injb, zcat);
    run_block(b0, zcat, z2);
    { float* tmp = z; z = z2; z2 = tmp; }
    for (int i = 0; i < 4; ++i){
      run_block(bm[i], z, z2);
      { float* tmp = z; z = z2; z2 = tmp; }
    }
  }
  run_block(bf, z, z2);
  ln_kernel<<<NN, 256, 0, stream>>>(z2, DFEAT, DFEAT, xlnh, xlnl);
  gemm(xlnh, xlnl, hW1Th, hW1Tl, DFEAT, 512, DFEAT, DFEAT,
       nullptr, g1h, g1l, nullptr, 1|4);
  zero_f32<<<1, 64, 0, stream>>>(gsum, 64);
  head_dot_kernel<<<NN/4, 256, 0, stream>>>(g1h, g1l, hW2_c, batch, gsum);
  finalize_kernel<<<1, 64, 0, stream>>>(gsum, dflag, d_out);
}

// Round 6
// 1984.152 us; speedup vs baseline: 1.3076x; 1.1488x over previous
//
#include <hip/hip_runtime.h>

#define NN 2048
#define NE 32768
#define NG 64
#define DINJ 240
#define DEMB 480
#define DFEAT 512

typedef unsigned short ushort_t;
typedef __attribute__((ext_vector_type(8))) short short8;
typedef __attribute__((ext_vector_type(4))) float floatx4;

__device__ __forceinline__ float b2f(ushort_t u){
  union { unsigned u; float f; } x; x.u = ((unsigned)u) << 16; return x.f;
}
__device__ __forceinline__ ushort_t f2b(float f){
  union { float f; unsigned u; } x; x.f = f;
  unsigned r = x.u + 0x7FFFu + ((x.u >> 16) & 1u);
  return (ushort_t)(r >> 16);
}
__device__ __forceinline__ float wredsum(float v){
  #pragma unroll
  for (int o = 32; o > 0; o >>= 1) v += __shfl_xor(v, o, 64);
  return v;
}
__device__ __forceinline__ float silu_f(float x){ return x / (1.f + __expf(-x)); }

// ---------------- small utility kernels ----------------
__global__ void zero_f32(float* p, int n){
  int i = blockIdx.x*256 + threadIdx.x; if (i < n) p[i] = 0.f;
}

// ---------------- input dtype detection ----------------
// flag=0: float inputs are bf16; flag=1: they are fp32.
__global__ void detect_kernel(const ushort_t* __restrict__ probe, int* flag){
  __shared__ int c;
  if (threadIdx.x == 0) c = 0;
  __syncthreads();
  ushort_t u = probe[2*threadIdx.x];
  int e = (u >> 7) & 0xFF;
  int plausible = (u == 0) || (e >= 100 && e <= 140);
  atomicAdd(&c, plausible);
  __syncthreads();
  if (threadIdx.x == 0) *flag = (c >= 192) ? 0 : 1;
}

// -------- convert small float inputs -> internal FP32 (exact either way) ----
struct CDesc { const void* src; float* dst; int n; };
struct CDescArr { CDesc d[11]; };
__global__ __launch_bounds__(256) void convert_inputs(CDescArr ca, const int* __restrict__ flag){
  CDesc cd = ca.d[blockIdx.y];
  int isf32 = *flag;
  for (int i = blockIdx.x*256 + threadIdx.x; i < cd.n; i += gridDim.x*256){
    cd.dst[i] = isf32 ? ((const float*)cd.src)[i] : b2f(((const ushort_t*)cd.src)[i]);
  }
}

// --- LDS-tiled weight transpose: src (K x M row-major) -> dst (Mpad x Kpad) --
// split bf16 hi/lo, zero-padded rows [M,Mpad) and cols [K,Kpad).
struct TDesc { const void* src; ushort_t* dh; ushort_t* dl; int K; int M; int Kpad; int Mpad; int eoff; };
struct TDescArr { TDesc d[37]; };
__global__ __launch_bounds__(256) void transpose_all(TDescArr ta, const int* __restrict__ flag){
  TDesc td = ta.d[blockIdx.z];
  int k0 = blockIdx.x*32, m0 = blockIdx.y*32;
  if (k0 >= td.Kpad || m0 >= td.Mpad) return;
  int isf32 = *flag;
  __shared__ float lds[32*33];
  int tx = threadIdx.x & 31, ty = threadIdx.x >> 5;
  #pragma unroll
  for (int r = 0; r < 4; ++r){
    int kl = ty + r*8;
    int k = k0 + kl, mm = m0 + tx;
    float x = 0.f;
    if (k < td.K && mm < td.M){
      size_t si = (size_t)td.eoff + (size_t)k*td.M + mm;
      x = isf32 ? ((const float*)td.src)[si] : b2f(((const ushort_t*)td.src)[si]);
    }
    lds[kl*33 + tx] = x;
  }
  __syncthreads();
  #pragma unroll
  for (int r = 0; r < 4; ++r){
    int nl = ty + r*8;
    int n = m0 + nl, k = k0 + tx;
    if (n < td.Mpad && k < td.Kpad){
      float x = lds[tx*33 + nl];
      ushort_t h = f2b(x);
      size_t di = (size_t)n*td.Kpad + k;
      td.dh[di] = h;
      td.dl[di] = f2b(x - b2f(h));
    }
  }
}

// ---------------- geometry (fp32 pos) ----------------
__global__ void geom_kernel(const float* __restrict__ pos,
                            const int* __restrict__ esrc, const int* __restrict__ edst,
                            float* __restrict__ sh, float* __restrict__ dist){
  int e = blockIdx.x*256 + threadIdx.x; if (e >= NE) return;
  int s = esrc[e], d = edst[e];
  float x = pos[s*3+0] - pos[d*3+0];
  float y = pos[s*3+1] - pos[d*3+1];
  float z = pos[s*3+2] - pos[d*3+2];
  float dd = sqrtf(x*x + y*y + z*z + 1e-12f);
  float ix = x/dd, iy = y/dd, iz = z/dd;
  const float s3 = 1.7320508075688772f, s15 = 3.872983346207417f, s5 = 2.23606797749979f;
  float* o = sh + (size_t)e*9;
  o[0] = 1.f; o[1] = s3*ix; o[2] = s3*iy; o[3] = s3*iz;
  o[4] = s15*ix*iy; o[5] = s15*iy*iz; o[6] = 0.5f*s5*(3.f*iz*iz - 1.f);
  o[7] = s15*ix*iz; o[8] = 0.5f*s15*(ix*ix - iy*iy);
  dist[e] = dd;
}

__global__ void rbf_kernel(const float* __restrict__ dist, float* __restrict__ rbf){
  int idx = blockIdx.x*256 + threadIdx.x; if (idx >= NE*128) return;
  int e = idx >> 7, r = idx & 127;
  float c = (float)r * (5.0f/127.0f);
  float u = (dist[e] - c) * (128.0f/5.0f);
  rbf[idx] = __expf(-0.5f*u*u);
}

__global__ void t9_kernel(const float* __restrict__ rbf, const float* __restrict__ sh,
                          const float* __restrict__ degWr, float* __restrict__ t9){
  int idx = blockIdx.x*256 + threadIdx.x; if (idx >= NE*9) return;
  int e = idx/9, j = idx - e*9;
  float s = 0.f;
  const float* rb = rbf + (size_t)e*128;
  for (int r = 0; r < 128; ++r) s += rb[r]*degWr[r*9+j];
  t9[idx] = sh[idx] * silu_f(s);
}

// ---------------- CSR build ----------------
__global__ void hist_kernel(const int* __restrict__ edst, int* counts){
  int e = blockIdx.x*256 + threadIdx.x; if (e < NE) atomicAdd(&counts[edst[e]], 1);
}
__global__ __launch_bounds__(1024) void scan_kernel(const int* __restrict__ counts,
                                                    int* rowptr, int* cursor){
  __shared__ int s[1024];
  int t = threadIdx.x;
  int c0 = counts[2*t], c1 = counts[2*t+1];
  s[t] = c0 + c1;
  __syncthreads();
  for (int off = 1; off < 1024; off <<= 1){
    int v = (t >= off) ? s[t-off] : 0;
    __syncthreads();
    s[t] += v;
    __syncthreads();
  }
  int excl = s[t] - (c0 + c1);
  rowptr[2*t]   = excl;       cursor[2*t]   = excl;
  rowptr[2*t+1] = excl + c0;  cursor[2*t+1] = excl + c0;
  if (t == 1023) rowptr[2048] = s[1023];
}
__global__ void scatter_kernel(const int* __restrict__ edst, int* cursor, int* perm){
  int e = blockIdx.x*256 + threadIdx.x; if (e >= NE) return;
  int p = atomicAdd(&cursor[edst[e]], 1);
  perm[p] = e;
}

// ---------------- inj = atom_table[node_atom] + (sum_e t9) @ degWsh / 16 -----
__global__ __launch_bounds__(64) void inj_kernel(const float* __restrict__ t9,
    const int* __restrict__ rowptr, const int* __restrict__ perm,
    const int* __restrict__ node_atom, const float* __restrict__ atom_table,
    const float* __restrict__ degWsh, float* __restrict__ inj){
  int i = blockIdx.x; int lane = threadIdx.x;
  int b = rowptr[i], e = rowptr[i+1];
  float T[9];
  #pragma unroll
  for (int j = 0; j < 9; ++j) T[j] = 0.f;
  for (int idx = b; idx < e; ++idx){
    int ed = perm[idx];
    #pragma unroll
    for (int j = 0; j < 9; ++j) T[j] += t9[(size_t)ed*9+j];
  }
  int a = node_atom[i];
  for (int c = lane; c < DINJ; c += 64){
    float s = 0.f;
    #pragma unroll
    for (int j = 0; j < 9; ++j) s += T[j]*degWsh[j*DINJ+c];
    inj[(size_t)i*DINJ+c] = atom_table[(size_t)a*DINJ+c] + s*(1.0f/16.0f);
  }
}

// ---------------- zcat = [z | inj] ----------------
__global__ void zcat_kernel(const float* __restrict__ z, const float* __restrict__ inj,
                            float* __restrict__ zc){
  int i = blockIdx.x*256 + threadIdx.x; if (i >= NN*720) return;
  int n = i / 720, d = i - n*720;
  zc[i] = (d < DEMB) ? z[(size_t)n*DEMB + d] : inj[(size_t)n*DINJ + (d - DEMB)];
}

// ------- LayerNorm (fp32 in -> bf16 out, zero-padded to Kpad) ----------------
__global__ __launch_bounds__(256) void ln_kernel(const float* __restrict__ in, int D,
                                                 int Kpad, ushort_t* __restrict__ oh){
  int i = blockIdx.x; int t = threadIdx.x;
  const float* row = in + (size_t)i*D;
  float s = 0.f, sq = 0.f;
  for (int d = t; d < D; d += 256){ float x = row[d]; s += x; sq += x*x; }
  __shared__ float ls[4], lq[4];
  s = wredsum(s); sq = wredsum(sq);
  int lane = t & 63, w = t >> 6;
  if (lane == 0){ ls[w] = s; lq[w] = sq; }
  __syncthreads();
  s  = ls[0]+ls[1]+ls[2]+ls[3];
  sq = lq[0]+lq[1]+lq[2]+lq[3];
  float mu = s / (float)D;
  float var = fmaxf(sq / (float)D - mu*mu, 0.f);
  float rs = rsqrtf(var + 1e-6f);
  ushort_t* ohrow = oh + (size_t)i*Kpad;
  for (int d = t; d < D; d += 256) ohrow[d] = f2b((row[d]-mu)*rs);
  for (int d = D + t; d < Kpad; d += 256) ohrow[d] = 0;
}

// -- MFMA GEMM: C = A * (Bh+Bl)^T. A single bf16 (activation-rounding is
//    negligible: R2==R3 evidence); B split hi/lo (weight quantization was the
//    error floor). 64x64 block tile, 32x32 per wave. KPAD compile-time.
// flags: 1 = silu, 2 = add residual R (ldc-strided), 4 = bf16 out else fp32
template<int KPAD>
__global__ __launch_bounds__(256) void gemm_bt(
    const ushort_t* __restrict__ A,
    const ushort_t* __restrict__ BTh, const ushort_t* __restrict__ BTl,
    int N, int ldc,
    float* __restrict__ Cf, ushort_t* __restrict__ Cb,
    const float* __restrict__ R, int flags){
  int lane = threadIdx.x & 63, wave = threadIdx.x >> 6;
  int row0 = blockIdx.y*64 + (wave>>1)*32;
  int col0 = blockIdx.x*64 + (wave&1)*32;
  int m = lane & 15, q4 = lane >> 4;
  size_t a0 = (size_t)(row0+m)*KPAD + q4*8;
  size_t a1 = a0 + (size_t)16*KPAD;
  size_t b0 = (size_t)(col0+m)*KPAD + q4*8;
  size_t b1 = b0 + (size_t)16*KPAD;
  floatx4 acc00 = {0,0,0,0}, acc01 = {0,0,0,0}, acc10 = {0,0,0,0}, acc11 = {0,0,0,0};
  constexpr int steps = KPAD >> 5;
  #pragma unroll 2
  for (int s = 0; s < steps; ++s){
    size_t o = (size_t)s*32;
    short8 A0 = *(const short8*)(A + a0 + o);
    short8 A1 = *(const short8*)(A + a1 + o);
    short8 B0h = *(const short8*)(BTh + b0 + o);
    short8 B0l = *(const short8*)(BTl + b0 + o);
    short8 B1h = *(const short8*)(BTh + b1 + o);
    short8 B1l = *(const short8*)(BTl + b1 + o);
    acc00 = __builtin_amdgcn_mfma_f32_16x16x32_bf16(A0, B0h, acc00, 0, 0, 0);
    acc00 = __builtin_amdgcn_mfma_f32_16x16x32_bf16(A0, B0l, acc00, 0, 0, 0);
    acc01 = __builtin_amdgcn_mfma_f32_16x16x32_bf16(A0, B1h, acc01, 0, 0, 0);
    acc01 = __builtin_amdgcn_mfma_f32_16x16x32_bf16(A0, B1l, acc01, 0, 0, 0);
    acc10 = __builtin_amdgcn_mfma_f32_16x16x32_bf16(A1, B0h, acc10, 0, 0, 0);
    acc10 = __builtin_amdgcn_mfma_f32_16x16x32_bf16(A1, B0l, acc10, 0, 0, 0);
    acc11 = __builtin_amdgcn_mfma_f32_16x16x32_bf16(A1, B1h, acc11, 0, 0, 0);
    acc11 = __builtin_amdgcn_mfma_f32_16x16x32_bf16(A1, B1l, acc11, 0, 0, 0);
  }
  #pragma unroll
  for (int rr = 0; rr < 2; ++rr){
    #pragma unroll
    for (int cc = 0; cc < 2; ++cc){
      int col = col0 + cc*16 + m;
      if (col >= N) continue;
      floatx4 acc = rr ? (cc ? acc11 : acc10) : (cc ? acc01 : acc00);
      int rowb = row0 + rr*16 + q4*4;
      #pragma unroll
      for (int r = 0; r < 4; ++r){
        size_t idx = (size_t)(rowb + r)*ldc + col;
        float v = acc[r];
        if (flags & 2) v += R[idx];
        if (flags & 1) v = silu_f(v);
        if (flags & 4) Cb[idx] = f2b(v);
        else           Cf[idx] = v;
      }
    }
  }
}

// ------- Pq[i][h][j] = q_i(head h) . Wsh_j(head h)  (2048 x 4 x 9) ----------
__global__ __launch_bounds__(256) void pq_kernel(const float* __restrict__ qkv,
    const float* __restrict__ Wsh, float* __restrict__ Pq){
  int i = blockIdx.x; int w = threadIdx.x >> 6; int lane = threadIdx.x & 63;
  const float* q = qkv + (size_t)i*1440 + w*120;
  float q0 = q[lane];
  float q1 = (lane < 56) ? q[64 + lane] : 0.f;
  #pragma unroll
  for (int j = 0; j < 9; ++j){
    const float* ws = Wsh + j*DEMB + w*120;
    float p = q0*ws[lane] + ((lane < 56) ? q1*ws[64 + lane] : 0.f);
    p = wredsum(p);
    if (lane == 0) Pq[((size_t)i*4 + w)*9 + j] = p;
  }
}

// ---------------- per-edge gate r[e][h] and logit[e][h] ----------------
// qkv layout: per node 1440 floats = [q(480) | k(480) | v(480)]
__global__ __launch_bounds__(256) void edge_logit_kernel(
    const float* __restrict__ qkv,
    const float* __restrict__ sh, const float* __restrict__ rbf,
    const float* __restrict__ Pq, const float* __restrict__ Wr,
    const int* __restrict__ esrc, const int* __restrict__ edst,
    float* __restrict__ r_out, float* __restrict__ logit){
  int e = blockIdx.x*4 + (threadIdx.x >> 6);
  int lane = threadIdx.x & 63;
  int s = esrc[e], dd = edst[e];
  float rb1 = rbf[(size_t)e*128 + lane], rb2 = rbf[(size_t)e*128 + 64 + lane];
  float rh[4];
  #pragma unroll
  for (int h = 0; h < 4; ++h){
    float p = rb1*Wr[lane*4+h] + rb2*Wr[(lane+64)*4+h];
    p = wredsum(p);
    rh[h] = silu_f(p);
  }
  if (lane == 0){
    r_out[e*4+0] = rh[0]; r_out[e*4+1] = rh[1];
    r_out[e*4+2] = rh[2]; r_out[e*4+3] = rh[3];
  }
  const float* qrow = qkv + (size_t)dd*1440;
  const float* krow = qkv + (size_t)s*1440 + 480;
  const float inv = 0.091287092917527686f; // 1/sqrt(120)
  #pragma unroll
  for (int h = 0; h < 4; ++h){
    int d = h*120 + lane;
    float p = qrow[d]*krow[d];
    if (lane < 56) p += qrow[d+64]*krow[d+64];
    p = wredsum(p);
    if (lane == 0){
      float mmq = 0.f;
      const float* pq = Pq + ((size_t)dd*4 + h)*9;
      #pragma unroll
      for (int j = 0; j < 9; ++j) mmq += sh[(size_t)e*9+j]*pq[j];
      logit[e*4+h] = rh[h]*(p + mmq)*inv;
    }
  }
}

// ------- per-node softmax + aggregation -> agg (bf16) ------------------------
#define CHUNK 128
__global__ __launch_bounds__(128) void node_attn_kernel(
    const float* __restrict__ logit, const float* __restrict__ r_e,
    const float* __restrict__ qkv, const float* __restrict__ sh,
    const float* __restrict__ Wsh,
    const int* __restrict__ rowptr, const int* __restrict__ perm,
    const int* __restrict__ esrc, ushort_t* __restrict__ aggh){
  int i = blockIdx.x; int t = threadIdx.x;
  int b = rowptr[i], en = rowptr[i+1]; int deg = en - b;
  __shared__ float mxs[4], dens[4], S[4][9];
  __shared__ float wbuf[CHUNK][4];
  __shared__ int srcbuf[CHUNK];
  if (t < 4){
    float mx = -1e30f;
    for (int idx = 0; idx < deg; ++idx){
      int e = perm[b+idx]; mx = fmaxf(mx, logit[e*4+t]);
    }
    if (deg == 0) mx = 0.f;
    float den = 0.f;
    for (int idx = 0; idx < deg; ++idx){
      int e = perm[b+idx]; den += __expf(logit[e*4+t]-mx);
    }
    mxs[t] = mx; dens[t] = den + 1e-9f;
  }
  __syncthreads();
  if (t < 36){
    int h = t/9, j = t - h*9;
    float a = 0.f;
    for (int idx = 0; idx < deg; ++idx){
      int e = perm[b+idx];
      float w = __expf(logit[e*4+h]-mxs[h]) / dens[h] * r_e[e*4+h];
      a += w * sh[(size_t)e*9+j];
    }
    S[h][j] = a;
  }
  __syncthreads();
  float acc[4] = {0.f, 0.f, 0.f, 0.f};
  for (int c0 = 0; c0 < deg; c0 += CHUNK){
    int cn = min(CHUNK, deg - c0);
    if (t < cn){
      int e = perm[b + c0 + t];
      #pragma unroll
      for (int h = 0; h < 4; ++h)
        wbuf[t][h] = __expf(logit[e*4+h]-mxs[h]) / dens[h] * r_e[e*4+h];
      srcbuf[t] = esrc[e];
    }
    __syncthreads();
    #pragma unroll
    for (int rseg = 0; rseg < 4; ++rseg){
      int d = t + rseg*128;
      if (d < DEMB){
        int h = d/120;
        float a = acc[rseg];
        for (int le = 0; le < cn; ++le)
          a += wbuf[le][h] * qkv[(size_t)srcbuf[le]*1440 + 960 + d];
        acc[rseg] = a;
      }
    }
    __syncthreads();
  }
  #pragma unroll
  for (int rseg = 0; rseg < 4; ++rseg){
    int d = t + rseg*128;
    if (d < DEMB){
      int h = d/120;
      float mm = 0.f;
      #pragma unroll
      for (int j = 0; j < 9; ++j) mm += S[h][j]*Wsh[j*DEMB + d];
      aggh[(size_t)i*DEMB + d] = f2b(acc[rseg] + mm);
    }
  }
}

// ---------------- head ----------------
__global__ __launch_bounds__(256) void head_dot_kernel(const ushort_t* __restrict__ g1h,
    const float* __restrict__ hW2, const int* __restrict__ batch, float* gsum){
  int i = blockIdx.x*4 + (threadIdx.x >> 6);
  int lane = threadIdx.x & 63;
  float s = 0.f;
  for (int d = lane; d < DFEAT; d += 64)
    s += b2f(g1h[(size_t)i*DFEAT + d]) * hW2[d];
  s = wredsum(s);
  if (lane == 0) atomicAdd(&gsum[batch[i]], s);
}
__global__ void finalize_kernel(const float* __restrict__ gsum,
                                const int* __restrict__ flag, void* out){
  int g = threadIdx.x;
  if (g < NG){
    float v = gsum[g] * 0.17677669529663687f; // 1/sqrt(32)
    if (*flag) ((float*)out)[g] = v;
    else       ((ushort_t*)out)[g] = f2b(v);
  }
}

// =====================================================================
extern "C" void kernel_launch(void* const* d_in, const int* in_sizes, int n_in,
                              void* d_out, int out_size, void* d_ws, size_t ws_size,
                              hipStream_t stream) {
  (void)in_sizes; (void)n_in; (void)out_size; (void)ws_size;
  const void* pos        = d_in[0];
  const int*  node_atom  = (const int*)d_in[1];
  const int*  esrc       = (const int*)d_in[2];
  const int*  edst       = (const int*)d_in[3];
  const int*  batch      = (const int*)d_in[4];
  const void* atom_table = d_in[5];
  const void* degWr      = d_in[6];
  const void* degWsh     = d_in[7];
  const void* b0_Wq  = d_in[8];
  const void* b0_Wk  = d_in[9];
  const void* b0_Wv  = d_in[10];
  const void* b0_Wsh = d_in[11];
  const void* b0_Wr  = d_in[12];
  const void* b0_Wo  = d_in[13];
  const void* b0_F1  = d_in[14];
  const void* b0_F2  = d_in[15];
  const void* bm_Wq  = d_in[16];
  const void* bm_Wk  = d_in[17];
  const void* bm_Wv  = d_in[18];
  const void* bm_Wsh = d_in[19];
  const void* bm_Wr  = d_in[20];
  const void* bm_Wo  = d_in[21];
  const void* bm_F1  = d_in[22];
  const void* bm_F2  = d_in[23];
  const void* bf_Wq  = d_in[24];
  const void* bf_Wk  = d_in[25];
  const void* bf_Wv  = d_in[26];
  const void* bf_Wsh = d_in[27];
  const void* bf_Wr  = d_in[28];
  const void* bf_Wo  = d_in[29];
  const void* bf_F1  = d_in[30];
  const void* bf_F2  = d_in[31];
  const void* hW1    = d_in[32];
  const void* hW2    = d_in[33];

  char* bws = (char*)d_ws;
  size_t off = 0;
  auto alloc = [&](size_t bytes) -> void* {
    void* p = bws + off;
    off += (bytes + 255) & ~(size_t)255;
    return p;
  };
  int* dflag   = (int*)alloc(256);
  float* sh_f  = (float*)alloc((size_t)NE*9*4);
  float* dist  = (float*)alloc((size_t)NE*4);
  float* rbf_f = (float*)alloc((size_t)NE*128*4);
  float* t9    = (float*)alloc((size_t)NE*9*4);
  int* counts  = (int*)alloc(2048*4);
  int* rowptr  = (int*)alloc(2049*4);
  int* cursor  = (int*)alloc(2048*4);
  int* perm    = (int*)alloc((size_t)NE*4);
  float* injb  = (float*)alloc((size_t)NN*DINJ*4);
  float* zA    = (float*)alloc((size_t)NN*512*4);
  float* zB    = (float*)alloc((size_t)NN*512*4);
  float* zcat  = (float*)alloc((size_t)NN*720*4);
  ushort_t* xlnh = (ushort_t*)alloc((size_t)NN*736*2);
  float* qkvb  = (float*)alloc((size_t)NN*1440*4);
  float* Pq    = (float*)alloc((size_t)NN*36*4);
  float* r_e   = (float*)alloc((size_t)NE*4*4);
  float* logit = (float*)alloc((size_t)NE*4*4);
  ushort_t* aggh = (ushort_t*)alloc((size_t)NN*DEMB*2);
  float* ybuf  = (float*)alloc((size_t)NN*720*4);
  ushort_t* h1h = (ushort_t*)alloc((size_t)NN*DEMB*2);
  ushort_t* g1h = (ushort_t*)alloc((size_t)NN*DFEAT*2);
  float* gsum  = (float*)alloc(64*4);

  // fp32 internal copies of small tensors
  float* pos_c    = (float*)alloc((size_t)NN*3*4);
  float* atom_c   = (float*)alloc((size_t)64*DINJ*4);
  float* degWr_c  = (float*)alloc((size_t)128*9*4);
  float* degWsh_c = (float*)alloc((size_t)9*DINJ*4);
  float* b0_Wsh_c = (float*)alloc((size_t)9*480*4);
  float* b0_Wr_c  = (float*)alloc((size_t)128*4*4);
  float* bm_Wsh_c = (float*)alloc((size_t)4*9*480*4);
  float* bm_Wr_c  = (float*)alloc((size_t)4*128*4*4);
  float* bf_Wsh_c = (float*)alloc((size_t)9*480*4);
  float* bf_Wr_c  = (float*)alloc((size_t)128*4*4);
  float* hW2_c    = (float*)alloc((size_t)512*4);

  // transposed weights (split bf16 hi/lo, Npad x Kpad)
  auto allocW = [&](size_t elems, ushort_t*& h, ushort_t*& l){
    h = (ushort_t*)alloc(elems*2); l = (ushort_t*)alloc(elems*2);
  };
  ushort_t *b0_qkvTh,*b0_qkvTl,*b0_WoTh,*b0_WoTl,*b0_F1Th,*b0_F1Tl,*b0_F2Th,*b0_F2Tl;
  allocW((size_t)1472*736, b0_qkvTh, b0_qkvTl);
  allocW((size_t)768*480,  b0_WoTh,  b0_WoTl);
  allocW((size_t)512*736,  b0_F1Th,  b0_F1Tl);
  allocW((size_t)512*480,  b0_F2Th,  b0_F2Tl);
  ushort_t *bm_qkvTh[4],*bm_qkvTl[4],*bm_WoTh[4],*bm_WoTl[4],*bm_F1Th[4],*bm_F1Tl[4],*bm_F2Th[4],*bm_F2Tl[4];
  for (int i = 0; i < 4; ++i){
    allocW((size_t)1472*480, bm_qkvTh[i], bm_qkvTl[i]);
    allocW((size_t)512*480,  bm_WoTh[i],  bm_WoTl[i]);
    allocW((size_t)512*480,  bm_F1Th[i],  bm_F1Tl[i]);
    allocW((size_t)512*480,  bm_F2Th[i],  bm_F2Tl[i]);
  }
  ushort_t *bf_qkvTh,*bf_qkvTl,*bf_WoTh,*bf_WoTl,*bf_F1Th,*bf_F1Tl,*bf_F2Th,*bf_F2Tl,*hW1Th,*hW1Tl;
  allocW((size_t)1472*480, bf_qkvTh, bf_qkvTl);
  allocW((size_t)512*480,  bf_WoTh,  bf_WoTl);
  allocW((size_t)512*480,  bf_F1Th,  bf_F1Tl);
  allocW((size_t)512*480,  bf_F2Th,  bf_F2Tl);
  allocW((size_t)512*512,  hW1Th,    hW1Tl);

  detect_kernel<<<1, 256, 0, stream>>>((const ushort_t*)atom_table, dflag);

  CDescArr ca;
  int ci = 0;
  auto addC = [&](const void* s, float* d, int n){
    ca.d[ci].src = s; ca.d[ci].dst = d; ca.d[ci].n = n; ++ci;
  };
  addC(pos, pos_c, NN*3);
  addC(atom_table, atom_c, 64*DINJ);
  addC(degWr, degWr_c, 128*9);
  addC(degWsh, degWsh_c, 9*DINJ);
  addC(b0_Wsh, b0_Wsh_c, 9*480);
  addC(b0_Wr, b0_Wr_c, 128*4);
  addC(bm_Wsh, bm_Wsh_c, 4*9*480);
  addC(bm_Wr, bm_Wr_c, 4*128*4);
  addC(bf_Wsh, bf_Wsh_c, 9*480);
  addC(bf_Wr, bf_Wr_c, 128*4);
  addC(hW2, hW2_c, 512);
  convert_inputs<<<dim3(8, 11), 256, 0, stream>>>(ca, dflag);

  TDescArr ta;
  int ti = 0;
  auto addT = [&](const void* s, ushort_t* dh, ushort_t* dl, int K, int M,
                  int Kp, int Mp, int rowoff, int eo){
    ta.d[ti].src = s;
    ta.d[ti].dh = dh + (size_t)rowoff*Kp;
    ta.d[ti].dl = dl + (size_t)rowoff*Kp;
    ta.d[ti].K = K; ta.d[ti].M = M; ta.d[ti].Kpad = Kp; ta.d[ti].Mpad = Mp;
    ta.d[ti].eoff = eo; ++ti;
  };
  addT(b0_Wq, b0_qkvTh, b0_qkvTl, 720, 480, 736, 480, 0,   0);
  addT(b0_Wk, b0_qkvTh, b0_qkvTl, 720, 480, 736, 480, 480, 0);
  addT(b0_Wv, b0_qkvTh, b0_qkvTl, 720, 480, 736, 512, 960, 0);
  addT(b0_Wo, b0_WoTh,  b0_WoTl,  480, 720, 480, 768, 0,   0);
  addT(b0_F1, b0_F1Th,  b0_F1Tl,  720, 480, 736, 512, 0,   0);
  addT(b0_F2, b0_F2Th,  b0_F2Tl,  480, 480, 480, 512, 0,   0);
  for (int i = 0; i < 4; ++i){
    int eo = i*480*480;
    addT(bm_Wq, bm_qkvTh[i], bm_qkvTl[i], 480, 480, 480, 480, 0,   eo);
    addT(bm_Wk, bm_qkvTh[i], bm_qkvTl[i], 480, 480, 480, 480, 480, eo);
    addT(bm_Wv, bm_qkvTh[i], bm_qkvTl[i], 480, 480, 480, 512, 960, eo);
    addT(bm_Wo, bm_WoTh[i],  bm_WoTl[i],  480, 480, 480, 512, 0,   eo);
    addT(bm_F1, bm_F1Th[i],  bm_F1Tl[i],  480, 480, 480, 512, 0,   eo);
    addT(bm_F2, bm_F2Th[i],  bm_F2Tl[i],  480, 480, 480, 512, 0,   eo);
  }
  addT(bf_Wq, bf_qkvTh, bf_qkvTl, 480, 480, 480, 480, 0,   0);
  addT(bf_Wk, bf_qkvTh, bf_qkvTl, 480, 480, 480, 480, 480, 0);
  addT(bf_Wv, bf_qkvTh, bf_qkvTl, 480, 480, 480, 512, 960, 0);
  addT(bf_Wo, bf_WoTh,  bf_WoTl,  480, 480, 480, 512, 0,   0);
  addT(bf_F1, bf_F1Th,  bf_F1Tl,  480, 480, 480, 512, 0,   0);
  addT(bf_F2, bf_F2Th,  bf_F2Tl,  480, 512, 480, 512, 0,   0);
  addT(hW1,   hW1Th,    hW1Tl,    512, 512, 512, 512, 0,   0);
  transpose_all<<<dim3(23, 24, 37), 256, 0, stream>>>(ta, dflag);

  geom_kernel<<<NE/256, 256, 0, stream>>>(pos_c, esrc, edst, sh_f, dist);
  rbf_kernel<<<(NE*128)/256, 256, 0, stream>>>(dist, rbf_f);
  t9_kernel<<<(NE*9 + 255)/256, 256, 0, stream>>>(rbf_f, sh_f, degWr_c, t9);

  zero_f32<<<(2048 + 255)/256, 256, 0, stream>>>((float*)counts, 2048);
  hist_kernel<<<NE/256, 256, 0, stream>>>(edst, counts);
  scan_kernel<<<1, 1024, 0, stream>>>(counts, rowptr, cursor);
  scatter_kernel<<<NE/256, 256, 0, stream>>>(edst, cursor, perm);

  inj_kernel<<<NN, 64, 0, stream>>>(t9, rowptr, perm, node_atom, atom_c, degWsh_c, injb);
  zero_f32<<<(NN*DEMB)/256, 256, 0, stream>>>(zA, NN*DEMB);

  auto gemm = [&](const ushort_t* A, const ushort_t* BTh, const ushort_t* BTl,
                  int N, int Npad, int Kp, int ldc,
                  float* Cf, ushort_t* Cb, const float* R, int flags){
    dim3 g(Npad/64, 32);
    if (Kp == 480)
      gemm_bt<480><<<g, 256, 0, stream>>>(A, BTh, BTl, N, ldc, Cf, Cb, R, flags);
    else if (Kp == 512)
      gemm_bt<512><<<g, 256, 0, stream>>>(A, BTh, BTl, N, ldc, Cf, Cb, R, flags);
    else
      gemm_bt<736><<<g, 256, 0, stream>>>(A, BTh, BTl, N, ldc, Cf, Cb, R, flags);
  };

  struct BW {
    const float *Wsh, *Wr;
    const ushort_t *qkvTh,*qkvTl,*WoTh,*WoTl,*F1Th,*F1Tl,*F2Th,*F2Tl;
    int Din, Kpad, Dout; bool res;
  };
  auto run_block = [&](const BW& bw, const float* zin, float* zout){
    ln_kernel<<<NN, 256, 0, stream>>>(zin, bw.Din, bw.Kpad, xlnh);
    gemm(xlnh, bw.qkvTh, bw.qkvTl, 1440, 1472, bw.Kpad, 1440,
         qkvb, nullptr, nullptr, 0);
    pq_kernel<<<NN, 256, 0, stream>>>(qkvb, bw.Wsh, Pq);
    edge_logit_kernel<<<NE/4, 256, 0, stream>>>(qkvb, sh_f, rbf_f, Pq, bw.Wr,
                                                esrc, edst, r_e, logit);
    node_attn_kernel<<<NN, 128, 0, stream>>>(logit, r_e, qkvb, sh_f, bw.Wsh,
                                             rowptr, perm, esrc, aggh);
    int WoNpad = (bw.Din == 720) ? 768 : 512;
    gemm(aggh, bw.WoTh, bw.WoTl, bw.Din, WoNpad, 480, bw.Din,
         ybuf, nullptr, zin, 2);
    ln_kernel<<<NN, 256, 0, stream>>>(ybuf, bw.Din, bw.Kpad, xlnh);
    gemm(xlnh, bw.F1Th, bw.F1Tl, DEMB, 512, bw.Kpad, DEMB,
         nullptr, h1h, nullptr, 1|4);
    gemm(h1h, bw.F2Th, bw.F2Tl, bw.Dout, 512, 480, bw.Dout,
         zout, nullptr, bw.res ? ybuf : nullptr, bw.res ? 2 : 0);
  };

  BW b0 = { b0_Wsh_c, b0_Wr_c,
            b0_qkvTh,b0_qkvTl,b0_WoTh,b0_WoTl,b0_F1Th,b0_F1Tl,b0_F2Th,b0_F2Tl,
            720, 736, 480, false };
  BW bm[4];
  for (int i = 0; i < 4; ++i){
    bm[i] = { bm_Wsh_c + (size_t)i*9*480, bm_Wr_c + (size_t)i*128*4,
              bm_qkvTh[i],bm_qkvTl[i],bm_WoTh[i],bm_WoTl[i],
              bm_F1Th[i],bm_F1Tl[i],bm_F2Th[i],bm_F2Tl[i],
              480, 480, 480, true };
  }
  BW bf = { bf_Wsh_c, bf_Wr_c,
            bf_qkvTh,bf_qkvTl,bf_WoTh,bf_WoTl,bf_F1Th,bf_F1Tl,bf_F2Th,bf_F2Tl,
            480, 480, 512, false };

  float* z  = zA;
  float* z2 = zB;
  for (int iter = 0; iter < 2; ++iter){
    zcat_kernel<<<(NN*720)/256, 256, 0, stream>>>(z, injb, zcat);
    run_block(b0, zcat, z2);
    { float* tmp = z; z = z2; z2 = tmp; }
    for (int i = 0; i < 4; ++i){
      run_block(bm[i], z, z2);
      { float* tmp = z; z = z2; z2 = tmp; }
    }
  }
  run_block(bf, z, z2);
  ln_kernel<<<NN, 256, 0, stream>>>(z2, DFEAT, DFEAT, xlnh);
  gemm(xlnh, hW1Th, hW1Tl, DFEAT, 512, DFEAT, DFEAT,
       nullptr, g1h, nullptr, 1|4);
  zero_f32<<<1, 64, 0, stream>>>(gsum, 64);
  head_dot_kernel<<<NN/4, 256, 0, stream>>>(g1h, hW2_c, batch, gsum);
  finalize_kernel<<<1, 64, 0, stream>>>(gsum, dflag, d_out);
}

// Round 7
// 1732.026 us; speedup vs baseline: 1.4980x; 1.1456x over previous
//
#include <hip/hip_runtime.h>

#define NN 2048
#define NE 32768
#define NG 64
#define DINJ 240
#define DEMB 480
#define DFEAT 512

typedef unsigned short ushort_t;
typedef __attribute__((ext_vector_type(8))) short short8;
typedef __attribute__((ext_vector_type(4))) float floatx4;

__device__ __forceinline__ float b2f(ushort_t u){
  union { unsigned u; float f; } x; x.u = ((unsigned)u) << 16; return x.f;
}
__device__ __forceinline__ ushort_t f2b(float f){
  union { float f; unsigned u; } x; x.f = f;
  unsigned r = x.u + 0x7FFFu + ((x.u >> 16) & 1u);
  return (ushort_t)(r >> 16);
}
__device__ __forceinline__ float wredsum(float v){
  #pragma unroll
  for (int o = 32; o > 0; o >>= 1) v += __shfl_xor(v, o, 64);
  return v;
}
__device__ __forceinline__ float silu_f(float x){ return x / (1.f + __expf(-x)); }

// ---------------- small utility kernels ----------------
__global__ void zero_f32(float* p, int n){
  int i = blockIdx.x*256 + threadIdx.x; if (i < n) p[i] = 0.f;
}

// ---------------- input dtype detection ----------------
__global__ void detect_kernel(const ushort_t* __restrict__ probe, int* flag){
  __shared__ int c;
  if (threadIdx.x == 0) c = 0;
  __syncthreads();
  ushort_t u = probe[2*threadIdx.x];
  int e = (u >> 7) & 0xFF;
  int plausible = (u == 0) || (e >= 100 && e <= 140);
  atomicAdd(&c, plausible);
  __syncthreads();
  if (threadIdx.x == 0) *flag = (c >= 192) ? 0 : 1;
}

// -------- convert small float inputs -> internal FP32 (exact either way) ----
struct CDesc { const void* src; float* dst; int n; };
struct CDescArr { CDesc d[11]; };
__global__ __launch_bounds__(256) void convert_inputs(CDescArr ca, const int* __restrict__ flag){
  CDesc cd = ca.d[blockIdx.y];
  int isf32 = *flag;
  for (int i = blockIdx.x*256 + threadIdx.x; i < cd.n; i += gridDim.x*256){
    cd.dst[i] = isf32 ? ((const float*)cd.src)[i] : b2f(((const ushort_t*)cd.src)[i]);
  }
}

// --- LDS-tiled weight transpose: src (K x M row-major) -> dst (Mpad x Kpad) --
struct TDesc { const void* src; ushort_t* dh; ushort_t* dl; int K; int M; int Kpad; int Mpad; int eoff; };
struct TDescArr { TDesc d[37]; };
__global__ __launch_bounds__(256) void transpose_all(TDescArr ta, const int* __restrict__ flag){
  TDesc td = ta.d[blockIdx.z];
  int k0 = blockIdx.x*32, m0 = blockIdx.y*32;
  if (k0 >= td.Kpad || m0 >= td.Mpad) return;
  int isf32 = *flag;
  __shared__ float lds[32*33];
  int tx = threadIdx.x & 31, ty = threadIdx.x >> 5;
  #pragma unroll
  for (int r = 0; r < 4; ++r){
    int kl = ty + r*8;
    int k = k0 + kl, mm = m0 + tx;
    float x = 0.f;
    if (k < td.K && mm < td.M){
      size_t si = (size_t)td.eoff + (size_t)k*td.M + mm;
      x = isf32 ? ((const float*)td.src)[si] : b2f(((const ushort_t*)td.src)[si]);
    }
    lds[kl*33 + tx] = x;
  }
  __syncthreads();
  #pragma unroll
  for (int r = 0; r < 4; ++r){
    int nl = ty + r*8;
    int n = m0 + nl, k = k0 + tx;
    if (n < td.Mpad && k < td.Kpad){
      float x = lds[tx*33 + nl];
      ushort_t h = f2b(x);
      size_t di = (size_t)n*td.Kpad + k;
      td.dh[di] = h;
      td.dl[di] = f2b(x - b2f(h));
    }
  }
}

// ---------------- geometry (fp32 pos) ----------------
__global__ void geom_kernel(const float* __restrict__ pos,
                            const int* __restrict__ esrc, const int* __restrict__ edst,
                            float* __restrict__ sh, float* __restrict__ dist){
  int e = blockIdx.x*256 + threadIdx.x; if (e >= NE) return;
  int s = esrc[e], d = edst[e];
  float x = pos[s*3+0] - pos[d*3+0];
  float y = pos[s*3+1] - pos[d*3+1];
  float z = pos[s*3+2] - pos[d*3+2];
  float dd = sqrtf(x*x + y*y + z*z + 1e-12f);
  float ix = x/dd, iy = y/dd, iz = z/dd;
  const float s3 = 1.7320508075688772f, s15 = 3.872983346207417f, s5 = 2.23606797749979f;
  float* o = sh + (size_t)e*9;
  o[0] = 1.f; o[1] = s3*ix; o[2] = s3*iy; o[3] = s3*iz;
  o[4] = s15*ix*iy; o[5] = s15*iy*iz; o[6] = 0.5f*s5*(3.f*iz*iz - 1.f);
  o[7] = s15*ix*iz; o[8] = 0.5f*s15*(ix*ix - iy*iy);
  dist[e] = dd;
}

__global__ void rbf_kernel(const float* __restrict__ dist, float* __restrict__ rbf){
  int idx = blockIdx.x*256 + threadIdx.x; if (idx >= NE*128) return;
  int e = idx >> 7, r = idx & 127;
  float c = (float)r * (5.0f/127.0f);
  float u = (dist[e] - c) * (128.0f/5.0f);
  rbf[idx] = __expf(-0.5f*u*u);
}

__global__ void t9_kernel(const float* __restrict__ rbf, const float* __restrict__ sh,
                          const float* __restrict__ degWr, float* __restrict__ t9){
  int idx = blockIdx.x*256 + threadIdx.x; if (idx >= NE*9) return;
  int e = idx/9, j = idx - e*9;
  float s = 0.f;
  const float* rb = rbf + (size_t)e*128;
  for (int r = 0; r < 128; ++r) s += rb[r]*degWr[r*9+j];
  t9[idx] = sh[idx] * silu_f(s);
}

// ---- gate: r_all[slot][e][h] = silu(rbf[e] . Wr_slot[:,h]), 6 slots, once ---
__global__ __launch_bounds__(256) void gate_kernel(const float* __restrict__ rbf,
    const float* __restrict__ b0Wr, const float* __restrict__ bmWr,
    const float* __restrict__ bfWr, float* __restrict__ r_all){
  int slot = blockIdx.y;
  const float* Wr = (slot == 0) ? b0Wr : ((slot <= 4) ? bmWr + (size_t)(slot-1)*512 : bfWr);
  int e = blockIdx.x*4 + (threadIdx.x >> 6);
  int lane = threadIdx.x & 63;
  float rb1 = rbf[(size_t)e*128 + lane], rb2 = rbf[(size_t)e*128 + 64 + lane];
  float* out = r_all + ((size_t)slot*NE + e)*4;
  #pragma unroll
  for (int h = 0; h < 4; ++h){
    float p = rb1*Wr[lane*4+h] + rb2*Wr[(lane+64)*4+h];
    p = wredsum(p);
    if (lane == 0) out[h] = silu_f(p);
  }
}

// ---------------- CSR build ----------------
__global__ void hist_kernel(const int* __restrict__ edst, int* counts){
  int e = blockIdx.x*256 + threadIdx.x; if (e < NE) atomicAdd(&counts[edst[e]], 1);
}
__global__ __launch_bounds__(1024) void scan_kernel(const int* __restrict__ counts,
                                                    int* rowptr, int* cursor){
  __shared__ int s[1024];
  int t = threadIdx.x;
  int c0 = counts[2*t], c1 = counts[2*t+1];
  s[t] = c0 + c1;
  __syncthreads();
  for (int off = 1; off < 1024; off <<= 1){
    int v = (t >= off) ? s[t-off] : 0;
    __syncthreads();
    s[t] += v;
    __syncthreads();
  }
  int excl = s[t] - (c0 + c1);
  rowptr[2*t]   = excl;       cursor[2*t]   = excl;
  rowptr[2*t+1] = excl + c0;  cursor[2*t+1] = excl + c0;
  if (t == 1023) rowptr[2048] = s[1023];
}
__global__ void scatter_kernel(const int* __restrict__ edst, int* cursor, int* perm){
  int e = blockIdx.x*256 + threadIdx.x; if (e >= NE) return;
  int p = atomicAdd(&cursor[edst[e]], 1);
  perm[p] = e;
}

// ---------------- inj = atom_table[node_atom] + (sum_e t9) @ degWsh / 16 -----
__global__ __launch_bounds__(64) void inj_kernel(const float* __restrict__ t9,
    const int* __restrict__ rowptr, const int* __restrict__ perm,
    const int* __restrict__ node_atom, const float* __restrict__ atom_table,
    const float* __restrict__ degWsh, float* __restrict__ inj){
  int i = blockIdx.x; int lane = threadIdx.x;
  int b = rowptr[i], e = rowptr[i+1];
  float T[9];
  #pragma unroll
  for (int j = 0; j < 9; ++j) T[j] = 0.f;
  for (int idx = b; idx < e; ++idx){
    int ed = perm[idx];
    #pragma unroll
    for (int j = 0; j < 9; ++j) T[j] += t9[(size_t)ed*9+j];
  }
  int a = node_atom[i];
  for (int c = lane; c < DINJ; c += 64){
    float s = 0.f;
    #pragma unroll
    for (int j = 0; j < 9; ++j) s += T[j]*degWsh[j*DINJ+c];
    inj[(size_t)i*DINJ+c] = atom_table[(size_t)a*DINJ+c] + s*(1.0f/16.0f);
  }
}

// ---------------- zcat = [z | inj] ----------------
__global__ void zcat_kernel(const float* __restrict__ z, const float* __restrict__ inj,
                            float* __restrict__ zc){
  int i = blockIdx.x*256 + threadIdx.x; if (i >= NN*720) return;
  int n = i / 720, d = i - n*720;
  zc[i] = (d < DEMB) ? z[(size_t)n*DEMB + d] : inj[(size_t)n*DINJ + (d - DEMB)];
}

// ------- LayerNorm (fp32 in -> bf16 out, zero-padded to Kpad) ----------------
__global__ __launch_bounds__(256) void ln_kernel(const float* __restrict__ in, int D,
                                                 int Kpad, ushort_t* __restrict__ oh){
  int i = blockIdx.x; int t = threadIdx.x;
  const float* row = in + (size_t)i*D;
  float s = 0.f, sq = 0.f;
  for (int d = t; d < D; d += 256){ float x = row[d]; s += x; sq += x*x; }
  __shared__ float ls[4], lq[4];
  s = wredsum(s); sq = wredsum(sq);
  int lane = t & 63, w = t >> 6;
  if (lane == 0){ ls[w] = s; lq[w] = sq; }
  __syncthreads();
  s  = ls[0]+ls[1]+ls[2]+ls[3];
  sq = lq[0]+lq[1]+lq[2]+lq[3];
  float mu = s / (float)D;
  float var = fmaxf(sq / (float)D - mu*mu, 0.f);
  float rs = rsqrtf(var + 1e-6f);
  ushort_t* ohrow = oh + (size_t)i*Kpad;
  for (int d = t; d < D; d += 256) ohrow[d] = f2b((row[d]-mu)*rs);
  for (int d = D + t; d < Kpad; d += 256) ohrow[d] = 0;
}

// -- MFMA GEMM: C = A * (Bh+Bl)^T, software-pipelined (prefetch depth 1) ------
// flags: 1 = silu, 2 = add residual R (ldc-strided), 4 = bf16 out else fp32
template<int KPAD>
__global__ __launch_bounds__(256) void gemm_bt(
    const ushort_t* __restrict__ A,
    const ushort_t* __restrict__ BTh, const ushort_t* __restrict__ BTl,
    int N, int ldc,
    float* __restrict__ Cf, ushort_t* __restrict__ Cb,
    const float* __restrict__ R, int flags){
  int lane = threadIdx.x & 63, wave = threadIdx.x >> 6;
  int row0 = blockIdx.y*64 + (wave>>1)*32;
  int col0 = blockIdx.x*64 + (wave&1)*32;
  int m = lane & 15, q4 = lane >> 4;
  size_t a0 = (size_t)(row0+m)*KPAD + q4*8;
  size_t a1 = a0 + (size_t)16*KPAD;
  size_t b0 = (size_t)(col0+m)*KPAD + q4*8;
  size_t b1 = b0 + (size_t)16*KPAD;
  floatx4 acc00 = {0,0,0,0}, acc01 = {0,0,0,0}, acc10 = {0,0,0,0}, acc11 = {0,0,0,0};
  constexpr int steps = KPAD >> 5;
  short8 cA0 = *(const short8*)(A + a0);
  short8 cA1 = *(const short8*)(A + a1);
  short8 cB0h = *(const short8*)(BTh + b0);
  short8 cB0l = *(const short8*)(BTl + b0);
  short8 cB1h = *(const short8*)(BTh + b1);
  short8 cB1l = *(const short8*)(BTl + b1);
  #pragma unroll
  for (int s = 0; s < steps; ++s){
    short8 nA0, nA1, nB0h, nB0l, nB1h, nB1l;
    if (s + 1 < steps){
      size_t o = (size_t)(s+1)*32;
      nA0  = *(const short8*)(A   + a0 + o);
      nA1  = *(const short8*)(A   + a1 + o);
      nB0h = *(const short8*)(BTh + b0 + o);
      nB0l = *(const short8*)(BTl + b0 + o);
      nB1h = *(const short8*)(BTh + b1 + o);
      nB1l = *(const short8*)(BTl + b1 + o);
    }
    acc00 = __builtin_amdgcn_mfma_f32_16x16x32_bf16(cA0, cB0h, acc00, 0, 0, 0);
    acc00 = __builtin_amdgcn_mfma_f32_16x16x32_bf16(cA0, cB0l, acc00, 0, 0, 0);
    acc01 = __builtin_amdgcn_mfma_f32_16x16x32_bf16(cA0, cB1h, acc01, 0, 0, 0);
    acc01 = __builtin_amdgcn_mfma_f32_16x16x32_bf16(cA0, cB1l, acc01, 0, 0, 0);
    acc10 = __builtin_amdgcn_mfma_f32_16x16x32_bf16(cA1, cB0h, acc10, 0, 0, 0);
    acc10 = __builtin_amdgcn_mfma_f32_16x16x32_bf16(cA1, cB0l, acc10, 0, 0, 0);
    acc11 = __builtin_amdgcn_mfma_f32_16x16x32_bf16(cA1, cB1h, acc11, 0, 0, 0);
    acc11 = __builtin_amdgcn_mfma_f32_16x16x32_bf16(cA1, cB1l, acc11, 0, 0, 0);
    cA0 = nA0; cA1 = nA1; cB0h = nB0h; cB0l = nB0l; cB1h = nB1h; cB1l = nB1l;
  }
  #pragma unroll
  for (int rr = 0; rr < 2; ++rr){
    #pragma unroll
    for (int cc = 0; cc < 2; ++cc){
      int col = col0 + cc*16 + m;
      if (col >= N) continue;
      floatx4 acc = rr ? (cc ? acc11 : acc10) : (cc ? acc01 : acc00);
      int rowb = row0 + rr*16 + q4*4;
      #pragma unroll
      for (int r = 0; r < 4; ++r){
        size_t idx = (size_t)(rowb + r)*ldc + col;
        float v = acc[r];
        if (flags & 2) v += R[idx];
        if (flags & 1) v = silu_f(v);
        if (flags & 4) Cb[idx] = f2b(v);
        else           Cf[idx] = v;
      }
    }
  }
}

// ------- Pq[i][h][j] = q_i(head h) . Wsh_j(head h)  (2048 x 4 x 9) ----------
__global__ __launch_bounds__(256) void pq_kernel(const float* __restrict__ qkv,
    const float* __restrict__ Wsh, float* __restrict__ Pq){
  int i = blockIdx.x; int w = threadIdx.x >> 6; int lane = threadIdx.x & 63;
  const float* q = qkv + (size_t)i*1440 + w*120;
  float q0 = q[lane];
  float q1 = (lane < 56) ? q[64 + lane] : 0.f;
  #pragma unroll
  for (int j = 0; j < 9; ++j){
    const float* ws = Wsh + j*DEMB + w*120;
    float p = q0*ws[lane] + ((lane < 56) ? q1*ws[64 + lane] : 0.f);
    p = wredsum(p);
    if (lane == 0) Pq[((size_t)i*4 + w)*9 + j] = p;
  }
}

// ---------------- per-edge logit[e][h] (gate precomputed) --------------------
__global__ __launch_bounds__(256) void edge_logit_kernel(
    const float* __restrict__ qkv,
    const float* __restrict__ sh,
    const float* __restrict__ Pq, const float* __restrict__ r_slot,
    const int* __restrict__ esrc, const int* __restrict__ edst,
    float* __restrict__ logit){
  int e = blockIdx.x*4 + (threadIdx.x >> 6);
  int lane = threadIdx.x & 63;
  int s = esrc[e], dd = edst[e];
  const float* qrow = qkv + (size_t)dd*1440;
  const float* krow = qkv + (size_t)s*1440 + 480;
  const float inv = 0.091287092917527686f; // 1/sqrt(120)
  #pragma unroll
  for (int h = 0; h < 4; ++h){
    int d = h*120 + lane;
    float p = qrow[d]*krow[d];
    if (lane < 56) p += qrow[d+64]*krow[d+64];
    p = wredsum(p);
    if (lane == 0){
      float mmq = 0.f;
      const float* pq = Pq + ((size_t)dd*4 + h)*9;
      #pragma unroll
      for (int j = 0; j < 9; ++j) mmq += sh[(size_t)e*9+j]*pq[j];
      logit[e*4+h] = r_slot[e*4+h]*(p + mmq)*inv;
    }
  }
}

// ------- per-node softmax + aggregation -> agg (bf16), 256 threads -----------
__global__ __launch_bounds__(256) void node_attn_kernel(
    const float* __restrict__ logit, const float* __restrict__ r_slot,
    const float* __restrict__ qkv, const float* __restrict__ sh,
    const float* __restrict__ Wsh,
    const int* __restrict__ rowptr, const int* __restrict__ perm,
    const int* __restrict__ esrc, ushort_t* __restrict__ aggh){
  int i = blockIdx.x; int t = threadIdx.x;
  int lane = t & 63, w = t >> 6;
  int b = rowptr[i]; int deg = rowptr[i+1] - b;
  __shared__ float mxs[4], dens[4];
  __shared__ float wbuf[64][5];
  __shared__ int srcbuf[64], ebuf[64];
  __shared__ float S[4][9];
  // phase 1: wave w handles head w
  float mx = -1e30f;
  for (int idx = lane; idx < deg; idx += 64)
    mx = fmaxf(mx, logit[perm[b+idx]*4 + w]);
  #pragma unroll
  for (int o = 32; o > 0; o >>= 1) mx = fmaxf(mx, __shfl_xor(mx, o, 64));
  if (deg == 0) mx = 0.f;
  float den = 0.f;
  for (int idx = lane; idx < deg; idx += 64)
    den += __expf(logit[perm[b+idx]*4 + w] - mx);
  den = wredsum(den) + 1e-9f;
  if (lane == 0){ mxs[w] = mx; dens[w] = den; }
  if (t < 36) S[t/9][t - (t/9)*9] = 0.f;
  __syncthreads();

  const int d0 = 2*t;                 // t<240: dims d0, d0+1 (same head)
  const int h2 = d0/120;
  float acc0 = 0.f, acc1 = 0.f;
  for (int c0 = 0; c0 < deg; c0 += 64){
    int cn = min(64, deg - c0);
    if (t < cn){
      int e = perm[b + c0 + t];
      ebuf[t] = e;
      srcbuf[t] = esrc[e];
      #pragma unroll
      for (int h = 0; h < 4; ++h)
        wbuf[t][h] = __expf(logit[e*4+h]-mxs[h]) / dens[h] * r_slot[e*4+h];
    }
    __syncthreads();
    if (t < 36){
      int h = t/9, j = t - h*9;
      float a = S[h][j];
      for (int le = 0; le < cn; ++le)
        a += wbuf[le][h] * sh[(size_t)ebuf[le]*9 + j];
      S[h][j] = a;
    }
    if (t < 240){
      for (int le = 0; le < cn; ++le){
        float wgt = wbuf[le][h2];
        const float2 vv = *(const float2*)(qkv + (size_t)srcbuf[le]*1440 + 960 + d0);
        acc0 += wgt*vv.x;
        acc1 += wgt*vv.y;
      }
    }
    __syncthreads();
  }
  if (t < 240){
    float mm0 = 0.f, mm1 = 0.f;
    #pragma unroll
    for (int j = 0; j < 9; ++j){
      mm0 += S[h2][j]*Wsh[j*DEMB + d0];
      mm1 += S[h2][j]*Wsh[j*DEMB + d0 + 1];
    }
    aggh[(size_t)i*DEMB + d0]     = f2b(acc0 + mm0);
    aggh[(size_t)i*DEMB + d0 + 1] = f2b(acc1 + mm1);
  }
}

// ---------------- head ----------------
__global__ __launch_bounds__(256) void head_dot_kernel(const ushort_t* __restrict__ g1h,
    const float* __restrict__ hW2, const int* __restrict__ batch, float* gsum){
  int i = blockIdx.x*4 + (threadIdx.x >> 6);
  int lane = threadIdx.x & 63;
  float s = 0.f;
  for (int d = lane; d < DFEAT; d += 64)
    s += b2f(g1h[(size_t)i*DFEAT + d]) * hW2[d];
  s = wredsum(s);
  if (lane == 0) atomicAdd(&gsum[batch[i]], s);
}
__global__ void finalize_kernel(const float* __restrict__ gsum,
                                const int* __restrict__ flag, void* out){
  int g = threadIdx.x;
  if (g < NG){
    float v = gsum[g] * 0.17677669529663687f; // 1/sqrt(32)
    if (*flag) ((float*)out)[g] = v;
    else       ((ushort_t*)out)[g] = f2b(v);
  }
}

// =====================================================================
extern "C" void kernel_launch(void* const* d_in, const int* in_sizes, int n_in,
                              void* d_out, int out_size, void* d_ws, size_t ws_size,
                              hipStream_t stream) {
  (void)in_sizes; (void)n_in; (void)out_size; (void)ws_size;
  const void* pos        = d_in[0];
  const int*  node_atom  = (const int*)d_in[1];
  const int*  esrc       = (const int*)d_in[2];
  const int*  edst       = (const int*)d_in[3];
  const int*  batch      = (const int*)d_in[4];
  const void* atom_table = d_in[5];
  const void* degWr      = d_in[6];
  const void* degWsh     = d_in[7];
  const void* b0_Wq  = d_in[8];
  const void* b0_Wk  = d_in[9];
  const void* b0_Wv  = d_in[10];
  const void* b0_Wsh = d_in[11];
  const void* b0_Wr  = d_in[12];
  const void* b0_Wo  = d_in[13];
  const void* b0_F1  = d_in[14];
  const void* b0_F2  = d_in[15];
  const void* bm_Wq  = d_in[16];
  const void* bm_Wk  = d_in[17];
  const void* bm_Wv  = d_in[18];
  const void* bm_Wsh = d_in[19];
  const void* bm_Wr  = d_in[20];
  const void* bm_Wo  = d_in[21];
  const void* bm_F1  = d_in[22];
  const void* bm_F2  = d_in[23];
  const void* bf_Wq  = d_in[24];
  const void* bf_Wk  = d_in[25];
  const void* bf_Wv  = d_in[26];
  const void* bf_Wsh = d_in[27];
  const void* bf_Wr  = d_in[28];
  const void* bf_Wo  = d_in[29];
  const void* bf_F1  = d_in[30];
  const void* bf_F2  = d_in[31];
  const void* hW1    = d_in[32];
  const void* hW2    = d_in[33];

  char* bws = (char*)d_ws;
  size_t off = 0;
  auto alloc = [&](size_t bytes) -> void* {
    void* p = bws + off;
    off += (bytes + 255) & ~(size_t)255;
    return p;
  };
  int* dflag   = (int*)alloc(256);
  float* sh_f  = (float*)alloc((size_t)NE*9*4);
  float* dist  = (float*)alloc((size_t)NE*4);
  float* rbf_f = (float*)alloc((size_t)NE*128*4);
  float* t9    = (float*)alloc((size_t)NE*9*4);
  int* counts  = (int*)alloc(2048*4);
  int* rowptr  = (int*)alloc(2049*4);
  int* cursor  = (int*)alloc(2048*4);
  int* perm    = (int*)alloc((size_t)NE*4);
  float* injb  = (float*)alloc((size_t)NN*DINJ*4);
  float* zA    = (float*)alloc((size_t)NN*512*4);
  float* zB    = (float*)alloc((size_t)NN*512*4);
  float* zcat  = (float*)alloc((size_t)NN*720*4);
  ushort_t* xlnh = (ushort_t*)alloc((size_t)NN*736*2);
  float* qkvb  = (float*)alloc((size_t)NN*1440*4);
  float* Pq    = (float*)alloc((size_t)NN*36*4);
  float* r_all = (float*)alloc((size_t)6*NE*4*4);
  float* logit = (float*)alloc((size_t)NE*4*4);
  ushort_t* aggh = (ushort_t*)alloc((size_t)NN*DEMB*2);
  float* ybuf  = (float*)alloc((size_t)NN*720*4);
  ushort_t* h1h = (ushort_t*)alloc((size_t)NN*DEMB*2);
  ushort_t* g1h = (ushort_t*)alloc((size_t)NN*DFEAT*2);
  float* gsum  = (float*)alloc(64*4);

  // fp32 internal copies of small tensors
  float* pos_c    = (float*)alloc((size_t)NN*3*4);
  float* atom_c   = (float*)alloc((size_t)64*DINJ*4);
  float* degWr_c  = (float*)alloc((size_t)128*9*4);
  float* degWsh_c = (float*)alloc((size_t)9*DINJ*4);
  float* b0_Wsh_c = (float*)alloc((size_t)9*480*4);
  float* b0_Wr_c  = (float*)alloc((size_t)128*4*4);
  float* bm_Wsh_c = (float*)alloc((size_t)4*9*480*4);
  float* bm_Wr_c  = (float*)alloc((size_t)4*128*4*4);
  float* bf_Wsh_c = (float*)alloc((size_t)9*480*4);
  float* bf_Wr_c  = (float*)alloc((size_t)128*4*4);
  float* hW2_c    = (float*)alloc((size_t)512*4);

  // transposed weights (split bf16 hi/lo, Npad x Kpad)
  auto allocW = [&](size_t elems, ushort_t*& h, ushort_t*& l){
    h = (ushort_t*)alloc(elems*2); l = (ushort_t*)alloc(elems*2);
  };
  ushort_t *b0_qkvTh,*b0_qkvTl,*b0_WoTh,*b0_WoTl,*b0_F1Th,*b0_F1Tl,*b0_F2Th,*b0_F2Tl;
  allocW((size_t)1472*736, b0_qkvTh, b0_qkvTl);
  allocW((size_t)768*480,  b0_WoTh,  b0_WoTl);
  allocW((size_t)512*736,  b0_F1Th,  b0_F1Tl);
  allocW((size_t)512*480,  b0_F2Th,  b0_F2Tl);
  ushort_t *bm_qkvTh[4],*bm_qkvTl[4],*bm_WoTh[4],*bm_WoTl[4],*bm_F1Th[4],*bm_F1Tl[4],*bm_F2Th[4],*bm_F2Tl[4];
  for (int i = 0; i < 4; ++i){
    allocW((size_t)1472*480, bm_qkvTh[i], bm_qkvTl[i]);
    allocW((size_t)512*480,  bm_WoTh[i],  bm_WoTl[i]);
    allocW((size_t)512*480,  bm_F1Th[i],  bm_F1Tl[i]);
    allocW((size_t)512*480,  bm_F2Th[i],  bm_F2Tl[i]);
  }
  ushort_t *bf_qkvTh,*bf_qkvTl,*bf_WoTh,*bf_WoTl,*bf_F1Th,*bf_F1Tl,*bf_F2Th,*bf_F2Tl,*hW1Th,*hW1Tl;
  allocW((size_t)1472*480, bf_qkvTh, bf_qkvTl);
  allocW((size_t)512*480,  bf_WoTh,  bf_WoTl);
  allocW((size_t)512*480,  bf_F1Th,  bf_F1Tl);
  allocW((size_t)512*480,  bf_F2Th,  bf_F2Tl);
  allocW((size_t)512*512,  hW1Th,    hW1Tl);

  detect_kernel<<<1, 256, 0, stream>>>((const ushort_t*)atom_table, dflag);

  CDescArr ca;
  int ci = 0;
  auto addC = [&](const void* s, float* d, int n){
    ca.d[ci].src = s; ca.d[ci].dst = d; ca.d[ci].n = n; ++ci;
  };
  addC(pos, pos_c, NN*3);
  addC(atom_table, atom_c, 64*DINJ);
  addC(degWr, degWr_c, 128*9);
  addC(degWsh, degWsh_c, 9*DINJ);
  addC(b0_Wsh, b0_Wsh_c, 9*480);
  addC(b0_Wr, b0_Wr_c, 128*4);
  addC(bm_Wsh, bm_Wsh_c, 4*9*480);
  addC(bm_Wr, bm_Wr_c, 4*128*4);
  addC(bf_Wsh, bf_Wsh_c, 9*480);
  addC(bf_Wr, bf_Wr_c, 128*4);
  addC(hW2, hW2_c, 512);
  convert_inputs<<<dim3(8, 11), 256, 0, stream>>>(ca, dflag);

  TDescArr ta;
  int ti = 0;
  auto addT = [&](const void* s, ushort_t* dh, ushort_t* dl, int K, int M,
                  int Kp, int Mp, int rowoff, int eo){
    ta.d[ti].src = s;
    ta.d[ti].dh = dh + (size_t)rowoff*Kp;
    ta.d[ti].dl = dl + (size_t)rowoff*Kp;
    ta.d[ti].K = K; ta.d[ti].M = M; ta.d[ti].Kpad = Kp; ta.d[ti].Mpad = Mp;
    ta.d[ti].eoff = eo; ++ti;
  };
  addT(b0_Wq, b0_qkvTh, b0_qkvTl, 720, 480, 736, 480, 0,   0);
  addT(b0_Wk, b0_qkvTh, b0_qkvTl, 720, 480, 736, 480, 480, 0);
  addT(b0_Wv, b0_qkvTh, b0_qkvTl, 720, 480, 736, 512, 960, 0);
  addT(b0_Wo, b0_WoTh,  b0_WoTl,  480, 720, 480, 768, 0,   0);
  addT(b0_F1, b0_F1Th,  b0_F1Tl,  720, 480, 736, 512, 0,   0);
  addT(b0_F2, b0_F2Th,  b0_F2Tl,  480, 480, 480, 512, 0,   0);
  for (int i = 0; i < 4; ++i){
    int eo = i*480*480;
    addT(bm_Wq, bm_qkvTh[i], bm_qkvTl[i], 480, 480, 480, 480, 0,   eo);
    addT(bm_Wk, bm_qkvTh[i], bm_qkvTl[i], 480, 480, 480, 480, 480, eo);
    addT(bm_Wv, bm_qkvTh[i], bm_qkvTl[i], 480, 480, 480, 512, 960, eo);
    addT(bm_Wo, bm_WoTh[i],  bm_WoTl[i],  480, 480, 480, 512, 0,   eo);
    addT(bm_F1, bm_F1Th[i],  bm_F1Tl[i],  480, 480, 480, 512, 0,   eo);
    addT(bm_F2, bm_F2Th[i],  bm_F2Tl[i],  480, 480, 480, 512, 0,   eo);
  }
  addT(bf_Wq, bf_qkvTh, bf_qkvTl, 480, 480, 480, 480, 0,   0);
  addT(bf_Wk, bf_qkvTh, bf_qkvTl, 480, 480, 480, 480, 480, 0);
  addT(bf_Wv, bf_qkvTh, bf_qkvTl, 480, 480, 480, 512, 960, 0);
  addT(bf_Wo, bf_WoTh,  bf_WoTl,  480, 480, 480, 512, 0,   0);
  addT(bf_F1, bf_F1Th,  bf_F1Tl,  480, 480, 480, 512, 0,   0);
  addT(bf_F2, bf_F2Th,  bf_F2Tl,  480, 512, 480, 512, 0,   0);
  addT(hW1,   hW1Th,    hW1Tl,    512, 512, 512, 512, 0,   0);
  transpose_all<<<dim3(23, 24, 37), 256, 0, stream>>>(ta, dflag);

  geom_kernel<<<NE/256, 256, 0, stream>>>(pos_c, esrc, edst, sh_f, dist);
  rbf_kernel<<<(NE*128)/256, 256, 0, stream>>>(dist, rbf_f);
  t9_kernel<<<(NE*9 + 255)/256, 256, 0, stream>>>(rbf_f, sh_f, degWr_c, t9);
  gate_kernel<<<dim3(NE/4, 6), 256, 0, stream>>>(rbf_f, b0_Wr_c, bm_Wr_c, bf_Wr_c, r_all);

  zero_f32<<<(2048 + 255)/256, 256, 0, stream>>>((float*)counts, 2048);
  hist_kernel<<<NE/256, 256, 0, stream>>>(edst, counts);
  scan_kernel<<<1, 1024, 0, stream>>>(counts, rowptr, cursor);
  scatter_kernel<<<NE/256, 256, 0, stream>>>(edst, cursor, perm);

  inj_kernel<<<NN, 64, 0, stream>>>(t9, rowptr, perm, node_atom, atom_c, degWsh_c, injb);
  zero_f32<<<(NN*DEMB)/256, 256, 0, stream>>>(zA, NN*DEMB);

  auto gemm = [&](const ushort_t* A, const ushort_t* BTh, const ushort_t* BTl,
                  int N, int Npad, int Kp, int ldc,
                  float* Cf, ushort_t* Cb, const float* R, int flags){
    dim3 g(Npad/64, 32);
    if (Kp == 480)
      gemm_bt<480><<<g, 256, 0, stream>>>(A, BTh, BTl, N, ldc, Cf, Cb, R, flags);
    else if (Kp == 512)
      gemm_bt<512><<<g, 256, 0, stream>>>(A, BTh, BTl, N, ldc, Cf, Cb, R, flags);
    else
      gemm_bt<736><<<g, 256, 0, stream>>>(A, BTh, BTl, N, ldc, Cf, Cb, R, flags);
  };

  struct BW {
    const float *Wsh, *r_slot;
    const ushort_t *qkvTh,*qkvTl,*WoTh,*WoTl,*F1Th,*F1Tl,*F2Th,*F2Tl;
    int Din, Kpad, Dout; bool res;
  };
  auto run_block = [&](const BW& bw, const float* zin, float* zout){
    ln_kernel<<<NN, 256, 0, stream>>>(zin, bw.Din, bw.Kpad, xlnh);
    gemm(xlnh, bw.qkvTh, bw.qkvTl, 1440, 1472, bw.Kpad, 1440,
         qkvb, nullptr, nullptr, 0);
    pq_kernel<<<NN, 256, 0, stream>>>(qkvb, bw.Wsh, Pq);
    edge_logit_kernel<<<NE/4, 256, 0, stream>>>(qkvb, sh_f, Pq, bw.r_slot,
                                                esrc, edst, logit);
    node_attn_kernel<<<NN, 256, 0, stream>>>(logit, bw.r_slot, qkvb, sh_f, bw.Wsh,
                                             rowptr, perm, esrc, aggh);
    int WoNpad = (bw.Din == 720) ? 768 : 512;
    gemm(aggh, bw.WoTh, bw.WoTl, bw.Din, WoNpad, 480, bw.Din,
         ybuf, nullptr, zin, 2);
    ln_kernel<<<NN, 256, 0, stream>>>(ybuf, bw.Din, bw.Kpad, xlnh);
    gemm(xlnh, bw.F1Th, bw.F1Tl, DEMB, 512, bw.Kpad, DEMB,
         nullptr, h1h, nullptr, 1|4);
    gemm(h1h, bw.F2Th, bw.F2Tl, bw.Dout, 512, 480, bw.Dout,
         zout, nullptr, bw.res ? ybuf : nullptr, bw.res ? 2 : 0);
  };

  BW b0 = { b0_Wsh_c, r_all + (size_t)0*NE*4,
            b0_qkvTh,b0_qkvTl,b0_WoTh,b0_WoTl,b0_F1Th,b0_F1Tl,b0_F2Th,b0_F2Tl,
            720, 736, 480, false };
  BW bm[4];
  for (int i = 0; i < 4; ++i){
    bm[i] = { bm_Wsh_c + (size_t)i*9*480, r_all + (size_t)(1+i)*NE*4,
              bm_qkvTh[i],bm_qkvTl[i],bm_WoTh[i],bm_WoTl[i],
              bm_F1Th[i],bm_F1Tl[i],bm_F2Th[i],bm_F2Tl[i],
              480, 480, 480, true };
  }
  BW bf = { bf_Wsh_c, r_all + (size_t)5*NE*4,
            bf_qkvTh,bf_qkvTl,bf_WoTh,bf_WoTl,bf_F1Th,bf_F1Tl,bf_F2Th,bf_F2Tl,
            480, 480, 512, false };

  float* z  = zA;
  float* z2 = zB;
  for (int iter = 0; iter < 2; ++iter){
    zcat_kernel<<<(NN*720)/256, 256, 0, stream>>>(z, injb, zcat);
    run_block(b0, zcat, z2);
    { float* tmp = z; z = z2; z2 = tmp; }
    for (int i = 0; i < 4; ++i){
      run_block(bm[i], z, z2);
      { float* tmp = z; z = z2; z2 = tmp; }
    }
  }
  run_block(bf, z, z2);
  ln_kernel<<<NN, 256, 0, stream>>>(z2, DFEAT, DFEAT, xlnh);
  gemm(xlnh, hW1Th, hW1Tl, DFEAT, 512, DFEAT, DFEAT,
       nullptr, g1h, nullptr, 1|4);
  zero_f32<<<1, 64, 0, stream>>>(gsum, 64);
  head_dot_kernel<<<NN/4, 256, 0, stream>>>(g1h, hW2_c, batch, gsum);
  finalize_kernel<<<1, 64, 0, stream>>>(gsum, dflag, d_out);
}

// Round 8
// 1698.325 us; speedup vs baseline: 1.5277x; 1.0198x over previous
//
#include <hip/hip_runtime.h>

#define NN 2048
#define NE 32768
#define NG 64
#define DINJ 240
#define DEMB 480
#define DFEAT 512

typedef unsigned short ushort_t;
typedef __attribute__((ext_vector_type(8))) short short8;
typedef __attribute__((ext_vector_type(4))) float floatx4;

__device__ __forceinline__ float b2f(ushort_t u){
  union { unsigned u; float f; } x; x.u = ((unsigned)u) << 16; return x.f;
}
__device__ __forceinline__ ushort_t f2b(float f){
  union { float f; unsigned u; } x; x.f = f;
  unsigned r = x.u + 0x7FFFu + ((x.u >> 16) & 1u);
  return (ushort_t)(r >> 16);
}
__device__ __forceinline__ float wredsum(float v){
  #pragma unroll
  for (int o = 32; o > 0; o >>= 1) v += __shfl_xor(v, o, 64);
  return v;
}
__device__ __forceinline__ float silu_f(float x){ return x / (1.f + __expf(-x)); }

// ---------------- small utility kernels ----------------
__global__ void zero_f32(float* p, int n){
  int i = blockIdx.x*256 + threadIdx.x; if (i < n) p[i] = 0.f;
}

// ---------------- input dtype detection ----------------
__global__ void detect_kernel(const ushort_t* __restrict__ probe, int* flag){
  __shared__ int c;
  if (threadIdx.x == 0) c = 0;
  __syncthreads();
  ushort_t u = probe[2*threadIdx.x];
  int e = (u >> 7) & 0xFF;
  int plausible = (u == 0) || (e >= 100 && e <= 140);
  atomicAdd(&c, plausible);
  __syncthreads();
  if (threadIdx.x == 0) *flag = (c >= 192) ? 0 : 1;
}

// -------- convert small float inputs -> internal FP32 (exact either way) ----
struct CDesc { const void* src; float* dst; int n; };
struct CDescArr { CDesc d[11]; };
__global__ __launch_bounds__(256) void convert_inputs(CDescArr ca, const int* __restrict__ flag){
  CDesc cd = ca.d[blockIdx.y];
  int isf32 = *flag;
  for (int i = blockIdx.x*256 + threadIdx.x; i < cd.n; i += gridDim.x*256){
    cd.dst[i] = isf32 ? ((const float*)cd.src)[i] : b2f(((const ushort_t*)cd.src)[i]);
  }
}

// --- LDS-tiled weight transpose: src (K x M row-major) -> dst (Mpad x Kpad) --
struct TDesc { const void* src; ushort_t* dh; ushort_t* dl; int K; int M; int Kpad; int Mpad; int eoff; };
struct TDescArr { TDesc d[37]; };
__global__ __launch_bounds__(256) void transpose_all(TDescArr ta, const int* __restrict__ flag){
  TDesc td = ta.d[blockIdx.z];
  int k0 = blockIdx.x*32, m0 = blockIdx.y*32;
  if (k0 >= td.Kpad || m0 >= td.Mpad) return;
  int isf32 = *flag;
  __shared__ float lds[32*33];
  int tx = threadIdx.x & 31, ty = threadIdx.x >> 5;
  #pragma unroll
  for (int r = 0; r < 4; ++r){
    int kl = ty + r*8;
    int k = k0 + kl, mm = m0 + tx;
    float x = 0.f;
    if (k < td.K && mm < td.M){
      size_t si = (size_t)td.eoff + (size_t)k*td.M + mm;
      x = isf32 ? ((const float*)td.src)[si] : b2f(((const ushort_t*)td.src)[si]);
    }
    lds[kl*33 + tx] = x;
  }
  __syncthreads();
  #pragma unroll
  for (int r = 0; r < 4; ++r){
    int nl = ty + r*8;
    int n = m0 + nl, k = k0 + tx;
    if (n < td.Mpad && k < td.Kpad){
      float x = lds[tx*33 + nl];
      ushort_t h = f2b(x);
      size_t di = (size_t)n*td.Kpad + k;
      td.dh[di] = h;
      td.dl[di] = f2b(x - b2f(h));
    }
  }
}

// ---------------- geometry (fp32 pos) ----------------
__global__ void geom_kernel(const float* __restrict__ pos,
                            const int* __restrict__ esrc, const int* __restrict__ edst,
                            float* __restrict__ sh, float* __restrict__ dist){
  int e = blockIdx.x*256 + threadIdx.x; if (e >= NE) return;
  int s = esrc[e], d = edst[e];
  float x = pos[s*3+0] - pos[d*3+0];
  float y = pos[s*3+1] - pos[d*3+1];
  float z = pos[s*3+2] - pos[d*3+2];
  float dd = sqrtf(x*x + y*y + z*z + 1e-12f);
  float ix = x/dd, iy = y/dd, iz = z/dd;
  const float s3 = 1.7320508075688772f, s15 = 3.872983346207417f, s5 = 2.23606797749979f;
  float* o = sh + (size_t)e*9;
  o[0] = 1.f; o[1] = s3*ix; o[2] = s3*iy; o[3] = s3*iz;
  o[4] = s15*ix*iy; o[5] = s15*iy*iz; o[6] = 0.5f*s5*(3.f*iz*iz - 1.f);
  o[7] = s15*ix*iz; o[8] = 0.5f*s15*(ix*ix - iy*iy);
  dist[e] = dd;
}

__global__ void rbf_kernel(const float* __restrict__ dist, float* __restrict__ rbf){
  int idx = blockIdx.x*256 + threadIdx.x; if (idx >= NE*128) return;
  int e = idx >> 7, r = idx & 127;
  float c = (float)r * (5.0f/127.0f);
  float u = (dist[e] - c) * (128.0f/5.0f);
  rbf[idx] = __expf(-0.5f*u*u);
}

__global__ void t9_kernel(const float* __restrict__ rbf, const float* __restrict__ sh,
                          const float* __restrict__ degWr, float* __restrict__ t9){
  int idx = blockIdx.x*256 + threadIdx.x; if (idx >= NE*9) return;
  int e = idx/9, j = idx - e*9;
  float s = 0.f;
  const float* rb = rbf + (size_t)e*128;
  for (int r = 0; r < 128; ++r) s += rb[r]*degWr[r*9+j];
  t9[idx] = sh[idx] * silu_f(s);
}

// ---- gate: thread-per-output. r_all[slot][e][h] = silu(rbf[e].Wr_slot[:,h]) -
__global__ __launch_bounds__(256) void gate_kernel(const float* __restrict__ rbf,
    const float* __restrict__ b0Wr, const float* __restrict__ bmWr,
    const float* __restrict__ bfWr, float* __restrict__ r_all){
  int idx = blockIdx.x*256 + threadIdx.x;       // = e*24 + o
  if (idx >= NE*24) return;
  int e = idx / 24, o = idx - e*24;
  int slot = o >> 2, h = o & 3;
  const float* Wr = (slot == 0) ? b0Wr : ((slot <= 4) ? bmWr + (size_t)(slot-1)*512 : bfWr);
  const float* rb = rbf + (size_t)e*128;
  float p = 0.f;
  #pragma unroll 8
  for (int k = 0; k < 128; ++k) p += rb[k]*Wr[k*4+h];
  r_all[((size_t)slot*NE + e)*4 + h] = silu_f(p);
}

// ---------------- CSR build ----------------
__global__ void hist_kernel(const int* __restrict__ edst, int* counts){
  int e = blockIdx.x*256 + threadIdx.x; if (e < NE) atomicAdd(&counts[edst[e]], 1);
}
__global__ __launch_bounds__(1024) void scan_kernel(const int* __restrict__ counts,
                                                    int* rowptr, int* cursor){
  __shared__ int s[1024];
  int t = threadIdx.x;
  int c0 = counts[2*t], c1 = counts[2*t+1];
  s[t] = c0 + c1;
  __syncthreads();
  for (int off = 1; off < 1024; off <<= 1){
    int v = (t >= off) ? s[t-off] : 0;
    __syncthreads();
    s[t] += v;
    __syncthreads();
  }
  int excl = s[t] - (c0 + c1);
  rowptr[2*t]   = excl;       cursor[2*t]   = excl;
  rowptr[2*t+1] = excl + c0;  cursor[2*t+1] = excl + c0;
  if (t == 1023) rowptr[2048] = s[1023];
}
__global__ void scatter_kernel(const int* __restrict__ edst, int* cursor, int* perm){
  int e = blockIdx.x*256 + threadIdx.x; if (e >= NE) return;
  int p = atomicAdd(&cursor[edst[e]], 1);
  perm[p] = e;
}

// ---------------- inj = atom_table[node_atom] + (sum_e t9) @ degWsh / 16 -----
__global__ __launch_bounds__(64) void inj_kernel(const float* __restrict__ t9,
    const int* __restrict__ rowptr, const int* __restrict__ perm,
    const int* __restrict__ node_atom, const float* __restrict__ atom_table,
    const float* __restrict__ degWsh, float* __restrict__ inj){
  int i = blockIdx.x; int lane = threadIdx.x;
  int b = rowptr[i], e = rowptr[i+1];
  float T[9];
  #pragma unroll
  for (int j = 0; j < 9; ++j) T[j] = 0.f;
  for (int idx = b; idx < e; ++idx){
    int ed = perm[idx];
    #pragma unroll
    for (int j = 0; j < 9; ++j) T[j] += t9[(size_t)ed*9+j];
  }
  int a = node_atom[i];
  for (int c = lane; c < DINJ; c += 64){
    float s = 0.f;
    #pragma unroll
    for (int j = 0; j < 9; ++j) s += T[j]*degWsh[j*DINJ+c];
    inj[(size_t)i*DINJ+c] = atom_table[(size_t)a*DINJ+c] + s*(1.0f/16.0f);
  }
}

// ---------------- zcat = [z | inj] ----------------
__global__ void zcat_kernel(const float* __restrict__ z, const float* __restrict__ inj,
                            float* __restrict__ zc){
  int i = blockIdx.x*256 + threadIdx.x; if (i >= NN*720) return;
  int n = i / 720, d = i - n*720;
  zc[i] = (d < DEMB) ? z[(size_t)n*DEMB + d] : inj[(size_t)n*DINJ + (d - DEMB)];
}

// ------- LayerNorm (fp32 in -> bf16 out, zero-padded to Kpad) ----------------
__global__ __launch_bounds__(256) void ln_kernel(const float* __restrict__ in, int D,
                                                 int Kpad, ushort_t* __restrict__ oh){
  int i = blockIdx.x; int t = threadIdx.x;
  const float* row = in + (size_t)i*D;
  float s = 0.f, sq = 0.f;
  for (int d = t; d < D; d += 256){ float x = row[d]; s += x; sq += x*x; }
  __shared__ float ls[4], lq[4];
  s = wredsum(s); sq = wredsum(sq);
  int lane = t & 63, w = t >> 6;
  if (lane == 0){ ls[w] = s; lq[w] = sq; }
  __syncthreads();
  s  = ls[0]+ls[1]+ls[2]+ls[3];
  sq = lq[0]+lq[1]+lq[2]+lq[3];
  float mu = s / (float)D;
  float var = fmaxf(sq / (float)D - mu*mu, 0.f);
  float rs = rsqrtf(var + 1e-6f);
  ushort_t* ohrow = oh + (size_t)i*Kpad;
  for (int d = t; d < D; d += 256) ohrow[d] = f2b((row[d]-mu)*rs);
  for (int d = D + t; d < Kpad; d += 256) ohrow[d] = 0;
}

// -- MFMA GEMM: C = A * (Bh+Bl)^T, software-pipelined (prefetch depth 1) ------
template<int KPAD>
__global__ __launch_bounds__(256) void gemm_bt(
    const ushort_t* __restrict__ A,
    const ushort_t* __restrict__ BTh, const ushort_t* __restrict__ BTl,
    int N, int ldc,
    float* __restrict__ Cf, ushort_t* __restrict__ Cb,
    const float* __restrict__ R, int flags){
  int lane = threadIdx.x & 63, wave = threadIdx.x >> 6;
  int row0 = blockIdx.y*64 + (wave>>1)*32;
  int col0 = blockIdx.x*64 + (wave&1)*32;
  int m = lane & 15, q4 = lane >> 4;
  size_t a0 = (size_t)(row0+m)*KPAD + q4*8;
  size_t a1 = a0 + (size_t)16*KPAD;
  size_t b0 = (size_t)(col0+m)*KPAD + q4*8;
  size_t b1 = b0 + (size_t)16*KPAD;
  floatx4 acc00 = {0,0,0,0}, acc01 = {0,0,0,0}, acc10 = {0,0,0,0}, acc11 = {0,0,0,0};
  constexpr int steps = KPAD >> 5;
  short8 cA0 = *(const short8*)(A + a0);
  short8 cA1 = *(const short8*)(A + a1);
  short8 cB0h = *(const short8*)(BTh + b0);
  short8 cB0l = *(const short8*)(BTl + b0);
  short8 cB1h = *(const short8*)(BTh + b1);
  short8 cB1l = *(const short8*)(BTl + b1);
  #pragma unroll
  for (int s = 0; s < steps; ++s){
    short8 nA0, nA1, nB0h, nB0l, nB1h, nB1l;
    if (s + 1 < steps){
      size_t o = (size_t)(s+1)*32;
      nA0  = *(const short8*)(A   + a0 + o);
      nA1  = *(const short8*)(A   + a1 + o);
      nB0h = *(const short8*)(BTh + b0 + o);
      nB0l = *(const short8*)(BTl + b0 + o);
      nB1h = *(const short8*)(BTh + b1 + o);
      nB1l = *(const short8*)(BTl + b1 + o);
    }
    acc00 = __builtin_amdgcn_mfma_f32_16x16x32_bf16(cA0, cB0h, acc00, 0, 0, 0);
    acc00 = __builtin_amdgcn_mfma_f32_16x16x32_bf16(cA0, cB0l, acc00, 0, 0, 0);
    acc01 = __builtin_amdgcn_mfma_f32_16x16x32_bf16(cA0, cB1h, acc01, 0, 0, 0);
    acc01 = __builtin_amdgcn_mfma_f32_16x16x32_bf16(cA0, cB1l, acc01, 0, 0, 0);
    acc10 = __builtin_amdgcn_mfma_f32_16x16x32_bf16(cA1, cB0h, acc10, 0, 0, 0);
    acc10 = __builtin_amdgcn_mfma_f32_16x16x32_bf16(cA1, cB0l, acc10, 0, 0, 0);
    acc11 = __builtin_amdgcn_mfma_f32_16x16x32_bf16(cA1, cB1h, acc11, 0, 0, 0);
    acc11 = __builtin_amdgcn_mfma_f32_16x16x32_bf16(cA1, cB1l, acc11, 0, 0, 0);
    cA0 = nA0; cA1 = nA1; cB0h = nB0h; cB0l = nB0l; cB1h = nB1h; cB1l = nB1l;
  }
  #pragma unroll
  for (int rr = 0; rr < 2; ++rr){
    #pragma unroll
    for (int cc = 0; cc < 2; ++cc){
      int col = col0 + cc*16 + m;
      if (col >= N) continue;
      floatx4 acc = rr ? (cc ? acc11 : acc10) : (cc ? acc01 : acc00);
      int rowb = row0 + rr*16 + q4*4;
      #pragma unroll
      for (int r = 0; r < 4; ++r){
        size_t idx = (size_t)(rowb + r)*ldc + col;
        float v = acc[r];
        if (flags & 2) v += R[idx];
        if (flags & 1) v = silu_f(v);
        if (flags & 4) Cb[idx] = f2b(v);
        else           Cf[idx] = v;
      }
    }
  }
}

// ------- Pq[i][h][j] = q_i(head h) . Wsh_j(head h), thread-per-output --------
__global__ __launch_bounds__(256) void pq_kernel(const float* __restrict__ qkv,
    const float* __restrict__ Wsh, float* __restrict__ Pq){
  int idx = blockIdx.x*256 + threadIdx.x;       // = i*36 + o
  if (idx >= NN*36) return;
  int i = idx / 36, o = idx - i*36;
  int h = o / 9, j = o - h*9;
  const float4* q = (const float4*)(qkv + (size_t)i*1440 + h*120);
  const float4* w = (const float4*)(Wsh + (size_t)j*DEMB + h*120);
  float p = 0.f;
  #pragma unroll
  for (int it = 0; it < 30; ++it){
    float4 qv = q[it], wv = w[it];
    p += qv.x*wv.x + qv.y*wv.y + qv.z*wv.z + qv.w*wv.w;
  }
  Pq[((size_t)i*4 + h)*9 + j] = p;
}

// ---------------- per-edge logit[e][h], thread-per-output --------------------
__global__ __launch_bounds__(256) void edge_logit_kernel(
    const float* __restrict__ qkv,
    const float* __restrict__ sh,
    const float* __restrict__ Pq, const float* __restrict__ r_slot,
    const int* __restrict__ esrc, const int* __restrict__ edst,
    float* __restrict__ logit){
  int idx = blockIdx.x*256 + threadIdx.x;       // = e*4 + h
  int e = idx >> 2, h = idx & 3;
  if (e >= NE) return;
  int s = esrc[e], dd = edst[e];
  const float4* q = (const float4*)(qkv + (size_t)dd*1440 + h*120);
  const float4* k = (const float4*)(qkv + (size_t)s*1440 + 480 + h*120);
  float p = 0.f;
  #pragma unroll
  for (int it = 0; it < 30; ++it){
    float4 qv = q[it], kv = k[it];
    p += qv.x*kv.x + qv.y*kv.y + qv.z*kv.z + qv.w*kv.w;
  }
  const float* pq = Pq + ((size_t)dd*4 + h)*9;
  const float* she = sh + (size_t)e*9;
  float mmq = 0.f;
  #pragma unroll
  for (int j = 0; j < 9; ++j) mmq += she[j]*pq[j];
  logit[e*4+h] = r_slot[e*4+h]*(p + mmq)*0.091287092917527686f;
}

// ------- per-node softmax + aggregation -> agg (bf16), 256 threads -----------
__global__ __launch_bounds__(256) void node_attn_kernel(
    const float* __restrict__ logit, const float* __restrict__ r_slot,
    const float* __restrict__ qkv, const float* __restrict__ sh,
    const float* __restrict__ Wsh,
    const int* __restrict__ rowptr, const int* __restrict__ perm,
    const int* __restrict__ esrc, ushort_t* __restrict__ aggh){
  int i = blockIdx.x; int t = threadIdx.x;
  int lane = t & 63, w = t >> 6;
  int b = rowptr[i]; int deg = rowptr[i+1] - b;
  __shared__ float mxs[4], dens[4];
  __shared__ float wbuf[64][5];
  __shared__ int srcbuf[64], ebuf[64];
  __shared__ float S[4][9];
  float mx = -1e30f;
  for (int idx = lane; idx < deg; idx += 64)
    mx = fmaxf(mx, logit[perm[b+idx]*4 + w]);
  #pragma unroll
  for (int o = 32; o > 0; o >>= 1) mx = fmaxf(mx, __shfl_xor(mx, o, 64));
  if (deg == 0) mx = 0.f;
  float den = 0.f;
  for (int idx = lane; idx < deg; idx += 64)
    den += __expf(logit[perm[b+idx]*4 + w] - mx);
  den = wredsum(den) + 1e-9f;
  if (lane == 0){ mxs[w] = mx; dens[w] = den; }
  if (t < 36) S[t/9][t - (t/9)*9] = 0.f;
  __syncthreads();

  const int d0 = 2*t;
  const int h2 = d0/120;
  float acc0 = 0.f, acc1 = 0.f;
  for (int c0 = 0; c0 < deg; c0 += 64){
    int cn = min(64, deg - c0);
    if (t < cn){
      int e = perm[b + c0 + t];
      ebuf[t] = e;
      srcbuf[t] = esrc[e];
      #pragma unroll
      for (int h = 0; h < 4; ++h)
        wbuf[t][h] = __expf(logit[e*4+h]-mxs[h]) / dens[h] * r_slot[e*4+h];
    }
    __syncthreads();
    if (t < 36){
      int h = t/9, j = t - h*9;
      float a = S[h][j];
      for (int le = 0; le < cn; ++le)
        a += wbuf[le][h] * sh[(size_t)ebuf[le]*9 + j];
      S[h][j] = a;
    }
    if (t < 240){
      for (int le = 0; le < cn; ++le){
        float wgt = wbuf[le][h2];
        const float2 vv = *(const float2*)(qkv + (size_t)srcbuf[le]*1440 + 960 + d0);
        acc0 += wgt*vv.x;
        acc1 += wgt*vv.y;
      }
    }
    __syncthreads();
  }
  if (t < 240){
    float mm0 = 0.f, mm1 = 0.f;
    #pragma unroll
    for (int j = 0; j < 9; ++j){
      mm0 += S[h2][j]*Wsh[j*DEMB + d0];
      mm1 += S[h2][j]*Wsh[j*DEMB + d0 + 1];
    }
    aggh[(size_t)i*DEMB + d0]     = f2b(acc0 + mm0);
    aggh[(size_t)i*DEMB + d0 + 1] = f2b(acc1 + mm1);
  }
}

// ---------------- head ----------------
__global__ __launch_bounds__(256) void head_dot_kernel(const ushort_t* __restrict__ g1h,
    const float* __restrict__ hW2, const int* __restrict__ batch, float* gsum){
  int i = blockIdx.x*4 + (threadIdx.x >> 6);
  int lane = threadIdx.x & 63;
  float s = 0.f;
  for (int d = lane; d < DFEAT; d += 64)
    s += b2f(g1h[(size_t)i*DFEAT + d]) * hW2[d];
  s = wredsum(s);
  if (lane == 0) atomicAdd(&gsum[batch[i]], s);
}
__global__ void finalize_kernel(const float* __restrict__ gsum,
                                const int* __restrict__ flag, void* out){
  int g = threadIdx.x;
  if (g < NG){
    float v = gsum[g] * 0.17677669529663687f; // 1/sqrt(32)
    if (*flag) ((float*)out)[g] = v;
    else       ((ushort_t*)out)[g] = f2b(v);
  }
}

// =====================================================================
extern "C" void kernel_launch(void* const* d_in, const int* in_sizes, int n_in,
                              void* d_out, int out_size, void* d_ws, size_t ws_size,
                              hipStream_t stream) {
  (void)in_sizes; (void)n_in; (void)out_size; (void)ws_size;
  const void* pos        = d_in[0];
  const int*  node_atom  = (const int*)d_in[1];
  const int*  esrc       = (const int*)d_in[2];
  const int*  edst       = (const int*)d_in[3];
  const int*  batch      = (const int*)d_in[4];
  const void* atom_table = d_in[5];
  const void* degWr      = d_in[6];
  const void* degWsh     = d_in[7];
  const void* b0_Wq  = d_in[8];
  const void* b0_Wk  = d_in[9];
  const void* b0_Wv  = d_in[10];
  const void* b0_Wsh = d_in[11];
  const void* b0_Wr  = d_in[12];
  const void* b0_Wo  = d_in[13];
  const void* b0_F1  = d_in[14];
  const void* b0_F2  = d_in[15];
  const void* bm_Wq  = d_in[16];
  const void* bm_Wk  = d_in[17];
  const void* bm_Wv  = d_in[18];
  const void* bm_Wsh = d_in[19];
  const void* bm_Wr  = d_in[20];
  const void* bm_Wo  = d_in[21];
  const void* bm_F1  = d_in[22];
  const void* bm_F2  = d_in[23];
  const void* bf_Wq  = d_in[24];
  const void* bf_Wk  = d_in[25];
  const void* bf_Wv  = d_in[26];
  const void* bf_Wsh = d_in[27];
  const void* bf_Wr  = d_in[28];
  const void* bf_Wo  = d_in[29];
  const void* bf_F1  = d_in[30];
  const void* bf_F2  = d_in[31];
  const void* hW1    = d_in[32];
  const void* hW2    = d_in[33];

  char* bws = (char*)d_ws;
  size_t off = 0;
  auto alloc = [&](size_t bytes) -> void* {
    void* p = bws + off;
    off += (bytes + 255) & ~(size_t)255;
    return p;
  };
  int* dflag   = (int*)alloc(256);
  float* sh_f  = (float*)alloc((size_t)NE*9*4);
  float* dist  = (float*)alloc((size_t)NE*4);
  float* rbf_f = (float*)alloc((size_t)NE*128*4);
  float* t9    = (float*)alloc((size_t)NE*9*4);
  int* counts  = (int*)alloc(2048*4);
  int* rowptr  = (int*)alloc(2049*4);
  int* cursor  = (int*)alloc(2048*4);
  int* perm    = (int*)alloc((size_t)NE*4);
  float* injb  = (float*)alloc((size_t)NN*DINJ*4);
  float* zA    = (float*)alloc((size_t)NN*512*4);
  float* zB    = (float*)alloc((size_t)NN*512*4);
  float* zcat  = (float*)alloc((size_t)NN*720*4);
  ushort_t* xlnh = (ushort_t*)alloc((size_t)NN*736*2);
  float* qkvb  = (float*)alloc((size_t)NN*1440*4);
  float* Pq    = (float*)alloc((size_t)NN*36*4);
  float* r_all = (float*)alloc((size_t)6*NE*4*4);
  float* logit = (float*)alloc((size_t)NE*4*4);
  ushort_t* aggh = (ushort_t*)alloc((size_t)NN*DEMB*2);
  float* ybuf  = (float*)alloc((size_t)NN*720*4);
  ushort_t* h1h = (ushort_t*)alloc((size_t)NN*DEMB*2);
  ushort_t* g1h = (ushort_t*)alloc((size_t)NN*DFEAT*2);
  float* gsum  = (float*)alloc(64*4);

  float* pos_c    = (float*)alloc((size_t)NN*3*4);
  float* atom_c   = (float*)alloc((size_t)64*DINJ*4);
  float* degWr_c  = (float*)alloc((size_t)128*9*4);
  float* degWsh_c = (float*)alloc((size_t)9*DINJ*4);
  float* b0_Wsh_c = (float*)alloc((size_t)9*480*4);
  float* b0_Wr_c  = (float*)alloc((size_t)128*4*4);
  float* bm_Wsh_c = (float*)alloc((size_t)4*9*480*4);
  float* bm_Wr_c  = (float*)alloc((size_t)4*128*4*4);
  float* bf_Wsh_c = (float*)alloc((size_t)9*480*4);
  float* bf_Wr_c  = (float*)alloc((size_t)128*4*4);
  float* hW2_c    = (float*)alloc((size_t)512*4);

  auto allocW = [&](size_t elems, ushort_t*& h, ushort_t*& l){
    h = (ushort_t*)alloc(elems*2); l = (ushort_t*)alloc(elems*2);
  };
  ushort_t *b0_qkvTh,*b0_qkvTl,*b0_WoTh,*b0_WoTl,*b0_F1Th,*b0_F1Tl,*b0_F2Th,*b0_F2Tl;
  allocW((size_t)1472*736, b0_qkvTh, b0_qkvTl);
  allocW((size_t)768*480,  b0_WoTh,  b0_WoTl);
  allocW((size_t)512*736,  b0_F1Th,  b0_F1Tl);
  allocW((size_t)512*480,  b0_F2Th,  b0_F2Tl);
  ushort_t *bm_qkvTh[4],*bm_qkvTl[4],*bm_WoTh[4],*bm_WoTl[4],*bm_F1Th[4],*bm_F1Tl[4],*bm_F2Th[4],*bm_F2Tl[4];
  for (int i = 0; i < 4; ++i){
    allocW((size_t)1472*480, bm_qkvTh[i], bm_qkvTl[i]);
    allocW((size_t)512*480,  bm_WoTh[i],  bm_WoTl[i]);
    allocW((size_t)512*480,  bm_F1Th[i],  bm_F1Tl[i]);
    allocW((size_t)512*480,  bm_F2Th[i],  bm_F2Tl[i]);
  }
  ushort_t *bf_qkvTh,*bf_qkvTl,*bf_WoTh,*bf_WoTl,*bf_F1Th,*bf_F1Tl,*bf_F2Th,*bf_F2Tl,*hW1Th,*hW1Tl;
  allocW((size_t)1472*480, bf_qkvTh, bf_qkvTl);
  allocW((size_t)512*480,  bf_WoTh,  bf_WoTl);
  allocW((size_t)512*480,  bf_F1Th,  bf_F1Tl);
  allocW((size_t)512*480,  bf_F2Th,  bf_F2Tl);
  allocW((size_t)512*512,  hW1Th,    hW1Tl);

  detect_kernel<<<1, 256, 0, stream>>>((const ushort_t*)atom_table, dflag);

  CDescArr ca;
  int ci = 0;
  auto addC = [&](const void* s, float* d, int n){
    ca.d[ci].src = s; ca.d[ci].dst = d; ca.d[ci].n = n; ++ci;
  };
  addC(pos, pos_c, NN*3);
  addC(atom_table, atom_c, 64*DINJ);
  addC(degWr, degWr_c, 128*9);
  addC(degWsh, degWsh_c, 9*DINJ);
  addC(b0_Wsh, b0_Wsh_c, 9*480);
  addC(b0_Wr, b0_Wr_c, 128*4);
  addC(bm_Wsh, bm_Wsh_c, 4*9*480);
  addC(bm_Wr, bm_Wr_c, 4*128*4);
  addC(bf_Wsh, bf_Wsh_c, 9*480);
  addC(bf_Wr, bf_Wr_c, 128*4);
  addC(hW2, hW2_c, 512);
  convert_inputs<<<dim3(8, 11), 256, 0, stream>>>(ca, dflag);

  TDescArr ta;
  int ti = 0;
  auto addT = [&](const void* s, ushort_t* dh, ushort_t* dl, int K, int M,
                  int Kp, int Mp, int rowoff, int eo){
    ta.d[ti].src = s;
    ta.d[ti].dh = dh + (size_t)rowoff*Kp;
    ta.d[ti].dl = dl + (size_t)rowoff*Kp;
    ta.d[ti].K = K; ta.d[ti].M = M; ta.d[ti].Kpad = Kp; ta.d[ti].Mpad = Mp;
    ta.d[ti].eoff = eo; ++ti;
  };
  addT(b0_Wq, b0_qkvTh, b0_qkvTl, 720, 480, 736, 480, 0,   0);
  addT(b0_Wk, b0_qkvTh, b0_qkvTl, 720, 480, 736, 480, 480, 0);
  addT(b0_Wv, b0_qkvTh, b0_qkvTl, 720, 480, 736, 512, 960, 0);
  addT(b0_Wo, b0_WoTh,  b0_WoTl,  480, 720, 480, 768, 0,   0);
  addT(b0_F1, b0_F1Th,  b0_F1Tl,  720, 480, 736, 512, 0,   0);
  addT(b0_F2, b0_F2Th,  b0_F2Tl,  480, 480, 480, 512, 0,   0);
  for (int i = 0; i < 4; ++i){
    int eo = i*480*480;
    addT(bm_Wq, bm_qkvTh[i], bm_qkvTl[i], 480, 480, 480, 480, 0,   eo);
    addT(bm_Wk, bm_qkvTh[i], bm_qkvTl[i], 480, 480, 480, 480, 480, eo);
    addT(bm_Wv, bm_qkvTh[i], bm_qkvTl[i], 480, 480, 480, 512, 960, eo);
    addT(bm_Wo, bm_WoTh[i],  bm_WoTl[i],  480, 480, 480, 512, 0,   eo);
    addT(bm_F1, bm_F1Th[i],  bm_F1Tl[i],  480, 480, 480, 512, 0,   eo);
    addT(bm_F2, bm_F2Th[i],  bm_F2Tl[i],  480, 480, 480, 512, 0,   eo);
  }
  addT(bf_Wq, bf_qkvTh, bf_qkvTl, 480, 480, 480, 480, 0,   0);
  addT(bf_Wk, bf_qkvTh, bf_qkvTl, 480, 480, 480, 480, 480, 0);
  addT(bf_Wv, bf_qkvTh, bf_qkvTl, 480, 480, 480, 512, 960, 0);
  addT(bf_Wo, bf_WoTh,  bf_WoTl,  480, 480, 480, 512, 0,   0);
  addT(bf_F1, bf_F1Th,  bf_F1Tl,  480, 480, 480, 512, 0,   0);
  addT(bf_F2, bf_F2Th,  bf_F2Tl,  480, 512, 480, 512, 0,   0);
  addT(hW1,   hW1Th,    hW1Tl,    512, 512, 512, 512, 0,   0);
  transpose_all<<<dim3(23, 24, 37), 256, 0, stream>>>(ta, dflag);

  geom_kernel<<<NE/256, 256, 0, stream>>>(pos_c, esrc, edst, sh_f, dist);
  rbf_kernel<<<(NE*128)/256, 256, 0, stream>>>(dist, rbf_f);
  t9_kernel<<<(NE*9 + 255)/256, 256, 0, stream>>>(rbf_f, sh_f, degWr_c, t9);
  gate_kernel<<<(NE*24)/256, 256, 0, stream>>>(rbf_f, b0_Wr_c, bm_Wr_c, bf_Wr_c, r_all);

  zero_f32<<<(2048 + 255)/256, 256, 0, stream>>>((float*)counts, 2048);
  hist_kernel<<<NE/256, 256, 0, stream>>>(edst, counts);
  scan_kernel<<<1, 1024, 0, stream>>>(counts, rowptr, cursor);
  scatter_kernel<<<NE/256, 256, 0, stream>>>(edst, cursor, perm);

  inj_kernel<<<NN, 64, 0, stream>>>(t9, rowptr, perm, node_atom, atom_c, degWsh_c, injb);
  zero_f32<<<(NN*DEMB)/256, 256, 0, stream>>>(zA, NN*DEMB);

  auto gemm = [&](const ushort_t* A, const ushort_t* BTh, const ushort_t* BTl,
                  int N, int Npad, int Kp, int ldc,
                  float* Cf, ushort_t* Cb, const float* R, int flags){
    dim3 g(Npad/64, 32);
    if (Kp == 480)
      gemm_bt<480><<<g, 256, 0, stream>>>(A, BTh, BTl, N, ldc, Cf, Cb, R, flags);
    else if (Kp == 512)
      gemm_bt<512><<<g, 256, 0, stream>>>(A, BTh, BTl, N, ldc, Cf, Cb, R, flags);
    else
      gemm_bt<736><<<g, 256, 0, stream>>>(A, BTh, BTl, N, ldc, Cf, Cb, R, flags);
  };

  struct BW {
    const float *Wsh, *r_slot;
    const ushort_t *qkvTh,*qkvTl,*WoTh,*WoTl,*F1Th,*F1Tl,*F2Th,*F2Tl;
    int Din, Kpad, Dout; bool res;
  };
  auto run_block = [&](const BW& bw, const float* zin, float* zout){
    ln_kernel<<<NN, 256, 0, stream>>>(zin, bw.Din, bw.Kpad, xlnh);
    gemm(xlnh, bw.qkvTh, bw.qkvTl, 1440, 1472, bw.Kpad, 1440,
         qkvb, nullptr, nullptr, 0);
    pq_kernel<<<(NN*36 + 255)/256, 256, 0, stream>>>(qkvb, bw.Wsh, Pq);
    edge_logit_kernel<<<(NE*4)/256, 256, 0, stream>>>(qkvb, sh_f, Pq, bw.r_slot,
                                                      esrc, edst, logit);
    node_attn_kernel<<<NN, 256, 0, stream>>>(logit, bw.r_slot, qkvb, sh_f, bw.Wsh,
                                             rowptr, perm, esrc, aggh);
    int WoNpad = (bw.Din == 720) ? 768 : 512;
    gemm(aggh, bw.WoTh, bw.WoTl, bw.Din, WoNpad, 480, bw.Din,
         ybuf, nullptr, zin, 2);
    ln_kernel<<<NN, 256, 0, stream>>>(ybuf, bw.Din, bw.Kpad, xlnh);
    gemm(xlnh, bw.F1Th, bw.F1Tl, DEMB, 512, bw.Kpad, DEMB,
         nullptr, h1h, nullptr, 1|4);
    gemm(h1h, bw.F2Th, bw.F2Tl, bw.Dout, 512, 480, bw.Dout,
         zout, nullptr, bw.res ? ybuf : nullptr, bw.res ? 2 : 0);
  };

  BW b0 = { b0_Wsh_c, r_all + (size_t)0*NE*4,
            b0_qkvTh,b0_qkvTl,b0_WoTh,b0_WoTl,b0_F1Th,b0_F1Tl,b0_F2Th,b0_F2Tl,
            720, 736, 480, false };
  BW bm[4];
  for (int i = 0; i < 4; ++i){
    bm[i] = { bm_Wsh_c + (size_t)i*9*480, r_all + (size_t)(1+i)*NE*4,
              bm_qkvTh[i],bm_qkvTl[i],bm_WoTh[i],bm_WoTl[i],
              bm_F1Th[i],bm_F1Tl[i],bm_F2Th[i],bm_F2Tl[i],
              480, 480, 480, true };
  }
  BW bf = { bf_Wsh_c, r_all + (size_t)5*NE*4,
            bf_qkvTh,bf_qkvTl,bf_WoTh,bf_WoTl,bf_F1Th,bf_F1Tl,bf_F2Th,bf_F2Tl,
            480, 480, 512, false };

  float* z  = zA;
  float* z2 = zB;
  for (int iter = 0; iter < 2; ++iter){
    zcat_kernel<<<(NN*720)/256, 256, 0, stream>>>(z, injb, zcat);
    run_block(b0, zcat, z2);
    { float* tmp = z; z = z2; z2 = tmp; }
    for (int i = 0; i < 4; ++i){
      run_block(bm[i], z, z2);
      { float* tmp = z; z = z2; z2 = tmp; }
    }
  }
  run_block(bf, z, z2);
  ln_kernel<<<NN, 256, 0, stream>>>(z2, DFEAT, DFEAT, xlnh);
  gemm(xlnh, hW1Th, hW1Tl, DFEAT, 512, DFEAT, DFEAT,
       nullptr, g1h, nullptr, 1|4);
  zero_f32<<<1, 64, 0, stream>>>(gsum, 64);
  head_dot_kernel<<<NN/4, 256, 0, stream>>>(g1h, hW2_c, batch, gsum);
  finalize_kernel<<<1, 64, 0, stream>>>(gsum, dflag, d_out);
}

// Round 9
// 1489.483 us; speedup vs baseline: 1.7419x; 1.1402x over previous
//
#include <hip/hip_runtime.h>

#define NN 2048
#define NE 32768
#define NG 64
#define DINJ 240
#define DEMB 480
#define DFEAT 512
#define MAXDEG 192

typedef unsigned short ushort_t;
typedef __attribute__((ext_vector_type(8))) short short8;
typedef __attribute__((ext_vector_type(4))) float floatx4;

__device__ __forceinline__ float b2f(ushort_t u){
  union { unsigned u; float f; } x; x.u = ((unsigned)u) << 16; return x.f;
}
__device__ __forceinline__ ushort_t f2b(float f){
  union { float f; unsigned u; } x; x.f = f;
  unsigned r = x.u + 0x7FFFu + ((x.u >> 16) & 1u);
  return (ushort_t)(r >> 16);
}
__device__ __forceinline__ float wredsum(float v){
  #pragma unroll
  for (int o = 32; o > 0; o >>= 1) v += __shfl_xor(v, o, 64);
  return v;
}
__device__ __forceinline__ float silu_f(float x){ return x / (1.f + __expf(-x)); }

// ---------------- small utility kernels ----------------
__global__ void zero_f32(float* p, int n){
  int i = blockIdx.x*256 + threadIdx.x; if (i < n) p[i] = 0.f;
}

// ---------------- input dtype detection ----------------
__global__ void detect_kernel(const ushort_t* __restrict__ probe, int* flag){
  __shared__ int c;
  if (threadIdx.x == 0) c = 0;
  __syncthreads();
  ushort_t u = probe[2*threadIdx.x];
  int e = (u >> 7) & 0xFF;
  int plausible = (u == 0) || (e >= 100 && e <= 140);
  atomicAdd(&c, plausible);
  __syncthreads();
  if (threadIdx.x == 0) *flag = (c >= 192) ? 0 : 1;
}

// -------- convert small float inputs -> internal FP32 (exact either way) ----
struct CDesc { const void* src; float* dst; int n; };
struct CDescArr { CDesc d[11]; };
__global__ __launch_bounds__(256) void convert_inputs(CDescArr ca, const int* __restrict__ flag){
  CDesc cd = ca.d[blockIdx.y];
  int isf32 = *flag;
  for (int i = blockIdx.x*256 + threadIdx.x; i < cd.n; i += gridDim.x*256){
    cd.dst[i] = isf32 ? ((const float*)cd.src)[i] : b2f(((const ushort_t*)cd.src)[i]);
  }
}

// --- LDS-tiled weight transpose: src (K x M row-major) -> dst (Mpad x Kpad) --
struct TDesc { const void* src; ushort_t* dh; ushort_t* dl; int K; int M; int Kpad; int Mpad; int eoff; };
struct TDescArr { TDesc d[37]; };
__global__ __launch_bounds__(256) void transpose_all(TDescArr ta, const int* __restrict__ flag){
  TDesc td = ta.d[blockIdx.z];
  int k0 = blockIdx.x*32, m0 = blockIdx.y*32;
  if (k0 >= td.Kpad || m0 >= td.Mpad) return;
  int isf32 = *flag;
  __shared__ float lds[32*33];
  int tx = threadIdx.x & 31, ty = threadIdx.x >> 5;
  #pragma unroll
  for (int r = 0; r < 4; ++r){
    int kl = ty + r*8;
    int k = k0 + kl, mm = m0 + tx;
    float x = 0.f;
    if (k < td.K && mm < td.M){
      size_t si = (size_t)td.eoff + (size_t)k*td.M + mm;
      x = isf32 ? ((const float*)td.src)[si] : b2f(((const ushort_t*)td.src)[si]);
    }
    lds[kl*33 + tx] = x;
  }
  __syncthreads();
  #pragma unroll
  for (int r = 0; r < 4; ++r){
    int nl = ty + r*8;
    int n = m0 + nl, k = k0 + tx;
    if (n < td.Mpad && k < td.Kpad){
      float x = lds[tx*33 + nl];
      ushort_t h = f2b(x);
      size_t di = (size_t)n*td.Kpad + k;
      td.dh[di] = h;
      td.dl[di] = f2b(x - b2f(h));
    }
  }
}

// ---------------- geometry (fp32 pos) ----------------
__global__ void geom_kernel(const float* __restrict__ pos,
                            const int* __restrict__ esrc, const int* __restrict__ edst,
                            float* __restrict__ sh, float* __restrict__ dist){
  int e = blockIdx.x*256 + threadIdx.x; if (e >= NE) return;
  int s = esrc[e], d = edst[e];
  float x = pos[s*3+0] - pos[d*3+0];
  float y = pos[s*3+1] - pos[d*3+1];
  float z = pos[s*3+2] - pos[d*3+2];
  float dd = sqrtf(x*x + y*y + z*z + 1e-12f);
  float ix = x/dd, iy = y/dd, iz = z/dd;
  const float s3 = 1.7320508075688772f, s15 = 3.872983346207417f, s5 = 2.23606797749979f;
  float* o = sh + (size_t)e*9;
  o[0] = 1.f; o[1] = s3*ix; o[2] = s3*iy; o[3] = s3*iz;
  o[4] = s15*ix*iy; o[5] = s15*iy*iz; o[6] = 0.5f*s5*(3.f*iz*iz - 1.f);
  o[7] = s15*ix*iz; o[8] = 0.5f*s15*(ix*ix - iy*iy);
  dist[e] = dd;
}

__global__ void rbf_kernel(const float* __restrict__ dist, float* __restrict__ rbf){
  int idx = blockIdx.x*256 + threadIdx.x; if (idx >= NE*128) return;
  int e = idx >> 7, r = idx & 127;
  float c = (float)r * (5.0f/127.0f);
  float u = (dist[e] - c) * (128.0f/5.0f);
  rbf[idx] = __expf(-0.5f*u*u);
}

__global__ void t9_kernel(const float* __restrict__ rbf, const float* __restrict__ sh,
                          const float* __restrict__ degWr, float* __restrict__ t9){
  int idx = blockIdx.x*256 + threadIdx.x; if (idx >= NE*9) return;
  int e = idx/9, j = idx - e*9;
  float s = 0.f;
  const float* rb = rbf + (size_t)e*128;
  for (int r = 0; r < 128; ++r) s += rb[r]*degWr[r*9+j];
  t9[idx] = sh[idx] * silu_f(s);
}

// ---- pack 6 Wr slots into Wr_all[128][24] (k-major, o=slot*4+h inner) ------
__global__ void pack_wr(const float* __restrict__ b0Wr, const float* __restrict__ bmWr,
                        const float* __restrict__ bfWr, float* __restrict__ Wr_all){
  int idx = blockIdx.x*256 + threadIdx.x; if (idx >= 128*24) return;
  int k = idx / 24, o = idx - k*24;
  int slot = o >> 2, h = o & 3;
  const float* Wr = (slot == 0) ? b0Wr : ((slot <= 4) ? bmWr + (size_t)(slot-1)*512 : bfWr);
  Wr_all[idx] = Wr[k*4+h];
}

// ---- gate v3: thread-per-edge, 24 outputs; Wr via wave-uniform (scalar) ----
__global__ __launch_bounds__(256) void gate_kernel(const float* __restrict__ rbf,
    const float* __restrict__ Wr_all, float* __restrict__ r_all){
  int e = blockIdx.x*256 + threadIdx.x; if (e >= NE) return;
  const float4* rb4 = (const float4*)(rbf + (size_t)e*128);
  float acc[24];
  #pragma unroll
  for (int o = 0; o < 24; ++o) acc[o] = 0.f;
  for (int k4 = 0; k4 < 32; ++k4){
    float4 r = rb4[k4];
    const float* w = Wr_all + k4*96;
    #pragma unroll
    for (int o = 0; o < 24; ++o)
      acc[o] += r.x*w[o] + r.y*w[24+o] + r.z*w[48+o] + r.w*w[72+o];
  }
  #pragma unroll
  for (int o = 0; o < 24; ++o){
    int slot = o >> 2, h = o & 3;
    r_all[((size_t)slot*NE + e)*4 + h] = silu_f(acc[o]);
  }
}

// ---------------- CSR build ----------------
__global__ void hist_kernel(const int* __restrict__ edst, int* counts){
  int e = blockIdx.x*256 + threadIdx.x; if (e < NE) atomicAdd(&counts[edst[e]], 1);
}
__global__ __launch_bounds__(1024) void scan_kernel(const int* __restrict__ counts,
                                                    int* rowptr, int* cursor){
  __shared__ int s[1024];
  int t = threadIdx.x;
  int c0 = counts[2*t], c1 = counts[2*t+1];
  s[t] = c0 + c1;
  __syncthreads();
  for (int off = 1; off < 1024; off <<= 1){
    int v = (t >= off) ? s[t-off] : 0;
    __syncthreads();
    s[t] += v;
    __syncthreads();
  }
  int excl = s[t] - (c0 + c1);
  rowptr[2*t]   = excl;       cursor[2*t]   = excl;
  rowptr[2*t+1] = excl + c0;  cursor[2*t+1] = excl + c0;
  if (t == 1023) rowptr[2048] = s[1023];
}
__global__ void scatter_kernel(const int* __restrict__ edst, int* cursor, int* perm){
  int e = blockIdx.x*256 + threadIdx.x; if (e >= NE) return;
  int p = atomicAdd(&cursor[edst[e]], 1);
  perm[p] = e;
}

// ---------------- inj = atom_table[node_atom] + (sum_e t9) @ degWsh / 16 -----
__global__ __launch_bounds__(64) void inj_kernel(const float* __restrict__ t9,
    const int* __restrict__ rowptr, const int* __restrict__ perm,
    const int* __restrict__ node_atom, const float* __restrict__ atom_table,
    const float* __restrict__ degWsh, float* __restrict__ inj){
  int i = blockIdx.x; int lane = threadIdx.x;
  int b = rowptr[i], e = rowptr[i+1];
  float T[9];
  #pragma unroll
  for (int j = 0; j < 9; ++j) T[j] = 0.f;
  for (int idx = b; idx < e; ++idx){
    int ed = perm[idx];
    #pragma unroll
    for (int j = 0; j < 9; ++j) T[j] += t9[(size_t)ed*9+j];
  }
  int a = node_atom[i];
  for (int c = lane; c < DINJ; c += 64){
    float s = 0.f;
    #pragma unroll
    for (int j = 0; j < 9; ++j) s += T[j]*degWsh[j*DINJ+c];
    inj[(size_t)i*DINJ+c] = atom_table[(size_t)a*DINJ+c] + s*(1.0f/16.0f);
  }
}

// ---------------- zcat = [z | inj] ----------------
__global__ void zcat_kernel(const float* __restrict__ z, const float* __restrict__ inj,
                            float* __restrict__ zc){
  int i = blockIdx.x*256 + threadIdx.x; if (i >= NN*720) return;
  int n = i / 720, d = i - n*720;
  zc[i] = (d < DEMB) ? z[(size_t)n*DEMB + d] : inj[(size_t)n*DINJ + (d - DEMB)];
}

// ------- LayerNorm: one wave per row, 4 rows per block -----------------------
__global__ __launch_bounds__(256) void ln_kernel(const float* __restrict__ in, int D,
                                                 int Kpad, ushort_t* __restrict__ oh){
  int i = blockIdx.x*4 + (threadIdx.x >> 6);
  int lane = threadIdx.x & 63;
  const float* row = in + (size_t)i*D;
  float s = 0.f, sq = 0.f;
  for (int d = lane; d < D; d += 64){ float x = row[d]; s += x; sq += x*x; }
  s = wredsum(s); sq = wredsum(sq);
  float mu = s / (float)D;
  float var = fmaxf(sq / (float)D - mu*mu, 0.f);
  float rs = rsqrtf(var + 1e-6f);
  ushort_t* ohrow = oh + (size_t)i*Kpad;
  for (int d = lane; d < D; d += 64) ohrow[d] = f2b((row[d]-mu)*rs);
  for (int d = D + lane; d < Kpad; d += 64) ohrow[d] = 0;
}

// -- MFMA GEMM: C = A * (Bh+Bl)^T, software-pipelined (prefetch depth 1) ------
template<int KPAD>
__global__ __launch_bounds__(256) void gemm_bt(
    const ushort_t* __restrict__ A,
    const ushort_t* __restrict__ BTh, const ushort_t* __restrict__ BTl,
    int N, int ldc,
    float* __restrict__ Cf, ushort_t* __restrict__ Cb,
    const float* __restrict__ R, int flags){
  int lane = threadIdx.x & 63, wave = threadIdx.x >> 6;
  int row0 = blockIdx.y*64 + (wave>>1)*32;
  int col0 = blockIdx.x*64 + (wave&1)*32;
  int m = lane & 15, q4 = lane >> 4;
  size_t a0 = (size_t)(row0+m)*KPAD + q4*8;
  size_t a1 = a0 + (size_t)16*KPAD;
  size_t b0 = (size_t)(col0+m)*KPAD + q4*8;
  size_t b1 = b0 + (size_t)16*KPAD;
  floatx4 acc00 = {0,0,0,0}, acc01 = {0,0,0,0}, acc10 = {0,0,0,0}, acc11 = {0,0,0,0};
  constexpr int steps = KPAD >> 5;
  short8 cA0 = *(const short8*)(A + a0);
  short8 cA1 = *(const short8*)(A + a1);
  short8 cB0h = *(const short8*)(BTh + b0);
  short8 cB0l = *(const short8*)(BTl + b0);
  short8 cB1h = *(const short8*)(BTh + b1);
  short8 cB1l = *(const short8*)(BTl + b1);
  #pragma unroll
  for (int s = 0; s < steps; ++s){
    short8 nA0, nA1, nB0h, nB0l, nB1h, nB1l;
    if (s + 1 < steps){
      size_t o = (size_t)(s+1)*32;
      nA0  = *(const short8*)(A   + a0 + o);
      nA1  = *(const short8*)(A   + a1 + o);
      nB0h = *(const short8*)(BTh + b0 + o);
      nB0l = *(const short8*)(BTl + b0 + o);
      nB1h = *(const short8*)(BTh + b1 + o);
      nB1l = *(const short8*)(BTl + b1 + o);
    }
    acc00 = __builtin_amdgcn_mfma_f32_16x16x32_bf16(cA0, cB0h, acc00, 0, 0, 0);
    acc00 = __builtin_amdgcn_mfma_f32_16x16x32_bf16(cA0, cB0l, acc00, 0, 0, 0);
    acc01 = __builtin_amdgcn_mfma_f32_16x16x32_bf16(cA0, cB1h, acc01, 0, 0, 0);
    acc01 = __builtin_amdgcn_mfma_f32_16x16x32_bf16(cA0, cB1l, acc01, 0, 0, 0);
    acc10 = __builtin_amdgcn_mfma_f32_16x16x32_bf16(cA1, cB0h, acc10, 0, 0, 0);
    acc10 = __builtin_amdgcn_mfma_f32_16x16x32_bf16(cA1, cB0l, acc10, 0, 0, 0);
    acc11 = __builtin_amdgcn_mfma_f32_16x16x32_bf16(cA1, cB1h, acc11, 0, 0, 0);
    acc11 = __builtin_amdgcn_mfma_f32_16x16x32_bf16(cA1, cB1l, acc11, 0, 0, 0);
    cA0 = nA0; cA1 = nA1; cB0h = nB0h; cB0l = nB0l; cB1h = nB1h; cB1l = nB1l;
  }
  #pragma unroll
  for (int rr = 0; rr < 2; ++rr){
    #pragma unroll
    for (int cc = 0; cc < 2; ++cc){
      int col = col0 + cc*16 + m;
      if (col >= N) continue;
      floatx4 acc = rr ? (cc ? acc11 : acc10) : (cc ? acc01 : acc00);
      int rowb = row0 + rr*16 + q4*4;
      #pragma unroll
      for (int r = 0; r < 4; ++r){
        size_t idx = (size_t)(rowb + r)*ldc + col;
        float v = acc[r];
        if (flags & 2) v += R[idx];
        if (flags & 1) v = silu_f(v);
        if (flags & 4) Cb[idx] = f2b(v);
        else           Cf[idx] = v;
      }
    }
  }
}

// ------- fused per-node attention: logits + softmax + aggregation ------------
__global__ __launch_bounds__(256) void node_attn_kernel(
    const float* __restrict__ qkv, const float* __restrict__ sh,
    const float* __restrict__ Wsh, const float* __restrict__ r_slot,
    const int* __restrict__ rowptr, const int* __restrict__ perm,
    const int* __restrict__ esrc, ushort_t* __restrict__ aggh){
  int i = blockIdx.x; int t = threadIdx.x;
  int lane = t & 63, w = t >> 6;
  int b = rowptr[i]; int deg = min(rowptr[i+1] - b, MAXDEG);
  __shared__ float qL[480];
  __shared__ float PqL[36];
  __shared__ float logitL[MAXDEG*4];
  __shared__ float rL[MAXDEG*4];
  __shared__ int eL[MAXDEG], srcL[MAXDEG];
  __shared__ float S[36];
  __shared__ float mxs[4], dens[4];
  // stage q row + edge ids
  for (int d = t; d < 480; d += 256) qL[d] = qkv[(size_t)i*1440 + d];
  for (int idx = t; idx < deg; idx += 256){
    int e = perm[b+idx];
    eL[idx] = e;
    srcL[idx] = esrc[e];
  }
  __syncthreads();
  // Pq[h][j] = q(head h) . Wsh_j(head h)
  if (t < 36){
    int h = t/9, j = t - h*9;
    const float* ws = Wsh + (size_t)j*DEMB + h*120;
    const float* qh = qL + h*120;
    float p = 0.f;
    for (int k = 0; k < 120; ++k) p += qh[k]*ws[k];
    PqL[t] = p;
  }
  __syncthreads();
  // logits: 4 threads per edge
  const float inv = 0.091287092917527686f;
  for (int base = 0; base < deg; base += 64){
    int idx = base + (t >> 2);
    if (idx < deg){
      int h = t & 3;
      int e = eL[idx], s = srcL[idx];
      const float4* kk = (const float4*)(qkv + (size_t)s*1440 + 480 + h*120);
      const float4* qq = (const float4*)(qL + h*120);
      float p = 0.f;
      #pragma unroll
      for (int it = 0; it < 30; ++it){
        float4 a = qq[it], bb = kk[it];
        p += a.x*bb.x + a.y*bb.y + a.z*bb.z + a.w*bb.w;
      }
      float mmq = 0.f;
      const float* she = sh + (size_t)e*9;
      #pragma unroll
      for (int j = 0; j < 9; ++j) mmq += she[j]*PqL[h*9+j];
      float rr = r_slot[(size_t)e*4+h];
      rL[idx*4+h] = rr;
      logitL[idx*4+h] = rr*(p + mmq)*inv;
    }
  }
  __syncthreads();
  // softmax: wave w handles head w
  float mx = -1e30f;
  for (int idx = lane; idx < deg; idx += 64) mx = fmaxf(mx, logitL[idx*4+w]);
  #pragma unroll
  for (int o = 32; o > 0; o >>= 1) mx = fmaxf(mx, __shfl_xor(mx, o, 64));
  if (deg == 0) mx = 0.f;
  float den = 0.f;
  for (int idx = lane; idx < deg; idx += 64) den += __expf(logitL[idx*4+w]-mx);
  den = wredsum(den) + 1e-9f;
  if (lane == 0){ mxs[w] = mx; dens[w] = den; }
  __syncthreads();
  // weights in place
  for (int j = t; j < deg*4; j += 256){
    int h = j & 3;
    logitL[j] = __expf(logitL[j]-mxs[h]) / dens[h] * rL[j];
  }
  __syncthreads();
  // S (threads 240..255) and v-aggregation (threads 0..239) in parallel
  float a0 = 0.f, a1 = 0.f;
  int d0 = 2*t, h2 = d0/120;
  if (t >= 240){
    for (int o = t - 240; o < 36; o += 16){
      int h = o/9, j = o - h*9;
      float a = 0.f;
      for (int idx = 0; idx < deg; ++idx)
        a += logitL[idx*4+h]*sh[(size_t)eL[idx]*9+j];
      S[o] = a;
    }
  } else {
    for (int idx = 0; idx < deg; ++idx){
      float wgt = logitL[idx*4+h2];
      float2 vv = *(const float2*)(qkv + (size_t)srcL[idx]*1440 + 960 + d0);
      a0 += wgt*vv.x; a1 += wgt*vv.y;
    }
  }
  __syncthreads();
  if (t < 240){
    float mm0 = 0.f, mm1 = 0.f;
    #pragma unroll
    for (int j = 0; j < 9; ++j){
      mm0 += S[h2*9+j]*Wsh[j*DEMB + d0];
      mm1 += S[h2*9+j]*Wsh[j*DEMB + d0 + 1];
    }
    aggh[(size_t)i*DEMB + d0]     = f2b(a0 + mm0);
    aggh[(size_t)i*DEMB + d0 + 1] = f2b(a1 + mm1);
  }
}

// ---------------- head ----------------
__global__ __launch_bounds__(256) void head_dot_kernel(const ushort_t* __restrict__ g1h,
    const float* __restrict__ hW2, const int* __restrict__ batch, float* gsum){
  int i = blockIdx.x*4 + (threadIdx.x >> 6);
  int lane = threadIdx.x & 63;
  float s = 0.f;
  for (int d = lane; d < DFEAT; d += 64)
    s += b2f(g1h[(size_t)i*DFEAT + d]) * hW2[d];
  s = wredsum(s);
  if (lane == 0) atomicAdd(&gsum[batch[i]], s);
}
__global__ void finalize_kernel(const float* __restrict__ gsum,
                                const int* __restrict__ flag, void* out){
  int g = threadIdx.x;
  if (g < NG){
    float v = gsum[g] * 0.17677669529663687f; // 1/sqrt(32)
    if (*flag) ((float*)out)[g] = v;
    else       ((ushort_t*)out)[g] = f2b(v);
  }
}

// =====================================================================
extern "C" void kernel_launch(void* const* d_in, const int* in_sizes, int n_in,
                              void* d_out, int out_size, void* d_ws, size_t ws_size,
                              hipStream_t stream) {
  (void)in_sizes; (void)n_in; (void)out_size; (void)ws_size;
  const void* pos        = d_in[0];
  const int*  node_atom  = (const int*)d_in[1];
  const int*  esrc       = (const int*)d_in[2];
  const int*  edst       = (const int*)d_in[3];
  const int*  batch      = (const int*)d_in[4];
  const void* atom_table = d_in[5];
  const void* degWr      = d_in[6];
  const void* degWsh     = d_in[7];
  const void* b0_Wq  = d_in[8];
  const void* b0_Wk  = d_in[9];
  const void* b0_Wv  = d_in[10];
  const void* b0_Wsh = d_in[11];
  const void* b0_Wr  = d_in[12];
  const void* b0_Wo  = d_in[13];
  const void* b0_F1  = d_in[14];
  const void* b0_F2  = d_in[15];
  const void* bm_Wq  = d_in[16];
  const void* bm_Wk  = d_in[17];
  const void* bm_Wv  = d_in[18];
  const void* bm_Wsh = d_in[19];
  const void* bm_Wr  = d_in[20];
  const void* bm_Wo  = d_in[21];
  const void* bm_F1  = d_in[22];
  const void* bm_F2  = d_in[23];
  const void* bf_Wq  = d_in[24];
  const void* bf_Wk  = d_in[25];
  const void* bf_Wv  = d_in[26];
  const void* bf_Wsh = d_in[27];
  const void* bf_Wr  = d_in[28];
  const void* bf_Wo  = d_in[29];
  const void* bf_F1  = d_in[30];
  const void* bf_F2  = d_in[31];
  const void* hW1    = d_in[32];
  const void* hW2    = d_in[33];

  char* bws = (char*)d_ws;
  size_t off = 0;
  auto alloc = [&](size_t bytes) -> void* {
    void* p = bws + off;
    off += (bytes + 255) & ~(size_t)255;
    return p;
  };
  int* dflag   = (int*)alloc(256);
  float* sh_f  = (float*)alloc((size_t)NE*9*4);
  float* dist  = (float*)alloc((size_t)NE*4);
  float* rbf_f = (float*)alloc((size_t)NE*128*4);
  float* t9    = (float*)alloc((size_t)NE*9*4);
  int* counts  = (int*)alloc(2048*4);
  int* rowptr  = (int*)alloc(2049*4);
  int* cursor  = (int*)alloc(2048*4);
  int* perm    = (int*)alloc((size_t)NE*4);
  float* injb  = (float*)alloc((size_t)NN*DINJ*4);
  float* zA    = (float*)alloc((size_t)NN*512*4);
  float* zB    = (float*)alloc((size_t)NN*512*4);
  float* zcat  = (float*)alloc((size_t)NN*720*4);
  ushort_t* xlnh = (ushort_t*)alloc((size_t)NN*736*2);
  float* qkvb  = (float*)alloc((size_t)NN*1440*4);
  float* Wr_all = (float*)alloc((size_t)128*24*4);
  float* r_all = (float*)alloc((size_t)6*NE*4*4);
  ushort_t* aggh = (ushort_t*)alloc((size_t)NN*DEMB*2);
  float* ybuf  = (float*)alloc((size_t)NN*720*4);
  ushort_t* h1h = (ushort_t*)alloc((size_t)NN*DEMB*2);
  ushort_t* g1h = (ushort_t*)alloc((size_t)NN*DFEAT*2);
  float* gsum  = (float*)alloc(64*4);

  float* pos_c    = (float*)alloc((size_t)NN*3*4);
  float* atom_c   = (float*)alloc((size_t)64*DINJ*4);
  float* degWr_c  = (float*)alloc((size_t)128*9*4);
  float* degWsh_c = (float*)alloc((size_t)9*DINJ*4);
  float* b0_Wsh_c = (float*)alloc((size_t)9*480*4);
  float* b0_Wr_c  = (float*)alloc((size_t)128*4*4);
  float* bm_Wsh_c = (float*)alloc((size_t)4*9*480*4);
  float* bm_Wr_c  = (float*)alloc((size_t)4*128*4*4);
  float* bf_Wsh_c = (float*)alloc((size_t)9*480*4);
  float* bf_Wr_c  = (float*)alloc((size_t)128*4*4);
  float* hW2_c    = (float*)alloc((size_t)512*4);

  auto allocW = [&](size_t elems, ushort_t*& h, ushort_t*& l){
    h = (ushort_t*)alloc(elems*2); l = (ushort_t*)alloc(elems*2);
  };
  ushort_t *b0_qkvTh,*b0_qkvTl,*b0_WoTh,*b0_WoTl,*b0_F1Th,*b0_F1Tl,*b0_F2Th,*b0_F2Tl;
  allocW((size_t)1472*736, b0_qkvTh, b0_qkvTl);
  allocW((size_t)768*480,  b0_WoTh,  b0_WoTl);
  allocW((size_t)512*736,  b0_F1Th,  b0_F1Tl);
  allocW((size_t)512*480,  b0_F2Th,  b0_F2Tl);
  ushort_t *bm_qkvTh[4],*bm_qkvTl[4],*bm_WoTh[4],*bm_WoTl[4],*bm_F1Th[4],*bm_F1Tl[4],*bm_F2Th[4],*bm_F2Tl[4];
  for (int i = 0; i < 4; ++i){
    allocW((size_t)1472*480, bm_qkvTh[i], bm_qkvTl[i]);
    allocW((size_t)512*480,  bm_WoTh[i],  bm_WoTl[i]);
    allocW((size_t)512*480,  bm_F1Th[i],  bm_F1Tl[i]);
    allocW((size_t)512*480,  bm_F2Th[i],  bm_F2Tl[i]);
  }
  ushort_t *bf_qkvTh,*bf_qkvTl,*bf_WoTh,*bf_WoTl,*bf_F1Th,*bf_F1Tl,*bf_F2Th,*bf_F2Tl,*hW1Th,*hW1Tl;
  allocW((size_t)1472*480, bf_qkvTh, bf_qkvTl);
  allocW((size_t)512*480,  bf_WoTh,  bf_WoTl);
  allocW((size_t)512*480,  bf_F1Th,  bf_F1Tl);
  allocW((size_t)512*480,  bf_F2Th,  bf_F2Tl);
  allocW((size_t)512*512,  hW1Th,    hW1Tl);

  detect_kernel<<<1, 256, 0, stream>>>((const ushort_t*)atom_table, dflag);

  CDescArr ca;
  int ci = 0;
  auto addC = [&](const void* s, float* d, int n){
    ca.d[ci].src = s; ca.d[ci].dst = d; ca.d[ci].n = n; ++ci;
  };
  addC(pos, pos_c, NN*3);
  addC(atom_table, atom_c, 64*DINJ);
  addC(degWr, degWr_c, 128*9);
  addC(degWsh, degWsh_c, 9*DINJ);
  addC(b0_Wsh, b0_Wsh_c, 9*480);
  addC(b0_Wr, b0_Wr_c, 128*4);
  addC(bm_Wsh, bm_Wsh_c, 4*9*480);
  addC(bm_Wr, bm_Wr_c, 4*128*4);
  addC(bf_Wsh, bf_Wsh_c, 9*480);
  addC(bf_Wr, bf_Wr_c, 128*4);
  addC(hW2, hW2_c, 512);
  convert_inputs<<<dim3(8, 11), 256, 0, stream>>>(ca, dflag);

  TDescArr ta;
  int ti = 0;
  auto addT = [&](const void* s, ushort_t* dh, ushort_t* dl, int K, int M,
                  int Kp, int Mp, int rowoff, int eo){
    ta.d[ti].src = s;
    ta.d[ti].dh = dh + (size_t)rowoff*Kp;
    ta.d[ti].dl = dl + (size_t)rowoff*Kp;
    ta.d[ti].K = K; ta.d[ti].M = M; ta.d[ti].Kpad = Kp; ta.d[ti].Mpad = Mp;
    ta.d[ti].eoff = eo; ++ti;
  };
  addT(b0_Wq, b0_qkvTh, b0_qkvTl, 720, 480, 736, 480, 0,   0);
  addT(b0_Wk, b0_qkvTh, b0_qkvTl, 720, 480, 736, 480, 480, 0);
  addT(b0_Wv, b0_qkvTh, b0_qkvTl, 720, 480, 736, 512, 960, 0);
  addT(b0_Wo, b0_WoTh,  b0_WoTl,  480, 720, 480, 768, 0,   0);
  addT(b0_F1, b0_F1Th,  b0_F1Tl,  720, 480, 736, 512, 0,   0);
  addT(b0_F2, b0_F2Th,  b0_F2Tl,  480, 480, 480, 512, 0,   0);
  for (int i = 0; i < 4; ++i){
    int eo = i*480*480;
    addT(bm_Wq, bm_qkvTh[i], bm_qkvTl[i], 480, 480, 480, 480, 0,   eo);
    addT(bm_Wk, bm_qkvTh[i], bm_qkvTl[i], 480, 480, 480, 480, 480, eo);
    addT(bm_Wv, bm_qkvTh[i], bm_qkvTl[i], 480, 480, 480, 512, 960, eo);
    addT(bm_Wo, bm_WoTh[i],  bm_WoTl[i],  480, 480, 480, 512, 0,   eo);
    addT(bm_F1, bm_F1Th[i],  bm_F1Tl[i],  480, 480, 480, 512, 0,   eo);
    addT(bm_F2, bm_F2Th[i],  bm_F2Tl[i],  480, 480, 480, 512, 0,   eo);
  }
  addT(bf_Wq, bf_qkvTh, bf_qkvTl, 480, 480, 480, 480, 0,   0);
  addT(bf_Wk, bf_qkvTh, bf_qkvTl, 480, 480, 480, 480, 480, 0);
  addT(bf_Wv, bf_qkvTh, bf_qkvTl, 480, 480, 480, 512, 960, 0);
  addT(bf_Wo, bf_WoTh,  bf_WoTl,  480, 480, 480, 512, 0,   0);
  addT(bf_F1, bf_F1Th,  bf_F1Tl,  480, 480, 480, 512, 0,   0);
  addT(bf_F2, bf_F2Th,  bf_F2Tl,  480, 512, 480, 512, 0,   0);
  addT(hW1,   hW1Th,    hW1Tl,    512, 512, 512, 512, 0,   0);
  transpose_all<<<dim3(23, 24, 37), 256, 0, stream>>>(ta, dflag);

  geom_kernel<<<NE/256, 256, 0, stream>>>(pos_c, esrc, edst, sh_f, dist);
  rbf_kernel<<<(NE*128)/256, 256, 0, stream>>>(dist, rbf_f);
  t9_kernel<<<(NE*9 + 255)/256, 256, 0, stream>>>(rbf_f, sh_f, degWr_c, t9);
  pack_wr<<<12, 256, 0, stream>>>(b0_Wr_c, bm_Wr_c, bf_Wr_c, Wr_all);
  gate_kernel<<<NE/256, 256, 0, stream>>>(rbf_f, Wr_all, r_all);

  zero_f32<<<(2048 + 255)/256, 256, 0, stream>>>((float*)counts, 2048);
  hist_kernel<<<NE/256, 256, 0, stream>>>(edst, counts);
  scan_kernel<<<1, 1024, 0, stream>>>(counts, rowptr, cursor);
  scatter_kernel<<<NE/256, 256, 0, stream>>>(edst, cursor, perm);

  inj_kernel<<<NN, 64, 0, stream>>>(t9, rowptr, perm, node_atom, atom_c, degWsh_c, injb);
  zero_f32<<<(NN*DEMB)/256, 256, 0, stream>>>(zA, NN*DEMB);

  auto gemm = [&](const ushort_t* A, const ushort_t* BTh, const ushort_t* BTl,
                  int N, int Npad, int Kp, int ldc,
                  float* Cf, ushort_t* Cb, const float* R, int flags){
    dim3 g(Npad/64, 32);
    if (Kp == 480)
      gemm_bt<480><<<g, 256, 0, stream>>>(A, BTh, BTl, N, ldc, Cf, Cb, R, flags);
    else if (Kp == 512)
      gemm_bt<512><<<g, 256, 0, stream>>>(A, BTh, BTl, N, ldc, Cf, Cb, R, flags);
    else
      gemm_bt<736><<<g, 256, 0, stream>>>(A, BTh, BTl, N, ldc, Cf, Cb, R, flags);
  };

  struct BW {
    const float *Wsh, *r_slot;
    const ushort_t *qkvTh,*qkvTl,*WoTh,*WoTl,*F1Th,*F1Tl,*F2Th,*F2Tl;
    int Din, Kpad, Dout; bool res;
  };
  auto run_block = [&](const BW& bw, const float* zin, float* zout){
    ln_kernel<<<NN/4, 256, 0, stream>>>(zin, bw.Din, bw.Kpad, xlnh);
    gemm(xlnh, bw.qkvTh, bw.qkvTl, 1440, 1472, bw.Kpad, 1440,
         qkvb, nullptr, nullptr, 0);
    node_attn_kernel<<<NN, 256, 0, stream>>>(qkvb, sh_f, bw.Wsh, bw.r_slot,
                                             rowptr, perm, esrc, aggh);
    int WoNpad = (bw.Din == 720) ? 768 : 512;
    gemm(aggh, bw.WoTh, bw.WoTl, bw.Din, WoNpad, 480, bw.Din,
         ybuf, nullptr, zin, 2);
    ln_kernel<<<NN/4, 256, 0, stream>>>(ybuf, bw.Din, bw.Kpad, xlnh);
    gemm(xlnh, bw.F1Th, bw.F1Tl, DEMB, 512, bw.Kpad, DEMB,
         nullptr, h1h, nullptr, 1|4);
    gemm(h1h, bw.F2Th, bw.F2Tl, bw.Dout, 512, 480, bw.Dout,
         zout, nullptr, bw.res ? ybuf : nullptr, bw.res ? 2 : 0);
  };

  BW b0 = { b0_Wsh_c, r_all + (size_t)0*NE*4,
            b0_qkvTh,b0_qkvTl,b0_WoTh,b0_WoTl,b0_F1Th,b0_F1Tl,b0_F2Th,b0_F2Tl,
            720, 736, 480, false };
  BW bm[4];
  for (int i = 0; i < 4; ++i){
    bm[i] = { bm_Wsh_c + (size_t)i*9*480, r_all + (size_t)(1+i)*NE*4,
              bm_qkvTh[i],bm_qkvTl[i],bm_WoTh[i],bm_WoTl[i],
              bm_F1Th[i],bm_F1Tl[i],bm_F2Th[i],bm_F2Tl[i],
              480, 480, 480, true };
  }
  BW bf = { bf_Wsh_c, r_all + (size_t)5*NE*4,
            bf_qkvTh,bf_qkvTl,bf_WoTh,bf_WoTl,bf_F1Th,bf_F1Tl,bf_F2Th,bf_F2Tl,
            480, 480, 512, false };

  float* z  = zA;
  float* z2 = zB;
  for (int iter = 0; iter < 2; ++iter){
    zcat_kernel<<<(NN*720)/256, 256, 0, stream>>>(z, injb, zcat);
    run_block(b0, zcat, z2);
    { float* tmp = z; z = z2; z2 = tmp; }
    for (int i = 0; i < 4; ++i){
      run_block(bm[i], z, z2);
      { float* tmp = z; z = z2; z2 = tmp; }
    }
  }
  run_block(bf, z, z2);
  ln_kernel<<<NN/4, 256, 0, stream>>>(z2, DFEAT, DFEAT, xlnh);
  gemm(xlnh, hW1Th, hW1Tl, DFEAT, 512, DFEAT, DFEAT,
       nullptr, g1h, nullptr, 1|4);
  zero_f32<<<1, 64, 0, stream>>>(gsum, 64);
  head_dot_kernel<<<NN/4, 256, 0, stream>>>(g1h, hW2_c, batch, gsum);
  finalize_kernel<<<1, 64, 0, stream>>>(gsum, dflag, d_out);
}

// Round 10
// 1428.823 us; speedup vs baseline: 1.8158x; 1.0425x over previous
//
#include <hip/hip_runtime.h>

#define NN 2048
#define NE 32768
#define NG 64
#define DINJ 240
#define DEMB 480
#define DFEAT 512
#define MAXDEG 192

typedef unsigned short ushort_t;
typedef __attribute__((ext_vector_type(8))) short short8;
typedef __attribute__((ext_vector_type(4))) float floatx4;

__device__ __forceinline__ float b2f(ushort_t u){
  union { unsigned u; float f; } x; x.u = ((unsigned)u) << 16; return x.f;
}
__device__ __forceinline__ ushort_t f2b(float f){
  union { float f; unsigned u; } x; x.f = f;
  unsigned r = x.u + 0x7FFFu + ((x.u >> 16) & 1u);
  return (ushort_t)(r >> 16);
}
__device__ __forceinline__ float wredsum(float v){
  #pragma unroll
  for (int o = 32; o > 0; o >>= 1) v += __shfl_xor(v, o, 64);
  return v;
}
__device__ __forceinline__ float silu_f(float x){ return x / (1.f + __expf(-x)); }

// ---------------- small utility kernels ----------------
__global__ void zero_f32(float* p, int n){
  int i = blockIdx.x*256 + threadIdx.x; if (i < n) p[i] = 0.f;
}

// ---------------- input dtype detection ----------------
__global__ void detect_kernel(const ushort_t* __restrict__ probe, int* flag){
  __shared__ int c;
  if (threadIdx.x == 0) c = 0;
  __syncthreads();
  ushort_t u = probe[2*threadIdx.x];
  int e = (u >> 7) & 0xFF;
  int plausible = (u == 0) || (e >= 100 && e <= 140);
  atomicAdd(&c, plausible);
  __syncthreads();
  if (threadIdx.x == 0) *flag = (c >= 192) ? 0 : 1;
}

// -------- convert small float inputs -> internal FP32 (exact either way) ----
struct CDesc { const void* src; float* dst; int n; };
struct CDescArr { CDesc d[11]; };
__global__ __launch_bounds__(256) void convert_inputs(CDescArr ca, const int* __restrict__ flag){
  CDesc cd = ca.d[blockIdx.y];
  int isf32 = *flag;
  for (int i = blockIdx.x*256 + threadIdx.x; i < cd.n; i += gridDim.x*256){
    cd.dst[i] = isf32 ? ((const float*)cd.src)[i] : b2f(((const ushort_t*)cd.src)[i]);
  }
}

// --- LDS-tiled weight transpose: src (K x M row-major) -> dst (Mpad x Kpad) --
struct TDesc { const void* src; ushort_t* dh; ushort_t* dl; int K; int M; int Kpad; int Mpad; int eoff; };
struct TDescArr { TDesc d[37]; };
__global__ __launch_bounds__(256) void transpose_all(TDescArr ta, const int* __restrict__ flag){
  TDesc td = ta.d[blockIdx.z];
  int k0 = blockIdx.x*32, m0 = blockIdx.y*32;
  if (k0 >= td.Kpad || m0 >= td.Mpad) return;
  int isf32 = *flag;
  __shared__ float lds[32*33];
  int tx = threadIdx.x & 31, ty = threadIdx.x >> 5;
  #pragma unroll
  for (int r = 0; r < 4; ++r){
    int kl = ty + r*8;
    int k = k0 + kl, mm = m0 + tx;
    float x = 0.f;
    if (k < td.K && mm < td.M){
      size_t si = (size_t)td.eoff + (size_t)k*td.M + mm;
      x = isf32 ? ((const float*)td.src)[si] : b2f(((const ushort_t*)td.src)[si]);
    }
    lds[kl*33 + tx] = x;
  }
  __syncthreads();
  #pragma unroll
  for (int r = 0; r < 4; ++r){
    int nl = ty + r*8;
    int n = m0 + nl, k = k0 + tx;
    if (n < td.Mpad && k < td.Kpad){
      float x = lds[tx*33 + nl];
      ushort_t h = f2b(x);
      size_t di = (size_t)n*td.Kpad + k;
      td.dh[di] = h;
      td.dl[di] = f2b(x - b2f(h));
    }
  }
}

// ---------------- geometry (fp32 pos) ----------------
__global__ void geom_kernel(const float* __restrict__ pos,
                            const int* __restrict__ esrc, const int* __restrict__ edst,
                            float* __restrict__ sh, float* __restrict__ dist){
  int e = blockIdx.x*256 + threadIdx.x; if (e >= NE) return;
  int s = esrc[e], d = edst[e];
  float x = pos[s*3+0] - pos[d*3+0];
  float y = pos[s*3+1] - pos[d*3+1];
  float z = pos[s*3+2] - pos[d*3+2];
  float dd = sqrtf(x*x + y*y + z*z + 1e-12f);
  float ix = x/dd, iy = y/dd, iz = z/dd;
  const float s3 = 1.7320508075688772f, s15 = 3.872983346207417f, s5 = 2.23606797749979f;
  float* o = sh + (size_t)e*9;
  o[0] = 1.f; o[1] = s3*ix; o[2] = s3*iy; o[3] = s3*iz;
  o[4] = s15*ix*iy; o[5] = s15*iy*iz; o[6] = 0.5f*s5*(3.f*iz*iz - 1.f);
  o[7] = s15*ix*iz; o[8] = 0.5f*s15*(ix*ix - iy*iy);
  dist[e] = dd;
}

__global__ void rbf_kernel(const float* __restrict__ dist, float* __restrict__ rbf){
  int idx = blockIdx.x*256 + threadIdx.x; if (idx >= NE*128) return;
  int e = idx >> 7, r = idx & 127;
  float c = (float)r * (5.0f/127.0f);
  float u = (dist[e] - c) * (128.0f/5.0f);
  rbf[idx] = __expf(-0.5f*u*u);
}

__global__ void t9_kernel(const float* __restrict__ rbf, const float* __restrict__ sh,
                          const float* __restrict__ degWr, float* __restrict__ t9){
  int idx = blockIdx.x*256 + threadIdx.x; if (idx >= NE*9) return;
  int e = idx/9, j = idx - e*9;
  float s = 0.f;
  const float* rb = rbf + (size_t)e*128;
  for (int r = 0; r < 128; ++r) s += rb[r]*degWr[r*9+j];
  t9[idx] = sh[idx] * silu_f(s);
}

// ---- pack 6 Wr slots into Wr_all[128][24] (k-major, o=slot*4+h inner) ------
__global__ void pack_wr(const float* __restrict__ b0Wr, const float* __restrict__ bmWr,
                        const float* __restrict__ bfWr, float* __restrict__ Wr_all){
  int idx = blockIdx.x*256 + threadIdx.x; if (idx >= 128*24) return;
  int k = idx / 24, o = idx - k*24;
  int slot = o >> 2, h = o & 3;
  const float* Wr = (slot == 0) ? b0Wr : ((slot <= 4) ? bmWr + (size_t)(slot-1)*512 : bfWr);
  Wr_all[idx] = Wr[k*4+h];
}

// ---- gate v3: thread-per-edge, 24 outputs; Wr via wave-uniform (scalar) ----
__global__ __launch_bounds__(256) void gate_kernel(const float* __restrict__ rbf,
    const float* __restrict__ Wr_all, float* __restrict__ r_all){
  int e = blockIdx.x*256 + threadIdx.x; if (e >= NE) return;
  const float4* rb4 = (const float4*)(rbf + (size_t)e*128);
  float acc[24];
  #pragma unroll
  for (int o = 0; o < 24; ++o) acc[o] = 0.f;
  for (int k4 = 0; k4 < 32; ++k4){
    float4 r = rb4[k4];
    const float* w = Wr_all + k4*96;
    #pragma unroll
    for (int o = 0; o < 24; ++o)
      acc[o] += r.x*w[o] + r.y*w[24+o] + r.z*w[48+o] + r.w*w[72+o];
  }
  #pragma unroll
  for (int o = 0; o < 24; ++o){
    int slot = o >> 2, h = o & 3;
    r_all[((size_t)slot*NE + e)*4 + h] = silu_f(acc[o]);
  }
}

// ---------------- CSR build ----------------
__global__ void hist_kernel(const int* __restrict__ edst, int* counts){
  int e = blockIdx.x*256 + threadIdx.x; if (e < NE) atomicAdd(&counts[edst[e]], 1);
}
__global__ __launch_bounds__(1024) void scan_kernel(const int* __restrict__ counts,
                                                    int* rowptr, int* cursor){
  __shared__ int s[1024];
  int t = threadIdx.x;
  int c0 = counts[2*t], c1 = counts[2*t+1];
  s[t] = c0 + c1;
  __syncthreads();
  for (int off = 1; off < 1024; off <<= 1){
    int v = (t >= off) ? s[t-off] : 0;
    __syncthreads();
    s[t] += v;
    __syncthreads();
  }
  int excl = s[t] - (c0 + c1);
  rowptr[2*t]   = excl;       cursor[2*t]   = excl;
  rowptr[2*t+1] = excl + c0;  cursor[2*t+1] = excl + c0;
  if (t == 1023) rowptr[2048] = s[1023];
}
__global__ void scatter_kernel(const int* __restrict__ edst, int* cursor, int* perm){
  int e = blockIdx.x*256 + threadIdx.x; if (e >= NE) return;
  int p = atomicAdd(&cursor[edst[e]], 1);
  perm[p] = e;
}

// ---------------- inj = atom_table[node_atom] + (sum_e t9) @ degWsh / 16 -----
__global__ __launch_bounds__(64) void inj_kernel(const float* __restrict__ t9,
    const int* __restrict__ rowptr, const int* __restrict__ perm,
    const int* __restrict__ node_atom, const float* __restrict__ atom_table,
    const float* __restrict__ degWsh, float* __restrict__ inj){
  int i = blockIdx.x; int lane = threadIdx.x;
  int b = rowptr[i], e = rowptr[i+1];
  float T[9];
  #pragma unroll
  for (int j = 0; j < 9; ++j) T[j] = 0.f;
  for (int idx = b; idx < e; ++idx){
    int ed = perm[idx];
    #pragma unroll
    for (int j = 0; j < 9; ++j) T[j] += t9[(size_t)ed*9+j];
  }
  int a = node_atom[i];
  for (int c = lane; c < DINJ; c += 64){
    float s = 0.f;
    #pragma unroll
    for (int j = 0; j < 9; ++j) s += T[j]*degWsh[j*DINJ+c];
    inj[(size_t)i*DINJ+c] = atom_table[(size_t)a*DINJ+c] + s*(1.0f/16.0f);
  }
}

// ---------------- zcat = [z | inj] ----------------
__global__ void zcat_kernel(const float* __restrict__ z, const float* __restrict__ inj,
                            float* __restrict__ zc){
  int i = blockIdx.x*256 + threadIdx.x; if (i >= NN*720) return;
  int n = i / 720, d = i - n*720;
  zc[i] = (d < DEMB) ? z[(size_t)n*DEMB + d] : inj[(size_t)n*DINJ + (d - DEMB)];
}

// ------- LayerNorm: one wave per row, 4 rows per block -----------------------
__global__ __launch_bounds__(256) void ln_kernel(const float* __restrict__ in, int D,
                                                 int Kpad, ushort_t* __restrict__ oh){
  int i = blockIdx.x*4 + (threadIdx.x >> 6);
  int lane = threadIdx.x & 63;
  const float* row = in + (size_t)i*D;
  float s = 0.f, sq = 0.f;
  for (int d = lane; d < D; d += 64){ float x = row[d]; s += x; sq += x*x; }
  s = wredsum(s); sq = wredsum(sq);
  float mu = s / (float)D;
  float var = fmaxf(sq / (float)D - mu*mu, 0.f);
  float rs = rsqrtf(var + 1e-6f);
  ushort_t* ohrow = oh + (size_t)i*Kpad;
  for (int d = lane; d < D; d += 64) ohrow[d] = f2b((row[d]-mu)*rs);
  for (int d = D + lane; d < Kpad; d += 64) ohrow[d] = 0;
}

// -- MFMA GEMM: C = A * B^T with B = Bh (+Bl if SPLITB). Depth-2 prefetch. ----
// flags: 1 = silu, 2 = add residual R (ldc-strided), 4 = bf16 out else fp32
template<int KPAD, bool SPLITB>
__global__ __launch_bounds__(256) void gemm_bt(
    const ushort_t* __restrict__ A,
    const ushort_t* __restrict__ BTh, const ushort_t* __restrict__ BTl,
    int N, int ldc,
    float* __restrict__ Cf, ushort_t* __restrict__ Cb,
    const float* __restrict__ R, int flags){
  int lane = threadIdx.x & 63, wave = threadIdx.x >> 6;
  int row0 = blockIdx.y*64 + (wave>>1)*32;
  int col0 = blockIdx.x*64 + (wave&1)*32;
  int m = lane & 15, q4 = lane >> 4;
  size_t a0 = (size_t)(row0+m)*KPAD + q4*8;
  size_t a1 = a0 + (size_t)16*KPAD;
  size_t b0 = (size_t)(col0+m)*KPAD + q4*8;
  size_t b1 = b0 + (size_t)16*KPAD;
  floatx4 acc00 = {0,0,0,0}, acc01 = {0,0,0,0}, acc10 = {0,0,0,0}, acc11 = {0,0,0,0};
  constexpr int steps = KPAD >> 5;
  struct Frag { short8 A0, A1, B0h, B1h, B0l, B1l; };
  auto loadF = [&](int s) -> Frag {
    Frag f;
    size_t o = (size_t)s*32;
    f.A0  = *(const short8*)(A   + a0 + o);
    f.A1  = *(const short8*)(A   + a1 + o);
    f.B0h = *(const short8*)(BTh + b0 + o);
    f.B1h = *(const short8*)(BTh + b1 + o);
    if (SPLITB){
      f.B0l = *(const short8*)(BTl + b0 + o);
      f.B1l = *(const short8*)(BTl + b1 + o);
    }
    return f;
  };
  Frag cur = loadF(0);
  Frag nxt = (steps > 1) ? loadF(1) : cur;
  #pragma unroll
  for (int s = 0; s < steps; ++s){
    Frag fut = (s + 2 < steps) ? loadF(s + 2) : cur;
    acc00 = __builtin_amdgcn_mfma_f32_16x16x32_bf16(cur.A0, cur.B0h, acc00, 0, 0, 0);
    acc01 = __builtin_amdgcn_mfma_f32_16x16x32_bf16(cur.A0, cur.B1h, acc01, 0, 0, 0);
    acc10 = __builtin_amdgcn_mfma_f32_16x16x32_bf16(cur.A1, cur.B0h, acc10, 0, 0, 0);
    acc11 = __builtin_amdgcn_mfma_f32_16x16x32_bf16(cur.A1, cur.B1h, acc11, 0, 0, 0);
    if (SPLITB){
      acc00 = __builtin_amdgcn_mfma_f32_16x16x32_bf16(cur.A0, cur.B0l, acc00, 0, 0, 0);
      acc01 = __builtin_amdgcn_mfma_f32_16x16x32_bf16(cur.A0, cur.B1l, acc01, 0, 0, 0);
      acc10 = __builtin_amdgcn_mfma_f32_16x16x32_bf16(cur.A1, cur.B0l, acc10, 0, 0, 0);
      acc11 = __builtin_amdgcn_mfma_f32_16x16x32_bf16(cur.A1, cur.B1l, acc11, 0, 0, 0);
    }
    cur = nxt; nxt = fut;
  }
  #pragma unroll
  for (int rr = 0; rr < 2; ++rr){
    #pragma unroll
    for (int cc = 0; cc < 2; ++cc){
      int col = col0 + cc*16 + m;
      if (col >= N) continue;
      floatx4 acc = rr ? (cc ? acc11 : acc10) : (cc ? acc01 : acc00);
      int rowb = row0 + rr*16 + q4*4;
      #pragma unroll
      for (int r = 0; r < 4; ++r){
        size_t idx = (size_t)(rowb + r)*ldc + col;
        float v = acc[r];
        if (flags & 2) v += R[idx];
        if (flags & 1) v = silu_f(v);
        if (flags & 4) Cb[idx] = f2b(v);
        else           Cf[idx] = v;
      }
    }
  }
}

// ------- fused per-node attention: logits + softmax + aggregation ------------
__global__ __launch_bounds__(256) void node_attn_kernel(
    const float* __restrict__ qkv, const float* __restrict__ sh,
    const float* __restrict__ Wsh, const float* __restrict__ r_slot,
    const int* __restrict__ rowptr, const int* __restrict__ perm,
    const int* __restrict__ esrc, ushort_t* __restrict__ aggh){
  int i = blockIdx.x; int t = threadIdx.x;
  int lane = t & 63, w = t >> 6;
  int b = rowptr[i]; int deg = min(rowptr[i+1] - b, MAXDEG);
  __shared__ float qL[480];
  __shared__ float PqL[36];
  __shared__ float logitL[MAXDEG*4];
  __shared__ float rL[MAXDEG*4];
  __shared__ int eL[MAXDEG], srcL[MAXDEG];
  __shared__ float S[36];
  __shared__ float mxs[4], dens[4];
  for (int d = t; d < 480; d += 256) qL[d] = qkv[(size_t)i*1440 + d];
  for (int idx = t; idx < deg; idx += 256){
    int e = perm[b+idx];
    eL[idx] = e;
    srcL[idx] = esrc[e];
  }
  __syncthreads();
  if (t < 36){
    int h = t/9, j = t - h*9;
    const float* ws = Wsh + (size_t)j*DEMB + h*120;
    const float* qh = qL + h*120;
    float p = 0.f;
    for (int k = 0; k < 120; ++k) p += qh[k]*ws[k];
    PqL[t] = p;
  }
  __syncthreads();
  const float inv = 0.091287092917527686f;
  for (int base = 0; base < deg; base += 64){
    int idx = base + (t >> 2);
    if (idx < deg){
      int h = t & 3;
      int e = eL[idx], s = srcL[idx];
      const float4* kk = (const float4*)(qkv + (size_t)s*1440 + 480 + h*120);
      const float4* qq = (const float4*)(qL + h*120);
      float p = 0.f;
      #pragma unroll
      for (int it = 0; it < 30; ++it){
        float4 a = qq[it], bb = kk[it];
        p += a.x*bb.x + a.y*bb.y + a.z*bb.z + a.w*bb.w;
      }
      float mmq = 0.f;
      const float* she = sh + (size_t)e*9;
      #pragma unroll
      for (int j = 0; j < 9; ++j) mmq += she[j]*PqL[h*9+j];
      float rr = r_slot[(size_t)e*4+h];
      rL[idx*4+h] = rr;
      logitL[idx*4+h] = rr*(p + mmq)*inv;
    }
  }
  __syncthreads();
  float mx = -1e30f;
  for (int idx = lane; idx < deg; idx += 64) mx = fmaxf(mx, logitL[idx*4+w]);
  #pragma unroll
  for (int o = 32; o > 0; o >>= 1) mx = fmaxf(mx, __shfl_xor(mx, o, 64));
  if (deg == 0) mx = 0.f;
  float den = 0.f;
  for (int idx = lane; idx < deg; idx += 64) den += __expf(logitL[idx*4+w]-mx);
  den = wredsum(den) + 1e-9f;
  if (lane == 0){ mxs[w] = mx; dens[w] = den; }
  __syncthreads();
  for (int j = t; j < deg*4; j += 256){
    int h = j & 3;
    logitL[j] = __expf(logitL[j]-mxs[h]) / dens[h] * rL[j];
  }
  __syncthreads();
  float a0 = 0.f, a1 = 0.f;
  int d0 = 2*t, h2 = d0/120;
  if (t >= 240){
    for (int o = t - 240; o < 36; o += 16){
      int h = o/9, j = o - h*9;
      float a = 0.f;
      for (int idx = 0; idx < deg; ++idx)
        a += logitL[idx*4+h]*sh[(size_t)eL[idx]*9+j];
      S[o] = a;
    }
  } else {
    for (int idx = 0; idx < deg; ++idx){
      float wgt = logitL[idx*4+h2];
      float2 vv = *(const float2*)(qkv + (size_t)srcL[idx]*1440 + 960 + d0);
      a0 += wgt*vv.x; a1 += wgt*vv.y;
    }
  }
  __syncthreads();
  if (t < 240){
    float mm0 = 0.f, mm1 = 0.f;
    #pragma unroll
    for (int j = 0; j < 9; ++j){
      mm0 += S[h2*9+j]*Wsh[j*DEMB + d0];
      mm1 += S[h2*9+j]*Wsh[j*DEMB + d0 + 1];
    }
    aggh[(size_t)i*DEMB + d0]     = f2b(a0 + mm0);
    aggh[(size_t)i*DEMB + d0 + 1] = f2b(a1 + mm1);
  }
}

// ---------------- head ----------------
__global__ __launch_bounds__(256) void head_dot_kernel(const ushort_t* __restrict__ g1h,
    const float* __restrict__ hW2, const int* __restrict__ batch, float* gsum){
  int i = blockIdx.x*4 + (threadIdx.x >> 6);
  int lane = threadIdx.x & 63;
  float s = 0.f;
  for (int d = lane; d < DFEAT; d += 64)
    s += b2f(g1h[(size_t)i*DFEAT + d]) * hW2[d];
  s = wredsum(s);
  if (lane == 0) atomicAdd(&gsum[batch[i]], s);
}
__global__ void finalize_kernel(const float* __restrict__ gsum,
                                const int* __restrict__ flag, void* out){
  int g = threadIdx.x;
  if (g < NG){
    float v = gsum[g] * 0.17677669529663687f; // 1/sqrt(32)
    if (*flag) ((float*)out)[g] = v;
    else       ((ushort_t*)out)[g] = f2b(v);
  }
}

// =====================================================================
extern "C" void kernel_launch(void* const* d_in, const int* in_sizes, int n_in,
                              void* d_out, int out_size, void* d_ws, size_t ws_size,
                              hipStream_t stream) {
  (void)in_sizes; (void)n_in; (void)out_size; (void)ws_size;
  const void* pos        = d_in[0];
  const int*  node_atom  = (const int*)d_in[1];
  const int*  esrc       = (const int*)d_in[2];
  const int*  edst       = (const int*)d_in[3];
  const int*  batch      = (const int*)d_in[4];
  const void* atom_table = d_in[5];
  const void* degWr      = d_in[6];
  const void* degWsh     = d_in[7];
  const void* b0_Wq  = d_in[8];
  const void* b0_Wk  = d_in[9];
  const void* b0_Wv  = d_in[10];
  const void* b0_Wsh = d_in[11];
  const void* b0_Wr  = d_in[12];
  const void* b0_Wo  = d_in[13];
  const void* b0_F1  = d_in[14];
  const void* b0_F2  = d_in[15];
  const void* bm_Wq  = d_in[16];
  const void* bm_Wk  = d_in[17];
  const void* bm_Wv  = d_in[18];
  const void* bm_Wsh = d_in[19];
  const void* bm_Wr  = d_in[20];
  const void* bm_Wo  = d_in[21];
  const void* bm_F1  = d_in[22];
  const void* bm_F2  = d_in[23];
  const void* bf_Wq  = d_in[24];
  const void* bf_Wk  = d_in[25];
  const void* bf_Wv  = d_in[26];
  const void* bf_Wsh = d_in[27];
  const void* bf_Wr  = d_in[28];
  const void* bf_Wo  = d_in[29];
  const void* bf_F1  = d_in[30];
  const void* bf_F2  = d_in[31];
  const void* hW1    = d_in[32];
  const void* hW2    = d_in[33];

  char* bws = (char*)d_ws;
  size_t off = 0;
  auto alloc = [&](size_t bytes) -> void* {
    void* p = bws + off;
    off += (bytes + 255) & ~(size_t)255;
    return p;
  };
  int* dflag   = (int*)alloc(256);
  float* sh_f  = (float*)alloc((size_t)NE*9*4);
  float* dist  = (float*)alloc((size_t)NE*4);
  float* rbf_f = (float*)alloc((size_t)NE*128*4);
  float* t9    = (float*)alloc((size_t)NE*9*4);
  int* counts  = (int*)alloc(2048*4);
  int* rowptr  = (int*)alloc(2049*4);
  int* cursor  = (int*)alloc(2048*4);
  int* perm    = (int*)alloc((size_t)NE*4);
  float* injb  = (float*)alloc((size_t)NN*DINJ*4);
  float* zA    = (float*)alloc((size_t)NN*512*4);
  float* zB    = (float*)alloc((size_t)NN*512*4);
  float* zcat  = (float*)alloc((size_t)NN*720*4);
  ushort_t* xlnh = (ushort_t*)alloc((size_t)NN*736*2);
  float* qkvb  = (float*)alloc((size_t)NN*1440*4);
  float* Wr_all = (float*)alloc((size_t)128*24*4);
  float* r_all = (float*)alloc((size_t)6*NE*4*4);
  ushort_t* aggh = (ushort_t*)alloc((size_t)NN*DEMB*2);
  float* ybuf  = (float*)alloc((size_t)NN*720*4);
  ushort_t* h1h = (ushort_t*)alloc((size_t)NN*DEMB*2);
  ushort_t* g1h = (ushort_t*)alloc((size_t)NN*DFEAT*2);
  float* gsum  = (float*)alloc(64*4);

  float* pos_c    = (float*)alloc((size_t)NN*3*4);
  float* atom_c   = (float*)alloc((size_t)64*DINJ*4);
  float* degWr_c  = (float*)alloc((size_t)128*9*4);
  float* degWsh_c = (float*)alloc((size_t)9*DINJ*4);
  float* b0_Wsh_c = (float*)alloc((size_t)9*480*4);
  float* b0_Wr_c  = (float*)alloc((size_t)128*4*4);
  float* bm_Wsh_c = (float*)alloc((size_t)4*9*480*4);
  float* bm_Wr_c  = (float*)alloc((size_t)4*128*4*4);
  float* bf_Wsh_c = (float*)alloc((size_t)9*480*4);
  float* bf_Wr_c  = (float*)alloc((size_t)128*4*4);
  float* hW2_c    = (float*)alloc((size_t)512*4);

  auto allocW = [&](size_t elems, ushort_t*& h, ushort_t*& l){
    h = (ushort_t*)alloc(elems*2); l = (ushort_t*)alloc(elems*2);
  };
  ushort_t *b0_qkvTh,*b0_qkvTl,*b0_WoTh,*b0_WoTl,*b0_F1Th,*b0_F1Tl,*b0_F2Th,*b0_F2Tl;
  allocW((size_t)1472*736, b0_qkvTh, b0_qkvTl);
  allocW((size_t)768*480,  b0_WoTh,  b0_WoTl);
  allocW((size_t)512*736,  b0_F1Th,  b0_F1Tl);
  allocW((size_t)512*480,  b0_F2Th,  b0_F2Tl);
  ushort_t *bm_qkvTh[4],*bm_qkvTl[4],*bm_WoTh[4],*bm_WoTl[4],*bm_F1Th[4],*bm_F1Tl[4],*bm_F2Th[4],*bm_F2Tl[4];
  for (int i = 0; i < 4; ++i){
    allocW((size_t)1472*480, bm_qkvTh[i], bm_qkvTl[i]);
    allocW((size_t)512*480,  bm_WoTh[i],  bm_WoTl[i]);
    allocW((size_t)512*480,  bm_F1Th[i],  bm_F1Tl[i]);
    allocW((size_t)512*480,  bm_F2Th[i],  bm_F2Tl[i]);
  }
  ushort_t *bf_qkvTh,*bf_qkvTl,*bf_WoTh,*bf_WoTl,*bf_F1Th,*bf_F1Tl,*bf_F2Th,*bf_F2Tl,*hW1Th,*hW1Tl;
  allocW((size_t)1472*480, bf_qkvTh, bf_qkvTl);
  allocW((size_t)512*480,  bf_WoTh,  bf_WoTl);
  allocW((size_t)512*480,  bf_F1Th,  bf_F1Tl);
  allocW((size_t)512*480,  bf_F2Th,  bf_F2Tl);
  allocW((size_t)512*512,  hW1Th,    hW1Tl);

  detect_kernel<<<1, 256, 0, stream>>>((const ushort_t*)atom_table, dflag);

  CDescArr ca;
  int ci = 0;
  auto addC = [&](const void* s, float* d, int n){
    ca.d[ci].src = s; ca.d[ci].dst = d; ca.d[ci].n = n; ++ci;
  };
  addC(pos, pos_c, NN*3);
  addC(atom_table, atom_c, 64*DINJ);
  addC(degWr, degWr_c, 128*9);
  addC(degWsh, degWsh_c, 9*DINJ);
  addC(b0_Wsh, b0_Wsh_c, 9*480);
  addC(b0_Wr, b0_Wr_c, 128*4);
  addC(bm_Wsh, bm_Wsh_c, 4*9*480);
  addC(bm_Wr, bm_Wr_c, 4*128*4);
  addC(bf_Wsh, bf_Wsh_c, 9*480);
  addC(bf_Wr, bf_Wr_c, 128*4);
  addC(hW2, hW2_c, 512);
  convert_inputs<<<dim3(8, 11), 256, 0, stream>>>(ca, dflag);

  TDescArr ta;
  int ti = 0;
  auto addT = [&](const void* s, ushort_t* dh, ushort_t* dl, int K, int M,
                  int Kp, int Mp, int rowoff, int eo){
    ta.d[ti].src = s;
    ta.d[ti].dh = dh + (size_t)rowoff*Kp;
    ta.d[ti].dl = dl + (size_t)rowoff*Kp;
    ta.d[ti].K = K; ta.d[ti].M = M; ta.d[ti].Kpad = Kp; ta.d[ti].Mpad = Mp;
    ta.d[ti].eoff = eo; ++ti;
  };
  addT(b0_Wq, b0_qkvTh, b0_qkvTl, 720, 480, 736, 480, 0,   0);
  addT(b0_Wk, b0_qkvTh, b0_qkvTl, 720, 480, 736, 480, 480, 0);
  addT(b0_Wv, b0_qkvTh, b0_qkvTl, 720, 480, 736, 512, 960, 0);
  addT(b0_Wo, b0_WoTh,  b0_WoTl,  480, 720, 480, 768, 0,   0);
  addT(b0_F1, b0_F1Th,  b0_F1Tl,  720, 480, 736, 512, 0,   0);
  addT(b0_F2, b0_F2Th,  b0_F2Tl,  480, 480, 480, 512, 0,   0);
  for (int i = 0; i < 4; ++i){
    int eo = i*480*480;
    addT(bm_Wq, bm_qkvTh[i], bm_qkvTl[i], 480, 480, 480, 480, 0,   eo);
    addT(bm_Wk, bm_qkvTh[i], bm_qkvTl[i], 480, 480, 480, 480, 480, eo);
    addT(bm_Wv, bm_qkvTh[i], bm_qkvTl[i], 480, 480, 480, 512, 960, eo);
    addT(bm_Wo, bm_WoTh[i],  bm_WoTl[i],  480, 480, 480, 512, 0,   eo);
    addT(bm_F1, bm_F1Th[i],  bm_F1Tl[i],  480, 480, 480, 512, 0,   eo);
    addT(bm_F2, bm_F2Th[i],  bm_F2Tl[i],  480, 480, 480, 512, 0,   eo);
  }
  addT(bf_Wq, bf_qkvTh, bf_qkvTl, 480, 480, 480, 480, 0,   0);
  addT(bf_Wk, bf_qkvTh, bf_qkvTl, 480, 480, 480, 480, 480, 0);
  addT(bf_Wv, bf_qkvTh, bf_qkvTl, 480, 480, 480, 512, 960, 0);
  addT(bf_Wo, bf_WoTh,  bf_WoTl,  480, 480, 480, 512, 0,   0);
  addT(bf_F1, bf_F1Th,  bf_F1Tl,  480, 480, 480, 512, 0,   0);
  addT(bf_F2, bf_F2Th,  bf_F2Tl,  480, 512, 480, 512, 0,   0);
  addT(hW1,   hW1Th,    hW1Tl,    512, 512, 512, 512, 0,   0);
  transpose_all<<<dim3(23, 24, 37), 256, 0, stream>>>(ta, dflag);

  geom_kernel<<<NE/256, 256, 0, stream>>>(pos_c, esrc, edst, sh_f, dist);
  rbf_kernel<<<(NE*128)/256, 256, 0, stream>>>(dist, rbf_f);
  t9_kernel<<<(NE*9 + 255)/256, 256, 0, stream>>>(rbf_f, sh_f, degWr_c, t9);
  pack_wr<<<12, 256, 0, stream>>>(b0_Wr_c, bm_Wr_c, bf_Wr_c, Wr_all);
  gate_kernel<<<NE/256, 256, 0, stream>>>(rbf_f, Wr_all, r_all);

  zero_f32<<<(2048 + 255)/256, 256, 0, stream>>>((float*)counts, 2048);
  hist_kernel<<<NE/256, 256, 0, stream>>>(edst, counts);
  scan_kernel<<<1, 1024, 0, stream>>>(counts, rowptr, cursor);
  scatter_kernel<<<NE/256, 256, 0, stream>>>(edst, cursor, perm);

  inj_kernel<<<NN, 64, 0, stream>>>(t9, rowptr, perm, node_atom, atom_c, degWsh_c, injb);
  zero_f32<<<(NN*DEMB)/256, 256, 0, stream>>>(zA, NN*DEMB);

  auto gemm = [&](const ushort_t* A, const ushort_t* BTh, const ushort_t* BTl,
                  int N, int Npad, int Kp, int ldc,
                  float* Cf, ushort_t* Cb, const float* R, int flags, bool split){
    dim3 g(Npad/64, 32);
    if (split){
      if (Kp == 480)
        gemm_bt<480,true><<<g, 256, 0, stream>>>(A, BTh, BTl, N, ldc, Cf, Cb, R, flags);
      else if (Kp == 512)
        gemm_bt<512,true><<<g, 256, 0, stream>>>(A, BTh, BTl, N, ldc, Cf, Cb, R, flags);
      else
        gemm_bt<736,true><<<g, 256, 0, stream>>>(A, BTh, BTl, N, ldc, Cf, Cb, R, flags);
    } else {
      if (Kp == 480)
        gemm_bt<480,false><<<g, 256, 0, stream>>>(A, BTh, BTl, N, ldc, Cf, Cb, R, flags);
      else if (Kp == 512)
        gemm_bt<512,false><<<g, 256, 0, stream>>>(A, BTh, BTl, N, ldc, Cf, Cb, R, flags);
      else
        gemm_bt<736,false><<<g, 256, 0, stream>>>(A, BTh, BTl, N, ldc, Cf, Cb, R, flags);
    }
  };

  struct BW {
    const float *Wsh, *r_slot;
    const ushort_t *qkvTh,*qkvTl,*WoTh,*WoTl,*F1Th,*F1Tl,*F2Th,*F2Tl;
    int Din, Kpad, Dout; bool res;
  };
  auto run_block = [&](const BW& bw, const float* zin, float* zout){
    ln_kernel<<<NN/4, 256, 0, stream>>>(zin, bw.Din, bw.Kpad, xlnh);
    gemm(xlnh, bw.qkvTh, bw.qkvTl, 1440, 1472, bw.Kpad, 1440,
         qkvb, nullptr, nullptr, 0, true);
    node_attn_kernel<<<NN, 256, 0, stream>>>(qkvb, sh_f, bw.Wsh, bw.r_slot,
                                             rowptr, perm, esrc, aggh);
    int WoNpad = (bw.Din == 720) ? 768 : 512;
    gemm(aggh, bw.WoTh, bw.WoTl, bw.Din, WoNpad, 480, bw.Din,
         ybuf, nullptr, zin, 2, false);
    ln_kernel<<<NN/4, 256, 0, stream>>>(ybuf, bw.Din, bw.Kpad, xlnh);
    gemm(xlnh, bw.F1Th, bw.F1Tl, DEMB, 512, bw.Kpad, DEMB,
         nullptr, h1h, nullptr, 1|4, false);
    gemm(h1h, bw.F2Th, bw.F2Tl, bw.Dout, 512, 480, bw.Dout,
         zout, nullptr, bw.res ? ybuf : nullptr, bw.res ? 2 : 0, false);
  };

  BW b0 = { b0_Wsh_c, r_all + (size_t)0*NE*4,
            b0_qkvTh,b0_qkvTl,b0_WoTh,b0_WoTl,b0_F1Th,b0_F1Tl,b0_F2Th,b0_F2Tl,
            720, 736, 480, false };
  BW bm[4];
  for (int i = 0; i < 4; ++i){
    bm[i] = { bm_Wsh_c + (size_t)i*9*480, r_all + (size_t)(1+i)*NE*4,
              bm_qkvTh[i],bm_qkvTl[i],bm_WoTh[i],bm_WoTl[i],
              bm_F1Th[i],bm_F1Tl[i],bm_F2Th[i],bm_F2Tl[i],
              480, 480, 480, true };
  }
  BW bf = { bf_Wsh_c, r_all + (size_t)5*NE*4,
            bf_qkvTh,bf_qkvTl,bf_WoTh,bf_WoTl,bf_F1Th,bf_F1Tl,bf_F2Th,bf_F2Tl,
            480, 480, 512, false };

  float* z  = zA;
  float* z2 = zB;
  for (int iter = 0; iter < 2; ++iter){
    zcat_kernel<<<(NN*720)/256, 256, 0, stream>>>(z, injb, zcat);
    run_block(b0, zcat, z2);
    { float* tmp = z; z = z2; z2 = tmp; }
    for (int i = 0; i < 4; ++i){
      run_block(bm[i], z, z2);
      { float* tmp = z; z = z2; z2 = tmp; }
    }
  }
  run_block(bf, z, z2);
  ln_kernel<<<NN/4, 256, 0, stream>>>(z2, DFEAT, DFEAT, xlnh);
  gemm(xlnh, hW1Th, hW1Tl, DFEAT, 512, DFEAT, DFEAT,
       nullptr, g1h, nullptr, 1|4, true);
  zero_f32<<<1, 64, 0, stream>>>(gsum, 64);
  head_dot_kernel<<<NN/4, 256, 0, stream>>>(g1h, hW2_c, batch, gsum);
  finalize_kernel<<<1, 64, 0, stream>>>(gsum, dflag, d_out);
}

// Round 11
// 1390.765 us; speedup vs baseline: 1.8655x; 1.0274x over previous
//
#include <hip/hip_runtime.h>

#define NN 2048
#define NE 32768
#define NG 64
#define DINJ 240
#define DEMB 480
#define DFEAT 512
#define MAXDEG 192

typedef unsigned short ushort_t;
typedef __attribute__((ext_vector_type(8))) short short8;
typedef __attribute__((ext_vector_type(4))) float floatx4;

__device__ __forceinline__ float b2f(ushort_t u){
  union { unsigned u; float f; } x; x.u = ((unsigned)u) << 16; return x.f;
}
__device__ __forceinline__ ushort_t f2b(float f){
  union { float f; unsigned u; } x; x.f = f;
  unsigned r = x.u + 0x7FFFu + ((x.u >> 16) & 1u);
  return (ushort_t)(r >> 16);
}
__device__ __forceinline__ float wredsum(float v){
  #pragma unroll
  for (int o = 32; o > 0; o >>= 1) v += __shfl_xor(v, o, 64);
  return v;
}
__device__ __forceinline__ float silu_f(float x){ return x / (1.f + __expf(-x)); }

// ---------------- small utility kernels ----------------
__global__ void zero_f32(float* p, int n){
  int i = blockIdx.x*256 + threadIdx.x; if (i < n) p[i] = 0.f;
}

// ---------------- input dtype detection ----------------
__global__ void detect_kernel(const ushort_t* __restrict__ probe, int* flag){
  __shared__ int c;
  if (threadIdx.x == 0) c = 0;
  __syncthreads();
  ushort_t u = probe[2*threadIdx.x];
  int e = (u >> 7) & 0xFF;
  int plausible = (u == 0) || (e >= 100 && e <= 140);
  atomicAdd(&c, plausible);
  __syncthreads();
  if (threadIdx.x == 0) *flag = (c >= 192) ? 0 : 1;
}

// -------- convert small float inputs -> internal FP32 (exact either way) ----
struct CDesc { const void* src; float* dst; int n; };
struct CDescArr { CDesc d[11]; };
__global__ __launch_bounds__(256) void convert_inputs(CDescArr ca, const int* __restrict__ flag){
  CDesc cd = ca.d[blockIdx.y];
  int isf32 = *flag;
  for (int i = blockIdx.x*256 + threadIdx.x; i < cd.n; i += gridDim.x*256){
    cd.dst[i] = isf32 ? ((const float*)cd.src)[i] : b2f(((const ushort_t*)cd.src)[i]);
  }
}

// --- LDS-tiled weight transpose: src (K x M row-major) -> dst (Mpad x Kpad) --
struct TDesc { const void* src; ushort_t* dh; ushort_t* dl; int K; int M; int Kpad; int Mpad; int eoff; };
struct TDescArr { TDesc d[37]; };
__global__ __launch_bounds__(256) void transpose_all(TDescArr ta, const int* __restrict__ flag){
  TDesc td = ta.d[blockIdx.z];
  int k0 = blockIdx.x*32, m0 = blockIdx.y*32;
  if (k0 >= td.Kpad || m0 >= td.Mpad) return;
  int isf32 = *flag;
  __shared__ float lds[32*33];
  int tx = threadIdx.x & 31, ty = threadIdx.x >> 5;
  #pragma unroll
  for (int r = 0; r < 4; ++r){
    int kl = ty + r*8;
    int k = k0 + kl, mm = m0 + tx;
    float x = 0.f;
    if (k < td.K && mm < td.M){
      size_t si = (size_t)td.eoff + (size_t)k*td.M + mm;
      x = isf32 ? ((const float*)td.src)[si] : b2f(((const ushort_t*)td.src)[si]);
    }
    lds[kl*33 + tx] = x;
  }
  __syncthreads();
  #pragma unroll
  for (int r = 0; r < 4; ++r){
    int nl = ty + r*8;
    int n = m0 + nl, k = k0 + tx;
    if (n < td.Mpad && k < td.Kpad){
      float x = lds[tx*33 + nl];
      ushort_t h = f2b(x);
      size_t di = (size_t)n*td.Kpad + k;
      td.dh[di] = h;
      td.dl[di] = f2b(x - b2f(h));
    }
  }
}

// ---- pack 6 Wr slots into Wr_all[128][24] (k-major, o=slot*4+h inner) ------
__global__ void pack_wr(const float* __restrict__ b0Wr, const float* __restrict__ bmWr,
                        const float* __restrict__ bfWr, float* __restrict__ Wr_all){
  int idx = blockIdx.x*256 + threadIdx.x; if (idx >= 128*24) return;
  int k = idx / 24, o = idx - k*24;
  int slot = o >> 2, h = o & 3;
  const float* Wr = (slot == 0) ? b0Wr : ((slot <= 4) ? bmWr + (size_t)(slot-1)*512 : bfWr);
  Wr_all[idx] = Wr[k*4+h];
}

// ---- fused per-edge setup: geometry + sh + t9 + all 6 gate slots ------------
// rbf computed on the fly (never materialized). Weights via wave-uniform loads.
__global__ __launch_bounds__(256) void edge_all_kernel(
    const float* __restrict__ pos,
    const int* __restrict__ esrc, const int* __restrict__ edst,
    const float* __restrict__ degWr, const float* __restrict__ Wr_all,
    float* __restrict__ sh_out, float* __restrict__ t9,
    float* __restrict__ r_all){
  int e = blockIdx.x*256 + threadIdx.x; if (e >= NE) return;
  int s = esrc[e], d = edst[e];
  float x = pos[s*3+0] - pos[d*3+0];
  float y = pos[s*3+1] - pos[d*3+1];
  float z = pos[s*3+2] - pos[d*3+2];
  float dd = sqrtf(x*x + y*y + z*z + 1e-12f);
  float ix = x/dd, iy = y/dd, iz = z/dd;
  const float s3 = 1.7320508075688772f, s15 = 3.872983346207417f, s5 = 2.23606797749979f;
  float sh[9];
  sh[0] = 1.f; sh[1] = s3*ix; sh[2] = s3*iy; sh[3] = s3*iz;
  sh[4] = s15*ix*iy; sh[5] = s15*iy*iz; sh[6] = 0.5f*s5*(3.f*iz*iz - 1.f);
  sh[7] = s15*ix*iz; sh[8] = 0.5f*s15*(ix*ix - iy*iy);
  #pragma unroll
  for (int j = 0; j < 9; ++j) sh_out[(size_t)e*9+j] = sh[j];
  float t9a[9], ga[24];
  #pragma unroll
  for (int j = 0; j < 9; ++j) t9a[j] = 0.f;
  #pragma unroll
  for (int o = 0; o < 24; ++o) ga[o] = 0.f;
  for (int k = 0; k < 128; ++k){
    float c = (float)k * (5.0f/127.0f);
    float u = (dd - c) * (128.0f/5.0f);
    float rb = __expf(-0.5f*u*u);
    const float* w9  = degWr + k*9;
    const float* w24 = Wr_all + k*24;
    #pragma unroll
    for (int j = 0; j < 9; ++j) t9a[j] += rb*w9[j];
    #pragma unroll
    for (int o = 0; o < 24; ++o) ga[o] += rb*w24[o];
  }
  #pragma unroll
  for (int j = 0; j < 9; ++j) t9[(size_t)e*9+j] = sh[j]*silu_f(t9a[j]);
  #pragma unroll
  for (int o = 0; o < 24; ++o){
    int slot = o >> 2, h = o & 3;
    r_all[((size_t)slot*NE + e)*4 + h] = silu_f(ga[o]);
  }
}

// ---------------- CSR build ----------------
__global__ void hist_kernel(const int* __restrict__ edst, int* counts){
  int e = blockIdx.x*256 + threadIdx.x; if (e < NE) atomicAdd(&counts[edst[e]], 1);
}
__global__ __launch_bounds__(1024) void scan_kernel(const int* __restrict__ counts,
                                                    int* rowptr, int* cursor){
  __shared__ int s[1024];
  int t = threadIdx.x;
  int c0 = counts[2*t], c1 = counts[2*t+1];
  s[t] = c0 + c1;
  __syncthreads();
  for (int off = 1; off < 1024; off <<= 1){
    int v = (t >= off) ? s[t-off] : 0;
    __syncthreads();
    s[t] += v;
    __syncthreads();
  }
  int excl = s[t] - (c0 + c1);
  rowptr[2*t]   = excl;       cursor[2*t]   = excl;
  rowptr[2*t+1] = excl + c0;  cursor[2*t+1] = excl + c0;
  if (t == 1023) rowptr[2048] = s[1023];
}
__global__ void scatter_kernel(const int* __restrict__ edst, int* cursor, int* perm){
  int e = blockIdx.x*256 + threadIdx.x; if (e >= NE) return;
  int p = atomicAdd(&cursor[edst[e]], 1);
  perm[p] = e;
}

// ---------------- inj = atom_table[node_atom] + (sum_e t9) @ degWsh / 16 -----
__global__ __launch_bounds__(64) void inj_kernel(const float* __restrict__ t9,
    const int* __restrict__ rowptr, const int* __restrict__ perm,
    const int* __restrict__ node_atom, const float* __restrict__ atom_table,
    const float* __restrict__ degWsh, float* __restrict__ inj){
  int i = blockIdx.x; int lane = threadIdx.x;
  int b = rowptr[i], e = rowptr[i+1];
  float T[9];
  #pragma unroll
  for (int j = 0; j < 9; ++j) T[j] = 0.f;
  for (int idx = b; idx < e; ++idx){
    int ed = perm[idx];
    #pragma unroll
    for (int j = 0; j < 9; ++j) T[j] += t9[(size_t)ed*9+j];
  }
  int a = node_atom[i];
  for (int c = lane; c < DINJ; c += 64){
    float s = 0.f;
    #pragma unroll
    for (int j = 0; j < 9; ++j) s += T[j]*degWsh[j*DINJ+c];
    inj[(size_t)i*DINJ+c] = atom_table[(size_t)a*DINJ+c] + s*(1.0f/16.0f);
  }
}

// ------- LayerNorm: one wave per row, 4 rows per block -----------------------
__global__ __launch_bounds__(256) void ln_kernel(const float* __restrict__ in, int D,
                                                 int Kpad, ushort_t* __restrict__ oh){
  int i = blockIdx.x*4 + (threadIdx.x >> 6);
  int lane = threadIdx.x & 63;
  const float* row = in + (size_t)i*D;
  float s = 0.f, sq = 0.f;
  for (int d = lane; d < D; d += 64){ float x = row[d]; s += x; sq += x*x; }
  s = wredsum(s); sq = wredsum(sq);
  float mu = s / (float)D;
  float var = fmaxf(sq / (float)D - mu*mu, 0.f);
  float rs = rsqrtf(var + 1e-6f);
  ushort_t* ohrow = oh + (size_t)i*Kpad;
  for (int d = lane; d < D; d += 64) ohrow[d] = f2b((row[d]-mu)*rs);
  for (int d = D + lane; d < Kpad; d += 64) ohrow[d] = 0;
}

// ------- LayerNorm over concat [z(480) | inj(240)] -> 736-padded bf16 --------
__global__ __launch_bounds__(256) void ln_cat_kernel(const float* __restrict__ z,
    const float* __restrict__ inj, ushort_t* __restrict__ oh){
  int i = blockIdx.x*4 + (threadIdx.x >> 6);
  int lane = threadIdx.x & 63;
  const float* zr = z + (size_t)i*480;
  const float* ir = inj + (size_t)i*240;
  float s = 0.f, sq = 0.f;
  for (int d = lane; d < 720; d += 64){
    float x = (d < 480) ? zr[d] : ir[d-480];
    s += x; sq += x*x;
  }
  s = wredsum(s); sq = wredsum(sq);
  float mu = s * (1.0f/720.0f);
  float var = fmaxf(sq * (1.0f/720.0f) - mu*mu, 0.f);
  float rs = rsqrtf(var + 1e-6f);
  ushort_t* ohrow = oh + (size_t)i*736;
  for (int d = lane; d < 720; d += 64){
    float x = (d < 480) ? zr[d] : ir[d-480];
    ohrow[d] = f2b((x-mu)*rs);
  }
  for (int d = 720 + lane; d < 736; d += 64) ohrow[d] = 0;
}

// -- MFMA GEMM: C = A * B^T with B = Bh (+Bl if SPLITB). Ring prefetch. -------
// flags: 1=silu, 2=add residual, 4=bf16 out, 8=residual is concat(R 480, R2 240)
template<int KPAD, bool SPLITB>
__global__ __launch_bounds__(256) void gemm_bt(
    const ushort_t* __restrict__ A,
    const ushort_t* __restrict__ BTh, const ushort_t* __restrict__ BTl,
    int N, int ldc,
    float* __restrict__ Cf, ushort_t* __restrict__ Cb,
    const float* __restrict__ R, const float* __restrict__ R2, int flags){
  int lane = threadIdx.x & 63, wave = threadIdx.x >> 6;
  int row0 = blockIdx.y*64 + (wave>>1)*32;
  int col0 = blockIdx.x*64 + (wave&1)*32;
  int m = lane & 15, q4 = lane >> 4;
  size_t a0 = (size_t)(row0+m)*KPAD + q4*8;
  size_t a1 = a0 + (size_t)16*KPAD;
  size_t b0 = (size_t)(col0+m)*KPAD + q4*8;
  size_t b1 = b0 + (size_t)16*KPAD;
  floatx4 acc00 = {0,0,0,0}, acc01 = {0,0,0,0}, acc10 = {0,0,0,0}, acc11 = {0,0,0,0};
  constexpr int steps = KPAD >> 5;
  constexpr int DEPTH = SPLITB ? 3 : 4;
  struct Frag { short8 A0, A1, B0h, B1h, B0l, B1l; };
  auto loadF = [&](int s) -> Frag {
    Frag f;
    size_t o = (size_t)s*32;
    f.A0  = *(const short8*)(A   + a0 + o);
    f.A1  = *(const short8*)(A   + a1 + o);
    f.B0h = *(const short8*)(BTh + b0 + o);
    f.B1h = *(const short8*)(BTh + b1 + o);
    if (SPLITB){
      f.B0l = *(const short8*)(BTl + b0 + o);
      f.B1l = *(const short8*)(BTl + b1 + o);
    }
    return f;
  };
  Frag ring[DEPTH];
  #pragma unroll
  for (int d = 0; d < DEPTH; ++d) ring[d] = loadF(d < steps ? d : steps-1);
  #pragma unroll
  for (int s = 0; s < steps; ++s){
    Frag cur = ring[s % DEPTH];
    if (s + DEPTH < steps) ring[s % DEPTH] = loadF(s + DEPTH);
    acc00 = __builtin_amdgcn_mfma_f32_16x16x32_bf16(cur.A0, cur.B0h, acc00, 0, 0, 0);
    acc01 = __builtin_amdgcn_mfma_f32_16x16x32_bf16(cur.A0, cur.B1h, acc01, 0, 0, 0);
    acc10 = __builtin_amdgcn_mfma_f32_16x16x32_bf16(cur.A1, cur.B0h, acc10, 0, 0, 0);
    acc11 = __builtin_amdgcn_mfma_f32_16x16x32_bf16(cur.A1, cur.B1h, acc11, 0, 0, 0);
    if (SPLITB){
      acc00 = __builtin_amdgcn_mfma_f32_16x16x32_bf16(cur.A0, cur.B0l, acc00, 0, 0, 0);
      acc01 = __builtin_amdgcn_mfma_f32_16x16x32_bf16(cur.A0, cur.B1l, acc01, 0, 0, 0);
      acc10 = __builtin_amdgcn_mfma_f32_16x16x32_bf16(cur.A1, cur.B0l, acc10, 0, 0, 0);
      acc11 = __builtin_amdgcn_mfma_f32_16x16x32_bf16(cur.A1, cur.B1l, acc11, 0, 0, 0);
    }
  }
  #pragma unroll
  for (int rr = 0; rr < 2; ++rr){
    #pragma unroll
    for (int cc = 0; cc < 2; ++cc){
      int col = col0 + cc*16 + m;
      if (col >= N) continue;
      floatx4 acc = rr ? (cc ? acc11 : acc10) : (cc ? acc01 : acc00);
      int rowb = row0 + rr*16 + q4*4;
      #pragma unroll
      for (int r = 0; r < 4; ++r){
        int row = rowb + r;
        size_t idx = (size_t)row*ldc + col;
        float v = acc[r];
        if (flags & 2){
          if (flags & 8)
            v += (col < 480) ? R[(size_t)row*480 + col] : R2[(size_t)row*240 + (col-480)];
          else
            v += R[idx];
        }
        if (flags & 1) v = silu_f(v);
        if (flags & 4) Cb[idx] = f2b(v);
        else           Cf[idx] = v;
      }
    }
  }
}

// ------- fused per-node attention: logits + softmax + aggregation ------------
__global__ __launch_bounds__(256) void node_attn_kernel(
    const float* __restrict__ qkv, const float* __restrict__ sh,
    const float* __restrict__ Wsh, const float* __restrict__ r_slot,
    const int* __restrict__ rowptr, const int* __restrict__ perm,
    const int* __restrict__ esrc, ushort_t* __restrict__ aggh){
  int i = blockIdx.x; int t = threadIdx.x;
  int lane = t & 63, w = t >> 6;
  int b = rowptr[i]; int deg = min(rowptr[i+1] - b, MAXDEG);
  __shared__ float qL[480];
  __shared__ float PqL[36];
  __shared__ float logitL[MAXDEG*4];
  __shared__ float rL[MAXDEG*4];
  __shared__ int eL[MAXDEG], srcL[MAXDEG];
  __shared__ float S[36];
  __shared__ float mxs[4], dens[4];
  for (int d = t; d < 480; d += 256) qL[d] = qkv[(size_t)i*1440 + d];
  for (int idx = t; idx < deg; idx += 256){
    int e = perm[b+idx];
    eL[idx] = e;
    srcL[idx] = esrc[e];
  }
  __syncthreads();
  if (t < 36){
    int h = t/9, j = t - h*9;
    const float* ws = Wsh + (size_t)j*DEMB + h*120;
    const float* qh = qL + h*120;
    float p = 0.f;
    for (int k = 0; k < 120; ++k) p += qh[k]*ws[k];
    PqL[t] = p;
  }
  __syncthreads();
  const float inv = 0.091287092917527686f;
  for (int base = 0; base < deg; base += 64){
    int idx = base + (t >> 2);
    if (idx < deg){
      int h = t & 3;
      int e = eL[idx], s = srcL[idx];
      const float4* kk = (const float4*)(qkv + (size_t)s*1440 + 480 + h*120);
      const float4* qq = (const float4*)(qL + h*120);
      float p = 0.f;
      #pragma unroll
      for (int it = 0; it < 30; ++it){
        float4 a = qq[it], bb = kk[it];
        p += a.x*bb.x + a.y*bb.y + a.z*bb.z + a.w*bb.w;
      }
      float mmq = 0.f;
      const float* she = sh + (size_t)e*9;
      #pragma unroll
      for (int j = 0; j < 9; ++j) mmq += she[j]*PqL[h*9+j];
      float rr = r_slot[(size_t)e*4+h];
      rL[idx*4+h] = rr;
      logitL[idx*4+h] = rr*(p + mmq)*inv;
    }
  }
  __syncthreads();
  float mx = -1e30f;
  for (int idx = lane; idx < deg; idx += 64) mx = fmaxf(mx, logitL[idx*4+w]);
  #pragma unroll
  for (int o = 32; o > 0; o >>= 1) mx = fmaxf(mx, __shfl_xor(mx, o, 64));
  if (deg == 0) mx = 0.f;
  float den = 0.f;
  for (int idx = lane; idx < deg; idx += 64) den += __expf(logitL[idx*4+w]-mx);
  den = wredsum(den) + 1e-9f;
  if (lane == 0){ mxs[w] = mx; dens[w] = den; }
  __syncthreads();
  for (int j = t; j < deg*4; j += 256){
    int h = j & 3;
    logitL[j] = __expf(logitL[j]-mxs[h]) / dens[h] * rL[j];
  }
  __syncthreads();
  float a0 = 0.f, a1 = 0.f;
  int d0 = 2*t, h2 = d0/120;
  if (t >= 240){
    for (int o = t - 240; o < 36; o += 16){
      int h = o/9, j = o - h*9;
      float a = 0.f;
      for (int idx = 0; idx < deg; ++idx)
        a += logitL[idx*4+h]*sh[(size_t)eL[idx]*9+j];
      S[o] = a;
    }
  } else {
    for (int idx = 0; idx < deg; ++idx){
      float wgt = logitL[idx*4+h2];
      float2 vv = *(const float2*)(qkv + (size_t)srcL[idx]*1440 + 960 + d0);
      a0 += wgt*vv.x; a1 += wgt*vv.y;
    }
  }
  __syncthreads();
  if (t < 240){
    float mm0 = 0.f, mm1 = 0.f;
    #pragma unroll
    for (int j = 0; j < 9; ++j){
      mm0 += S[h2*9+j]*Wsh[j*DEMB + d0];
      mm1 += S[h2*9+j]*Wsh[j*DEMB + d0 + 1];
    }
    aggh[(size_t)i*DEMB + d0]     = f2b(a0 + mm0);
    aggh[(size_t)i*DEMB + d0 + 1] = f2b(a1 + mm1);
  }
}

// ---------------- head ----------------
__global__ __launch_bounds__(256) void head_dot_kernel(const ushort_t* __restrict__ g1h,
    const float* __restrict__ hW2, const int* __restrict__ batch, float* gsum){
  int i = blockIdx.x*4 + (threadIdx.x >> 6);
  int lane = threadIdx.x & 63;
  float s = 0.f;
  for (int d = lane; d < DFEAT; d += 64)
    s += b2f(g1h[(size_t)i*DFEAT + d]) * hW2[d];
  s = wredsum(s);
  if (lane == 0) atomicAdd(&gsum[batch[i]], s);
}
__global__ void finalize_kernel(const float* __restrict__ gsum,
                                const int* __restrict__ flag, void* out){
  int g = threadIdx.x;
  if (g < NG){
    float v = gsum[g] * 0.17677669529663687f; // 1/sqrt(32)
    if (*flag) ((float*)out)[g] = v;
    else       ((ushort_t*)out)[g] = f2b(v);
  }
}

// =====================================================================
extern "C" void kernel_launch(void* const* d_in, const int* in_sizes, int n_in,
                              void* d_out, int out_size, void* d_ws, size_t ws_size,
                              hipStream_t stream) {
  (void)in_sizes; (void)n_in; (void)out_size; (void)ws_size;
  const void* pos        = d_in[0];
  const int*  node_atom  = (const int*)d_in[1];
  const int*  esrc       = (const int*)d_in[2];
  const int*  edst       = (const int*)d_in[3];
  const int*  batch      = (const int*)d_in[4];
  const void* atom_table = d_in[5];
  const void* degWr      = d_in[6];
  const void* degWsh     = d_in[7];
  const void* b0_Wq  = d_in[8];
  const void* b0_Wk  = d_in[9];
  const void* b0_Wv  = d_in[10];
  const void* b0_Wsh = d_in[11];
  const void* b0_Wr  = d_in[12];
  const void* b0_Wo  = d_in[13];
  const void* b0_F1  = d_in[14];
  const void* b0_F2  = d_in[15];
  const void* bm_Wq  = d_in[16];
  const void* bm_Wk  = d_in[17];
  const void* bm_Wv  = d_in[18];
  const void* bm_Wsh = d_in[19];
  const void* bm_Wr  = d_in[20];
  const void* bm_Wo  = d_in[21];
  const void* bm_F1  = d_in[22];
  const void* bm_F2  = d_in[23];
  const void* bf_Wq  = d_in[24];
  const void* bf_Wk  = d_in[25];
  const void* bf_Wv  = d_in[26];
  const void* bf_Wsh = d_in[27];
  const void* bf_Wr  = d_in[28];
  const void* bf_Wo  = d_in[29];
  const void* bf_F1  = d_in[30];
  const void* bf_F2  = d_in[31];
  const void* hW1    = d_in[32];
  const void* hW2    = d_in[33];

  char* bws = (char*)d_ws;
  size_t off = 0;
  auto alloc = [&](size_t bytes) -> void* {
    void* p = bws + off;
    off += (bytes + 255) & ~(size_t)255;
    return p;
  };
  int* dflag   = (int*)alloc(256);
  float* sh_f  = (float*)alloc((size_t)NE*9*4);
  float* t9    = (float*)alloc((size_t)NE*9*4);
  int* counts  = (int*)alloc(2048*4);
  int* rowptr  = (int*)alloc(2049*4);
  int* cursor  = (int*)alloc(2048*4);
  int* perm    = (int*)alloc((size_t)NE*4);
  float* injb  = (float*)alloc((size_t)NN*DINJ*4);
  float* zA    = (float*)alloc((size_t)NN*512*4);
  float* zB    = (float*)alloc((size_t)NN*512*4);
  ushort_t* xlnh = (ushort_t*)alloc((size_t)NN*736*2);
  float* qkvb  = (float*)alloc((size_t)NN*1440*4);
  float* Wr_all = (float*)alloc((size_t)128*24*4);
  float* r_all = (float*)alloc((size_t)6*NE*4*4);
  ushort_t* aggh = (ushort_t*)alloc((size_t)NN*DEMB*2);
  float* ybuf  = (float*)alloc((size_t)NN*720*4);
  ushort_t* h1h = (ushort_t*)alloc((size_t)NN*DEMB*2);
  ushort_t* g1h = (ushort_t*)alloc((size_t)NN*DFEAT*2);
  float* gsum  = (float*)alloc(64*4);

  float* pos_c    = (float*)alloc((size_t)NN*3*4);
  float* atom_c   = (float*)alloc((size_t)64*DINJ*4);
  float* degWr_c  = (float*)alloc((size_t)128*9*4);
  float* degWsh_c = (float*)alloc((size_t)9*DINJ*4);
  float* b0_Wsh_c = (float*)alloc((size_t)9*480*4);
  float* b0_Wr_c  = (float*)alloc((size_t)128*4*4);
  float* bm_Wsh_c = (float*)alloc((size_t)4*9*480*4);
  float* bm_Wr_c  = (float*)alloc((size_t)4*128*4*4);
  float* bf_Wsh_c = (float*)alloc((size_t)9*480*4);
  float* bf_Wr_c  = (float*)alloc((size_t)128*4*4);
  float* hW2_c    = (float*)alloc((size_t)512*4);

  auto allocW = [&](size_t elems, ushort_t*& h, ushort_t*& l){
    h = (ushort_t*)alloc(elems*2); l = (ushort_t*)alloc(elems*2);
  };
  ushort_t *b0_qkvTh,*b0_qkvTl,*b0_WoTh,*b0_WoTl,*b0_F1Th,*b0_F1Tl,*b0_F2Th,*b0_F2Tl;
  allocW((size_t)1472*736, b0_qkvTh, b0_qkvTl);
  allocW((size_t)768*480,  b0_WoTh,  b0_WoTl);
  allocW((size_t)512*736,  b0_F1Th,  b0_F1Tl);
  allocW((size_t)512*480,  b0_F2Th,  b0_F2Tl);
  ushort_t *bm_qkvTh[4],*bm_qkvTl[4],*bm_WoTh[4],*bm_WoTl[4],*bm_F1Th[4],*bm_F1Tl[4],*bm_F2Th[4],*bm_F2Tl[4];
  for (int i = 0; i < 4; ++i){
    allocW((size_t)1472*480, bm_qkvTh[i], bm_qkvTl[i]);
    allocW((size_t)512*480,  bm_WoTh[i],  bm_WoTl[i]);
    allocW((size_t)512*480,  bm_F1Th[i],  bm_F1Tl[i]);
    allocW((size_t)512*480,  bm_F2Th[i],  bm_F2Tl[i]);
  }
  ushort_t *bf_qkvTh,*bf_qkvTl,*bf_WoTh,*bf_WoTl,*bf_F1Th,*bf_F1Tl,*bf_F2Th,*bf_F2Tl,*hW1Th,*hW1Tl;
  allocW((size_t)1472*480, bf_qkvTh, bf_qkvTl);
  allocW((size_t)512*480,  bf_WoTh,  bf_WoTl);
  allocW((size_t)512*480,  bf_F1Th,  bf_F1Tl);
  allocW((size_t)512*480,  bf_F2Th,  bf_F2Tl);
  allocW((size_t)512*512,  hW1Th,    hW1Tl);

  detect_kernel<<<1, 256, 0, stream>>>((const ushort_t*)atom_table, dflag);

  CDescArr ca;
  int ci = 0;
  auto addC = [&](const void* s, float* d, int n){
    ca.d[ci].src = s; ca.d[ci].dst = d; ca.d[ci].n = n; ++ci;
  };
  addC(pos, pos_c, NN*3);
  addC(atom_table, atom_c, 64*DINJ);
  addC(degWr, degWr_c, 128*9);
  addC(degWsh, degWsh_c, 9*DINJ);
  addC(b0_Wsh, b0_Wsh_c, 9*480);
  addC(b0_Wr, b0_Wr_c, 128*4);
  addC(bm_Wsh, bm_Wsh_c, 4*9*480);
  addC(bm_Wr, bm_Wr_c, 4*128*4);
  addC(bf_Wsh, bf_Wsh_c, 9*480);
  addC(bf_Wr, bf_Wr_c, 128*4);
  addC(hW2, hW2_c, 512);
  convert_inputs<<<dim3(8, 11), 256, 0, stream>>>(ca, dflag);

  TDescArr ta;
  int ti = 0;
  auto addT = [&](const void* s, ushort_t* dh, ushort_t* dl, int K, int M,
                  int Kp, int Mp, int rowoff, int eo){
    ta.d[ti].src = s;
    ta.d[ti].dh = dh + (size_t)rowoff*Kp;
    ta.d[ti].dl = dl + (size_t)rowoff*Kp;
    ta.d[ti].K = K; ta.d[ti].M = M; ta.d[ti].Kpad = Kp; ta.d[ti].Mpad = Mp;
    ta.d[ti].eoff = eo; ++ti;
  };
  addT(b0_Wq, b0_qkvTh, b0_qkvTl, 720, 480, 736, 480, 0,   0);
  addT(b0_Wk, b0_qkvTh, b0_qkvTl, 720, 480, 736, 480, 480, 0);
  addT(b0_Wv, b0_qkvTh, b0_qkvTl, 720, 480, 736, 512, 960, 0);
  addT(b0_Wo, b0_WoTh,  b0_WoTl,  480, 720, 480, 768, 0,   0);
  addT(b0_F1, b0_F1Th,  b0_F1Tl,  720, 480, 736, 512, 0,   0);
  addT(b0_F2, b0_F2Th,  b0_F2Tl,  480, 480, 480, 512, 0,   0);
  for (int i = 0; i < 4; ++i){
    int eo = i*480*480;
    addT(bm_Wq, bm_qkvTh[i], bm_qkvTl[i], 480, 480, 480, 480, 0,   eo);
    addT(bm_Wk, bm_qkvTh[i], bm_qkvTl[i], 480, 480, 480, 480, 480, eo);
    addT(bm_Wv, bm_qkvTh[i], bm_qkvTl[i], 480, 480, 480, 512, 960, eo);
    addT(bm_Wo, bm_WoTh[i],  bm_WoTl[i],  480, 480, 480, 512, 0,   eo);
    addT(bm_F1, bm_F1Th[i],  bm_F1Tl[i],  480, 480, 480, 512, 0,   eo);
    addT(bm_F2, bm_F2Th[i],  bm_F2Tl[i],  480, 480, 480, 512, 0,   eo);
  }
  addT(bf_Wq, bf_qkvTh, bf_qkvTl, 480, 480, 480, 480, 0,   0);
  addT(bf_Wk, bf_qkvTh, bf_qkvTl, 480, 480, 480, 480, 480, 0);
  addT(bf_Wv, bf_qkvTh, bf_qkvTl, 480, 480, 480, 512, 960, 0);
  addT(bf_Wo, bf_WoTh,  bf_WoTl,  480, 480, 480, 512, 0,   0);
  addT(bf_F1, bf_F1Th,  bf_F1Tl,  480, 480, 480, 512, 0,   0);
  addT(bf_F2, bf_F2Th,  bf_F2Tl,  480, 512, 480, 512, 0,   0);
  addT(hW1,   hW1Th,    hW1Tl,    512, 512, 512, 512, 0,   0);
  transpose_all<<<dim3(23, 24, 37), 256, 0, stream>>>(ta, dflag);

  pack_wr<<<12, 256, 0, stream>>>(b0_Wr_c, bm_Wr_c, bf_Wr_c, Wr_all);
  edge_all_kernel<<<NE/256, 256, 0, stream>>>(pos_c, esrc, edst, degWr_c, Wr_all,
                                              sh_f, t9, r_all);

  zero_f32<<<(2048 + 255)/256, 256, 0, stream>>>((float*)counts, 2048);
  hist_kernel<<<NE/256, 256, 0, stream>>>(edst, counts);
  scan_kernel<<<1, 1024, 0, stream>>>(counts, rowptr, cursor);
  scatter_kernel<<<NE/256, 256, 0, stream>>>(edst, cursor, perm);

  inj_kernel<<<NN, 64, 0, stream>>>(t9, rowptr, perm, node_atom, atom_c, degWsh_c, injb);
  zero_f32<<<(NN*DEMB)/256, 256, 0, stream>>>(zA, NN*DEMB);

  auto gemm = [&](const ushort_t* A, const ushort_t* BTh, const ushort_t* BTl,
                  int N, int Npad, int Kp, int ldc,
                  float* Cf, ushort_t* Cb, const float* R, const float* R2,
                  int flags, bool split){
    dim3 g(Npad/64, 32);
    if (split){
      if (Kp == 480)
        gemm_bt<480,true><<<g, 256, 0, stream>>>(A, BTh, BTl, N, ldc, Cf, Cb, R, R2, flags);
      else if (Kp == 512)
        gemm_bt<512,true><<<g, 256, 0, stream>>>(A, BTh, BTl, N, ldc, Cf, Cb, R, R2, flags);
      else
        gemm_bt<736,true><<<g, 256, 0, stream>>>(A, BTh, BTl, N, ldc, Cf, Cb, R, R2, flags);
    } else {
      if (Kp == 480)
        gemm_bt<480,false><<<g, 256, 0, stream>>>(A, BTh, BTl, N, ldc, Cf, Cb, R, R2, flags);
      else if (Kp == 512)
        gemm_bt<512,false><<<g, 256, 0, stream>>>(A, BTh, BTl, N, ldc, Cf, Cb, R, R2, flags);
      else
        gemm_bt<736,false><<<g, 256, 0, stream>>>(A, BTh, BTl, N, ldc, Cf, Cb, R, R2, flags);
    }
  };

  struct BW {
    const float *Wsh, *r_slot;
    const ushort_t *qkvTh,*qkvTl,*WoTh,*WoTl,*F1Th,*F1Tl,*F2Th,*F2Tl;
    int Din, Kpad, Dout; bool res;
  };
  // zinj != null -> input is concat [zin(480) | zinj(240)] (b0 blocks)
  auto run_block = [&](const BW& bw, const float* zin, const float* zinj, float* zout){
    if (zinj) ln_cat_kernel<<<NN/4, 256, 0, stream>>>(zin, zinj, xlnh);
    else      ln_kernel<<<NN/4, 256, 0, stream>>>(zin, bw.Din, bw.Kpad, xlnh);
    gemm(xlnh, bw.qkvTh, bw.qkvTl, 1440, 1472, bw.Kpad, 1440,
         qkvb, nullptr, nullptr, nullptr, 0, true);
    node_attn_kernel<<<NN, 256, 0, stream>>>(qkvb, sh_f, bw.Wsh, bw.r_slot,
                                             rowptr, perm, esrc, aggh);
    int WoNpad = (bw.Din == 720) ? 768 : 512;
    gemm(aggh, bw.WoTh, bw.WoTl, bw.Din, WoNpad, 480, bw.Din,
         ybuf, nullptr, zin, zinj, zinj ? (2|8) : 2, false);
    ln_kernel<<<NN/4, 256, 0, stream>>>(ybuf, bw.Din, bw.Kpad, xlnh);
    gemm(xlnh, bw.F1Th, bw.F1Tl, DEMB, 512, bw.Kpad, DEMB,
         nullptr, h1h, nullptr, nullptr, 1|4, false);
    gemm(h1h, bw.F2Th, bw.F2Tl, bw.Dout, 512, 480, bw.Dout,
         zout, nullptr, bw.res ? ybuf : nullptr, nullptr, bw.res ? 2 : 0, false);
  };

  BW b0 = { b0_Wsh_c, r_all + (size_t)0*NE*4,
            b0_qkvTh,b0_qkvTl,b0_WoTh,b0_WoTl,b0_F1Th,b0_F1Tl,b0_F2Th,b0_F2Tl,
            720, 736, 480, false };
  BW bm[4];
  for (int i = 0; i < 4; ++i){
    bm[i] = { bm_Wsh_c + (size_t)i*9*480, r_all + (size_t)(1+i)*NE*4,
              bm_qkvTh[i],bm_qkvTl[i],bm_WoTh[i],bm_WoTl[i],
              bm_F1Th[i],bm_F1Tl[i],bm_F2Th[i],bm_F2Tl[i],
              480, 480, 480, true };
  }
  BW bf = { bf_Wsh_c, r_all + (size_t)5*NE*4,
            bf_qkvTh,bf_qkvTl,bf_WoTh,bf_WoTl,bf_F1Th,bf_F1Tl,bf_F2Th,bf_F2Tl,
            480, 480, 512, false };

  float* z  = zA;
  float* z2 = zB;
  for (int iter = 0; iter < 2; ++iter){
    run_block(b0, z, injb, z2);
    { float* tmp = z; z = z2; z2 = tmp; }
    for (int i = 0; i < 4; ++i){
      run_block(bm[i], z, nullptr, z2);
      { float* tmp = z; z = z2; z2 = tmp; }
    }
  }
  run_block(bf, z, nullptr, z2);
  ln_kernel<<<NN/4, 256, 0, stream>>>(z2, DFEAT, DFEAT, xlnh);
  gemm(xlnh, hW1Th, hW1Tl, DFEAT, 512, DFEAT, DFEAT,
       nullptr, g1h, nullptr, nullptr, 1|4, true);
  zero_f32<<<1, 64, 0, stream>>>(gsum, 64);
  head_dot_kernel<<<NN/4, 256, 0, stream>>>(g1h, hW2_c, batch, gsum);
  finalize_kernel<<<1, 64, 0, stream>>>(gsum, dflag, d_out);
}